// Round 16
// baseline (821.160 us; speedup 1.0000x reference)
//
#include <hip/hip_runtime.h>
#include <hip/hip_bf16.h>
#include <math.h>

// Problem constants
#define B_  8
#define N_  1024
#define C_  12
#define E_  256
#define H_  8
#define D_  32      // E/H
#define L_  4
#define XE_ 1024    // X*E
#define NC_ 5
#define S_  1025    // N+1
#define M_  8200    // B*S
#define EPS_ 1e-5f
#define SP_ 1088    // padded key-stride for vT (17*64, 16B-aligned)

typedef short bf16x8 __attribute__((ext_vector_type(8)));
typedef float f32x4 __attribute__((ext_vector_type(4)));
typedef __hip_bfloat16 bf16;

// async global->LDS DMA, 16 B per lane; LDS dest = wave-uniform base + lane*16
typedef __attribute__((address_space(1))) const unsigned int* as1_cuint;
typedef __attribute__((address_space(3))) unsigned int* as3_uint;
__device__ __forceinline__ void dma16(const void* g, void* l) {
    __builtin_amdgcn_global_load_lds((as1_cuint)g, (as3_uint)l, 16, 0, 0);
}

// ---------------- Embedding (wave per token): x@W+b -> LN -> GELU ----------
__global__ __launch_bounds__(256) void embed4_kernel(
    const float* __restrict__ x, const float* __restrict__ Wemb,
    const float* __restrict__ bemb, const float* __restrict__ g,
    const float* __restrict__ be, const float* __restrict__ cls,
    float* __restrict__ h)
{
    int wave = threadIdx.x >> 6, lane = threadIdx.x & 63;
    int t = blockIdx.x * 4 + wave;          // M_ = 4*2050 exactly
    int b = t / S_, s = t % S_;
    long base = (long)t * E_ + lane * 4;

    if (s == 0) {
        *(float4*)(h + base) = *(const float4*)(cls + lane * 4);
        return;
    }
    const float* xr = x + ((long)b * N_ + (s - 1)) * C_;
    float xv[C_];
#pragma unroll
    for (int c = 0; c < C_; ++c) xv[c] = xr[c];

    float4 acc = *(const float4*)(bemb + lane * 4);
#pragma unroll
    for (int c = 0; c < C_; ++c) {
        float4 w = *(const float4*)(Wemb + c * E_ + lane * 4);
        acc.x += xv[c] * w.x; acc.y += xv[c] * w.y;
        acc.z += xv[c] * w.z; acc.w += xv[c] * w.w;
    }
    float sum = acc.x + acc.y + acc.z + acc.w;
    float sq  = acc.x*acc.x + acc.y*acc.y + acc.z*acc.z + acc.w*acc.w;
#pragma unroll
    for (int off = 1; off < 64; off <<= 1) {
        sum += __shfl_xor(sum, off);
        sq  += __shfl_xor(sq,  off);
    }
    float mean = sum * (1.0f / E_);
    float var  = sq * (1.0f / E_) - mean * mean;
    float rstd = rsqrtf(var + EPS_);
    float4 gg = *(const float4*)(g + lane * 4);
    float4 bb = *(const float4*)(be + lane * 4);
    float4 o;
    float v;
    v = (acc.x - mean) * rstd * gg.x + bb.x; o.x = 0.5f * v * (1.0f + erff(v * 0.70710678118f));
    v = (acc.y - mean) * rstd * gg.y + bb.y; o.y = 0.5f * v * (1.0f + erff(v * 0.70710678118f));
    v = (acc.z - mean) * rstd * gg.z + bb.z; o.z = 0.5f * v * (1.0f + erff(v * 0.70710678118f));
    v = (acc.w - mean) * rstd * gg.w + bb.w; o.w = 0.5f * v * (1.0f + erff(v * 0.70710678118f));
    *(float4*)(h + base) = o;
}

// ------------- LN (wave per token): optional h+=pos, y=bf16(LN(h)) ---------
__global__ __launch_bounds__(256) void ln4_kernel(
    float* __restrict__ h, const float* __restrict__ pos,
    const float* __restrict__ g, const float* __restrict__ bb,
    bf16* __restrict__ y)
{
    int wave = threadIdx.x >> 6, lane = threadIdx.x & 63;
    int t = blockIdx.x * 4 + wave;
    int s = t % S_;
    long base = (long)t * E_ + lane * 4;

    float4 v = *(const float4*)(h + base);
    if (pos) {
        float4 pv = *(const float4*)(pos + (long)s * E_ + lane * 4);
        v.x += pv.x; v.y += pv.y; v.z += pv.z; v.w += pv.w;
        *(float4*)(h + base) = v;
    }
    float sum = v.x + v.y + v.z + v.w;
    float sq  = v.x*v.x + v.y*v.y + v.z*v.z + v.w*v.w;
#pragma unroll
    for (int off = 1; off < 64; off <<= 1) {
        sum += __shfl_xor(sum, off);
        sq  += __shfl_xor(sq,  off);
    }
    float mean = sum * (1.0f / E_);
    float var  = sq * (1.0f / E_) - mean * mean;
    float rstd = rsqrtf(var + EPS_);
    float4 gg = *(const float4*)(g + lane * 4);
    float4 b4 = *(const float4*)(bb + lane * 4);
    bf16 o[4];
    o[0] = __float2bfloat16((v.x - mean) * rstd * gg.x + b4.x);
    o[1] = __float2bfloat16((v.y - mean) * rstd * gg.y + b4.y);
    o[2] = __float2bfloat16((v.z - mean) * rstd * gg.z + b4.z);
    o[3] = __float2bfloat16((v.w - mean) * rstd * gg.w + b4.w);
    *(uint2*)(y + base) = *(uint2*)o;
}

// ---------- Single-launch weight pack (LDS 32x32 transpose) ----------------
__global__ __launch_bounds__(256) void pack_all(
    const float* __restrict__ Wq, const float* __restrict__ Wk,
    const float* __restrict__ Wv, const float* __restrict__ bq,
    const float* __restrict__ bk, const float* __restrict__ bv,
    const float* __restrict__ Wo, const float* __restrict__ W1,
    const float* __restrict__ W2,
    bf16* __restrict__ Wqkvt, float* __restrict__ bqkv,
    bf16* __restrict__ Wot, bf16* __restrict__ W1t, bf16* __restrict__ W2t)
{
    __shared__ float tile[32][33];
    int id = blockIdx.x;
    int tx = threadIdx.x & 31, ty = threadIdx.x >> 5;   // 32x8
    const float* src; bf16* dst;
    int c0, k0, Nsrc, Kd, row0;

    if (id < 768) {                       // QKV: 4l x 8k x 24n
        int l = id / 192, r = id % 192;
        int nt = r % 24, kt2 = r / 24;
        int n0 = nt * 32; k0 = kt2 * 32;
        Nsrc = 256; Kd = 256; row0 = n0;
        if (n0 < 256)      { src = Wq + (long)l * 65536; c0 = n0; }
        else if (n0 < 512) { src = Wk + (long)l * 65536; c0 = n0 - 256; }
        else               { src = Wv + (long)l * 65536; c0 = n0 - 512; }
        dst = Wqkvt + (long)l * 768 * 256;
        if (kt2 == 0 && ty == 0) {
            const float* bsrc = (n0 < 256) ? bq + l * 256 + c0
                              : (n0 < 512) ? bk + l * 256 + c0 : bv + l * 256 + c0;
            bqkv[l * 768 + n0 + tx] = bsrc[tx];
        }
    } else if (id < 1024) {               // Wo
        int r = id - 768; int l = r / 64; r %= 64;
        int nt = r & 7, kt2 = r >> 3;
        c0 = nt * 32; k0 = kt2 * 32; Nsrc = 256; Kd = 256; row0 = c0;
        src = Wo + (long)l * 65536; dst = Wot + (long)l * 65536;
    } else if (id < 2048) {               // W1
        int r = id - 1024; int l = r / 256; r %= 256;
        int nt = r % 32, kt2 = r / 32;
        c0 = nt * 32; k0 = kt2 * 32; Nsrc = 1024; Kd = 256; row0 = c0;
        src = W1 + (long)l * 262144; dst = W1t + (long)l * 262144;
    } else {                              // W2
        int r = id - 2048; int l = r / 256; r %= 256;
        int nt = r & 7, kt2 = r >> 3;
        c0 = nt * 32; k0 = kt2 * 32; Nsrc = 256; Kd = 1024; row0 = c0;
        src = W2 + (long)l * 262144; dst = W2t + (long)l * 262144;
    }
#pragma unroll
    for (int i = 0; i < 4; ++i)
        tile[ty + i * 8][tx] = src[(long)(k0 + ty + i * 8) * Nsrc + c0 + tx];
    __syncthreads();
#pragma unroll
    for (int i = 0; i < 4; ++i)
        dst[(long)(row0 + ty + i * 8) * Kd + k0 + tx] = __float2bfloat16(tile[tx][ty + i * 8]);
}

// ---- bf16 MFMA GEMM 128x128 tile, DMA staging + double buffer -------------
__global__ __launch_bounds__(256) void gemm_bf16_128(
    const bf16* __restrict__ A, const bf16* __restrict__ Wt,
    const float* __restrict__ bias,
    bf16* __restrict__ outB, bf16* __restrict__ vTout,
    int M, int K, int N, int act)
{
    __shared__ bf16 As[2][128 * 64];   // 2 x 16 KB
    __shared__ bf16 Bs[2][128 * 64];   // 2 x 16 KB
    int tid = threadIdx.x;
    int wave = tid >> 6, lane = tid & 63;
    int quad = lane >> 4, l16 = lane & 15;
    int wr = (wave >> 1) * 64, wc = (wave & 1) * 64;
    int row0 = blockIdx.y * 128;
    int col0 = blockIdx.x * 128;

    int sr = lane >> 3;       // row within 8-row DMA group
    int sc = lane & 7;        // 16-B chunk within row

    f32x4 acc[4][4];
#pragma unroll
    for (int i = 0; i < 4; ++i)
#pragma unroll
        for (int j = 0; j < 4; ++j) acc[i][j] = (f32x4){0.f,0.f,0.f,0.f};

    int nk = K >> 6;
    // prologue: DMA tile 0 into buffer 0
#pragma unroll
    for (int gi = 0; gi < 4; ++gi) {
        int gg = wave * 4 + gi;
        int rr = gg * 8 + sr;
        int cs = (sc - rr) & 7;
        dma16(A  + (long)(row0 + rr) * K + cs * 8, &As[0][gg * 8 * 64]);
        dma16(Wt + (long)(col0 + rr) * K + cs * 8, &Bs[0][gg * 8 * 64]);
    }
    for (int kt = 0; kt < nk; ++kt) {
        __syncthreads();                       // drains DMA for buf(kt&1)
        int buf = kt & 1;
        if (kt < nk - 1) {                     // DMA next tile into other buf
            int k1 = (kt + 1) << 6;
            int nb = buf ^ 1;
#pragma unroll
            for (int gi = 0; gi < 4; ++gi) {
                int gg = wave * 4 + gi;
                int rr = gg * 8 + sr;
                int cs = (sc - rr) & 7;
                dma16(A  + (long)(row0 + rr) * K + k1 + cs * 8, &As[nb][gg * 8 * 64]);
                dma16(Wt + (long)(col0 + rr) * K + k1 + cs * 8, &Bs[nb][gg * 8 * 64]);
            }
        }
#pragma unroll
        for (int ks8 = 0; ks8 < 8; ks8 += 4) {
            bf16x8 af[4], bfr[4];
#pragma unroll
            for (int i = 0; i < 4; ++i) {
                int rr = wr + i * 16 + l16;
                af[i] = *(const bf16x8*)&As[buf][rr * 64 + (((quad + ks8) + rr) & 7) * 8];
            }
#pragma unroll
            for (int j = 0; j < 4; ++j) {
                int rr = wc + j * 16 + l16;
                bfr[j] = *(const bf16x8*)&Bs[buf][rr * 64 + (((quad + ks8) + rr) & 7) * 8];
            }
#pragma unroll
            for (int i = 0; i < 4; ++i)
#pragma unroll
                for (int j = 0; j < 4; ++j)
                    acc[i][j] = __builtin_amdgcn_mfma_f32_16x16x32_bf16(af[i], bfr[j], acc[i][j], 0, 0, 0);
        }
    }
#pragma unroll
    for (int i = 0; i < 4; ++i) {
#pragma unroll
        for (int j = 0; j < 4; ++j) {
            int col = col0 + wc + j * 16 + l16;
#pragma unroll
            for (int r = 0; r < 4; ++r) {
                int m = row0 + wr + i * 16 + quad * 4 + r;
                if (m >= M) continue;
                float v = acc[i][j][r] + bias[col];
                if (act == 1) v = 0.5f * v * (1.0f + erff(v * 0.70710678118f));
                bf16 bvv = __float2bfloat16(v);
                outB[(long)m * N + col] = bvv;
                if (vTout && col >= 512) {   // V cols -> vT[bh][d][key]
                    int b2 = m / S_;
                    int key = m - b2 * S_;
                    int cc = col - 512;
                    vTout[((long)(b2 * 8 + (cc >> 5)) * 32 + (cc & 31)) * SP_ + key] = bvv;
                }
            }
        }
    }
}

// ---- bf16 MFMA GEMM 64x64 tile, DMA staging + double buffer ---------------
__global__ __launch_bounds__(256) void gemm_bf16(
    const bf16* __restrict__ A, const bf16* __restrict__ Wt,
    const float* __restrict__ bias, const float* __restrict__ res,
    float* __restrict__ outF, bf16* __restrict__ outB,
    int M, int K, int N, int act)
{
    __shared__ bf16 As[2][64 * 64];    // 2 x 8 KB
    __shared__ bf16 Bs[2][64 * 64];    // 2 x 8 KB
    int tid = threadIdx.x;
    int wave = tid >> 6, lane = tid & 63;
    int quad = lane >> 4, l16 = lane & 15;
    int row0 = blockIdx.y * 64;
    int col0 = blockIdx.x * 64;

    int sr = lane >> 3;
    int sc = lane & 7;

    f32x4 acc[4] = {{0.f,0.f,0.f,0.f},{0.f,0.f,0.f,0.f},{0.f,0.f,0.f,0.f},{0.f,0.f,0.f,0.f}};
    int nk = K >> 6;

    // prologue: DMA tile 0 into buffer 0
#pragma unroll
    for (int gi = 0; gi < 4; ++gi) {
        int id = wave * 4 + gi;           // 0..15
        int rr = (id & 7) * 8 + sr;
        int cs = (sc - rr) & 7;
        if (id < 8) dma16(A  + (long)(row0 + rr) * K + cs * 8, &As[0][(id & 7) * 8 * 64]);
        else        dma16(Wt + (long)(col0 + rr) * K + cs * 8, &Bs[0][(id & 7) * 8 * 64]);
    }
    for (int kt = 0; kt < nk; ++kt) {
        __syncthreads();
        int buf = kt & 1;
        if (kt < nk - 1) {
            int k1 = (kt + 1) << 6;
            int nb = buf ^ 1;
#pragma unroll
            for (int gi = 0; gi < 4; ++gi) {
                int id = wave * 4 + gi;
                int rr = (id & 7) * 8 + sr;
                int cs = (sc - rr) & 7;
                if (id < 8) dma16(A  + (long)(row0 + rr) * K + k1 + cs * 8, &As[nb][(id & 7) * 8 * 64]);
                else        dma16(Wt + (long)(col0 + rr) * K + k1 + cs * 8, &Bs[nb][(id & 7) * 8 * 64]);
            }
        }
#pragma unroll
        for (int ks8 = 0; ks8 < 8; ks8 += 4) {
            int rra = wave * 16 + l16;
            bf16x8 af = *(const bf16x8*)&As[buf][rra * 64 + (((quad + ks8) + rra) & 7) * 8];
#pragma unroll
            for (int nt = 0; nt < 4; ++nt) {
                int rrb = nt * 16 + l16;
                bf16x8 bf = *(const bf16x8*)&Bs[buf][rrb * 64 + (((quad + ks8) + rrb) & 7) * 8];
                acc[nt] = __builtin_amdgcn_mfma_f32_16x16x32_bf16(af, bf, acc[nt], 0, 0, 0);
            }
        }
    }
#pragma unroll
    for (int nt = 0; nt < 4; ++nt) {
        int col = col0 + nt * 16 + l16;
#pragma unroll
        for (int r = 0; r < 4; ++r) {
            int m = row0 + wave * 16 + quad * 4 + r;
            if (m >= M) continue;
            float v = acc[nt][r] + bias[col];
            if (act == 1) v = 0.5f * v * (1.0f + erff(v * 0.70710678118f));
            if (res)  v += res[(long)m * N + col];
            if (outF) outF[(long)m * N + col] = v;
            if (outB) outB[(long)m * N + col] = __float2bfloat16(v);
        }
    }
}

// --------------- MFMA flash attention v5: conflict-free P ------------------
// 128-query tiles, dbuf K/V. P stride 72 (bank-uniform); P written as packed
// uint (2x bf16) by even lanes (one shfl_xor per pair). No score clamp
// (scores O(10) here; masked tail still zeroes invalid keys).
#define NQT4 9   // ceil(S_/128)
__global__ __launch_bounds__(256) void attn_mfma5_kernel(
    const bf16* __restrict__ qkv, const bf16* __restrict__ vT,
    bf16* __restrict__ ob)
{
    __shared__ bf16 Ks[2][64 * 40];    // [key][d], row 80 B
    __shared__ bf16 Vs[2][32 * 80];    // [d][key], row 160 B
    __shared__ bf16 Pa[4][32 * 72];    // per-wave P [q][key], row 144 B

    int tid = threadIdx.x;
    int wave = tid >> 6, lane = tid & 63;
    int quad = lane >> 4, l16 = lane & 15;
    int bh = blockIdx.x / NQT4, qt = blockIdx.x % NQT4;
    int b = bh >> 3, hh = bh & 7;
    int q0 = qt * 128;
    long bS = (long)b * S_;
    bf16* Pw = Pa[wave];
    const bf16* vTb = vT + (long)bh * 32 * SP_;
    uint4 z4 = make_uint4(0,0,0,0);
    bool even = (l16 & 1) == 0;

    int skey = tid >> 2, sdg = tid & 3;
    int svd = tid >> 3, svc = tid & 7;

    bf16x8 aq[2];
#pragma unroll
    for (int f = 0; f < 2; ++f) {
        bf16x8 a = {0,0,0,0,0,0,0,0};
        int gq = q0 + wave * 32 + f * 16 + l16;
        if (gq < S_) a = *(const bf16x8*)(qkv + (bS + gq) * 768 + hh * 32 + quad * 8);
        aq[f] = a;
    }

    f32x4 o00 = {0.f,0.f,0.f,0.f}, o01 = {0.f,0.f,0.f,0.f};
    f32x4 o10 = {0.f,0.f,0.f,0.f}, o11 = {0.f,0.f,0.f,0.f};
    float lsum[2][4] = {{0.f,0.f,0.f,0.f},{0.f,0.f,0.f,0.f}};
    f32x4 zf = {0.f,0.f,0.f,0.f};

    {   // prologue: stage tile 0
        int gk = skey;
        uint4 kv = z4;
        if (gk < S_) kv = *(const uint4*)(qkv + (bS + gk) * 768 + 256 + hh * 32 + sdg * 8);
        *(uint4*)&Ks[0][skey * 40 + sdg * 8] = kv;
        *(uint4*)&Vs[0][svd * 80 + svc * 8] = *(const uint4*)(vTb + (long)svd * SP_ + svc * 8);
    }

    for (int kt = 0; kt < 17; ++kt) {
        int j0 = kt * 64;
        int bb = kt & 1;
        __syncthreads();

        if (kt < 16) {
            int j1 = j0 + 64;
            int gk = j1 + skey;
            uint4 kv = z4;
            if (gk < S_) kv = *(const uint4*)(qkv + (bS + gk) * 768 + 256 + hh * 32 + sdg * 8);
            *(uint4*)&Ks[bb ^ 1][skey * 40 + sdg * 8] = kv;
            *(uint4*)&Vs[bb ^ 1][svd * 80 + svc * 8] =
                *(const uint4*)(vTb + (long)svd * SP_ + j1 + svc * 8);
        }

        bf16x8 bk[4];
#pragma unroll
        for (int t4 = 0; t4 < 4; ++t4)
            bk[t4] = *(const bf16x8*)&Ks[bb][(t4 * 16 + l16) * 40 + quad * 8];

#pragma unroll
        for (int f = 0; f < 2; ++f) {
            f32x4 sc[4];
#pragma unroll
            for (int t4 = 0; t4 < 4; ++t4)
                sc[t4] = __builtin_amdgcn_mfma_f32_16x16x32_bf16(aq[f], bk[t4], zf, 0, 0, 0);
            if (kt < 16) {               // full tile: no validity masking
#pragma unroll
                for (int t4 = 0; t4 < 4; ++t4)
#pragma unroll
                    for (int r = 0; r < 4; ++r) {
                        float p = __expf(sc[t4][r]);
                        lsum[f][r] += p;
                        float ph = __shfl_xor(p, 1);     // neighbor key's p
                        if (even) {
                            unsigned u = (unsigned)(unsigned short)__bfloat16_as_ushort(__float2bfloat16(p))
                                       | ((unsigned)(unsigned short)__bfloat16_as_ushort(__float2bfloat16(ph)) << 16);
                            *(unsigned*)&Pw[(f * 16 + quad * 4 + r) * 72 + t4 * 16 + l16] = u;
                        }
                    }
            } else {                     // masked tail tile
#pragma unroll
                for (int t4 = 0; t4 < 4; ++t4) {
                    bool valid = (j0 + t4 * 16 + l16) < S_;
#pragma unroll
                    for (int r = 0; r < 4; ++r) {
                        float p = valid ? __expf(sc[t4][r]) : 0.f;
                        lsum[f][r] += p;
                        float ph = __shfl_xor(p, 1);
                        if (even) {
                            unsigned u = (unsigned)(unsigned short)__bfloat16_as_ushort(__float2bfloat16(p))
                                       | ((unsigned)(unsigned short)__bfloat16_as_ushort(__float2bfloat16(ph)) << 16);
                            *(unsigned*)&Pw[(f * 16 + quad * 4 + r) * 72 + t4 * 16 + l16] = u;
                        }
                    }
                }
            }
        }
#pragma unroll
        for (int ks2 = 0; ks2 < 64; ks2 += 32) {
            bf16x8 bv0 = *(const bf16x8*)&Vs[bb][l16 * 80 + ks2 + quad * 8];
            bf16x8 bv1 = *(const bf16x8*)&Vs[bb][(16 + l16) * 80 + ks2 + quad * 8];
            bf16x8 ap0 = *(const bf16x8*)&Pw[l16 * 72 + ks2 + quad * 8];
            bf16x8 ap1 = *(const bf16x8*)&Pw[(16 + l16) * 72 + ks2 + quad * 8];
            o00 = __builtin_amdgcn_mfma_f32_16x16x32_bf16(ap0, bv0, o00, 0, 0, 0);
            o01 = __builtin_amdgcn_mfma_f32_16x16x32_bf16(ap0, bv1, o01, 0, 0, 0);
            o10 = __builtin_amdgcn_mfma_f32_16x16x32_bf16(ap1, bv0, o10, 0, 0, 0);
            o11 = __builtin_amdgcn_mfma_f32_16x16x32_bf16(ap1, bv1, o11, 0, 0, 0);
        }
    }

#pragma unroll
    for (int f = 0; f < 2; ++f) {
        f32x4 oa = f ? o10 : o00;
        f32x4 obv = f ? o11 : o01;
#pragma unroll
        for (int r = 0; r < 4; ++r) {
            float t = lsum[f][r];
            t += __shfl_xor(t, 1); t += __shfl_xor(t, 2);
            t += __shfl_xor(t, 4); t += __shfl_xor(t, 8);
            float inv = 1.0f / (t * 16.0f);
            int gq = q0 + wave * 32 + f * 16 + quad * 4 + r;
            if (gq < S_) {
                long base = (bS + gq) * 256 + hh * 32;
                ob[base + l16]      = __float2bfloat16(oa[r] * inv);
                ob[base + 16 + l16] = __float2bfloat16(obv[r] * inv);
            }
        }
    }
}

// --------------- Pool: partial[b][sc][e] = sum over 65-row chunk -----------
__global__ __launch_bounds__(256) void pool_kernel(const float* __restrict__ h,
                                                   float* __restrict__ partial)
{
    int b = blockIdx.x >> 4, sc = blockIdx.x & 15;
    int e = threadIdx.x;
    int s0 = sc * 65, s1 = min(S_, s0 + 65);
    float acc = 0.f;
    for (int s = s0; s < s1; ++s) acc += h[((long)b * S_ + s) * E_ + e];
    partial[((long)b * 16 + sc) * E_ + e] = acc;
}

// --------------- Classifier final: Linear -> LN -> Linear -----------------
__global__ __launch_bounds__(256) void cls_final(
    const float* __restrict__ partial, const float* __restrict__ Wc1,
    const float* __restrict__ bc1, const float* __restrict__ lg,
    const float* __restrict__ lb, const float* __restrict__ Wc2,
    const float* __restrict__ bc2, float* __restrict__ out)
{
    int b = blockIdx.x;
    int e = threadIdx.x;
    __shared__ float p[256];
    __shared__ float red[256];
    __shared__ float lnv[256];

    float acc = 0.f;
#pragma unroll
    for (int sc = 0; sc < 16; ++sc) acc += partial[((long)b * 16 + sc) * E_ + e];
    p[e] = acc * (1.0f / S_);
    __syncthreads();

    float c1 = bc1[e];
    for (int kk = 0; kk < E_; ++kk) c1 += p[kk] * Wc1[kk * E_ + e];

    red[e] = c1; __syncthreads();
    for (int st = 128; st; st >>= 1) { if (e < st) red[e] += red[e + st]; __syncthreads(); }
    float mean = red[0] * (1.0f / E_); __syncthreads();
    float d = c1 - mean;
    red[e] = d * d; __syncthreads();
    for (int st = 128; st; st >>= 1) { if (e < st) red[e] += red[e + st]; __syncthreads(); }
    float var = red[0] * (1.0f / E_);
    lnv[e] = d * rsqrtf(var + EPS_) * lg[e] + lb[e];
    __syncthreads();

    if (e < NC_) {
        float oacc = bc2[e];
        for (int kk = 0; kk < E_; ++kk) oacc += lnv[kk] * Wc2[kk * NC_ + e];
        out[b * NC_ + e] = oacc;
    }
}

extern "C" void kernel_launch(void* const* d_in, const int* in_sizes, int n_in,
                              void* d_out, int out_size, void* d_ws, size_t ws_size,
                              hipStream_t stream)
{
    const float* x      = (const float*)d_in[0];
    const float* W_emb  = (const float*)d_in[1];
    const float* b_emb  = (const float*)d_in[2];
    const float* g_emb  = (const float*)d_in[3];
    const float* be_emb = (const float*)d_in[4];
    const float* cls    = (const float*)d_in[5];
    const float* pos    = (const float*)d_in[6];
    const float* ln1_g  = (const float*)d_in[7];
    const float* ln1_b  = (const float*)d_in[8];
    const float* Wq     = (const float*)d_in[9];
    const float* bq     = (const float*)d_in[10];
    const float* Wk     = (const float*)d_in[11];
    const float* bk     = (const float*)d_in[12];
    const float* Wv     = (const float*)d_in[13];
    const float* bv     = (const float*)d_in[14];
    const float* Wo     = (const float*)d_in[15];
    const float* bo     = (const float*)d_in[16];
    const float* ln2_g  = (const float*)d_in[17];
    const float* ln2_b  = (const float*)d_in[18];
    const float* W1     = (const float*)d_in[19];
    const float* b1     = (const float*)d_in[20];
    const float* W2     = (const float*)d_in[21];
    const float* b2     = (const float*)d_in[22];
    const float* Wc1    = (const float*)d_in[23];
    const float* bc1    = (const float*)d_in[24];
    const float* lnc_g  = (const float*)d_in[25];
    const float* lnc_b  = (const float*)d_in[26];
    const float* Wc2    = (const float*)d_in[27];
    const float* bc2    = (const float*)d_in[28];
    float* out = (float*)d_out;

    char* p = (char*)d_ws;
    float* h    = (float*)p; p += (long)M_ * 256 * 4;
    bf16* y     = (bf16*)p;  p += (long)M_ * 256 * 2;
    bf16* qkv   = (bf16*)p;  p += (long)M_ * 768 * 2;
    bf16* obuf  = (bf16*)p;  p += (long)M_ * 256 * 2;
    bf16* tb    = (bf16*)p;  p += (long)M_ * 1024 * 2;
    bf16* Wqkvt = (bf16*)p;  p += (long)L_ * 768 * 256 * 2;
    bf16* Wot   = (bf16*)p;  p += (long)L_ * 256 * 256 * 2;
    bf16* W1t   = (bf16*)p;  p += (long)L_ * 1024 * 256 * 2;
    bf16* W2t   = (bf16*)p;  p += (long)L_ * 256 * 1024 * 2;
    float* bqkv = (float*)p; p += (long)L_ * 768 * 4;
    float* pool = (float*)p; p += (long)B_ * 16 * 256 * 4;
    bf16* vT    = (bf16*)p;  p += (long)64 * 32 * SP_ * 2;

    // ---- weight packing (1 launch) ----
    pack_all<<<3072, 256, 0, stream>>>(Wq, Wk, Wv, bq, bk, bv, Wo, W1, W2,
                                       Wqkvt, bqkv, Wot, W1t, W2t);

    embed4_kernel<<<M_ / 4, 256, 0, stream>>>(x, W_emb, b_emb, g_emb, be_emb, cls, h);

    dim3 gQKV(6, 65), gMLP1(8, 65), gEE(4, 129);
    for (int l = 0; l < L_; ++l) {
        // h += pos; y = LN1(h)
        ln4_kernel<<<M_ / 4, 256, 0, stream>>>(h, pos, ln1_g + l * E_, ln1_b + l * E_, y);
        // qkv = y @ Wqkv + b (V cols also -> vT, transposed)
        gemm_bf16_128<<<gQKV, 256, 0, stream>>>(y, Wqkvt + (long)l * 768 * 256, bqkv + l * 768,
                                                qkv, vT, M_, 256, 768, 0);
        attn_mfma5_kernel<<<64 * NQT4, 256, 0, stream>>>(qkv, vT, obuf);
        // h += o @ Wo + bo
        gemm_bf16<<<gEE, 256, 0, stream>>>(obuf, Wot + (long)l * 65536, bo + l * E_,
                                           h, h, nullptr, M_, 256, 256, 0);
        // y = LN2(h); tb = GELU(y @ W1 + b1)
        ln4_kernel<<<M_ / 4, 256, 0, stream>>>(h, nullptr, ln2_g + l * E_, ln2_b + l * E_, y);
        gemm_bf16_128<<<gMLP1, 256, 0, stream>>>(y, W1t + (long)l * 262144, b1 + l * XE_,
                                                 tb, nullptr, M_, 256, 1024, 1);
        // h += tb @ W2 + b2
        gemm_bf16<<<gEE, 256, 0, stream>>>(tb, W2t + (long)l * 262144, b2 + l * E_,
                                           h, h, nullptr, M_, 1024, 256, 0);
    }

    pool_kernel<<<B_ * 16, 256, 0, stream>>>(h, pool);
    cls_final<<<B_, 256, 0, stream>>>(pool, Wc1, bc1, lnc_g, lnc_b, Wc2, bc2, out);
}

// Round 17
// 721.054 us; speedup vs baseline: 1.1388x; 1.1388x over previous
//
#include <hip/hip_runtime.h>
#include <hip/hip_bf16.h>
#include <math.h>

// Problem constants
#define B_  8
#define N_  1024
#define C_  12
#define E_  256
#define H_  8
#define D_  32      // E/H
#define L_  4
#define XE_ 1024    // X*E
#define NC_ 5
#define S_  1025    // N+1
#define M_  8200    // B*S
#define EPS_ 1e-5f
#define SP_ 1088    // padded key-stride for vT (17*64, 16B-aligned)

typedef short bf16x8 __attribute__((ext_vector_type(8)));
typedef float f32x4 __attribute__((ext_vector_type(4)));
typedef __hip_bfloat16 bf16;

// async global->LDS DMA, 16 B per lane; LDS dest = wave-uniform base + lane*16
typedef __attribute__((address_space(1))) const unsigned int* as1_cuint;
typedef __attribute__((address_space(3))) unsigned int* as3_uint;
__device__ __forceinline__ void dma16(const void* g, void* l) {
    __builtin_amdgcn_global_load_lds((as1_cuint)g, (as3_uint)l, 16, 0, 0);
}

// ---------------- Embedding (wave per token): x@W+b -> LN -> GELU ----------
__global__ __launch_bounds__(256) void embed4_kernel(
    const float* __restrict__ x, const float* __restrict__ Wemb,
    const float* __restrict__ bemb, const float* __restrict__ g,
    const float* __restrict__ be, const float* __restrict__ cls,
    float* __restrict__ h)
{
    int wave = threadIdx.x >> 6, lane = threadIdx.x & 63;
    int t = blockIdx.x * 4 + wave;          // M_ = 4*2050 exactly
    int b = t / S_, s = t % S_;
    long base = (long)t * E_ + lane * 4;

    if (s == 0) {
        *(float4*)(h + base) = *(const float4*)(cls + lane * 4);
        return;
    }
    const float* xr = x + ((long)b * N_ + (s - 1)) * C_;
    float xv[C_];
#pragma unroll
    for (int c = 0; c < C_; ++c) xv[c] = xr[c];

    float4 acc = *(const float4*)(bemb + lane * 4);
#pragma unroll
    for (int c = 0; c < C_; ++c) {
        float4 w = *(const float4*)(Wemb + c * E_ + lane * 4);
        acc.x += xv[c] * w.x; acc.y += xv[c] * w.y;
        acc.z += xv[c] * w.z; acc.w += xv[c] * w.w;
    }
    float sum = acc.x + acc.y + acc.z + acc.w;
    float sq  = acc.x*acc.x + acc.y*acc.y + acc.z*acc.z + acc.w*acc.w;
#pragma unroll
    for (int off = 1; off < 64; off <<= 1) {
        sum += __shfl_xor(sum, off);
        sq  += __shfl_xor(sq,  off);
    }
    float mean = sum * (1.0f / E_);
    float var  = sq * (1.0f / E_) - mean * mean;
    float rstd = rsqrtf(var + EPS_);
    float4 gg = *(const float4*)(g + lane * 4);
    float4 bb = *(const float4*)(be + lane * 4);
    float4 o;
    float v;
    v = (acc.x - mean) * rstd * gg.x + bb.x; o.x = 0.5f * v * (1.0f + erff(v * 0.70710678118f));
    v = (acc.y - mean) * rstd * gg.y + bb.y; o.y = 0.5f * v * (1.0f + erff(v * 0.70710678118f));
    v = (acc.z - mean) * rstd * gg.z + bb.z; o.z = 0.5f * v * (1.0f + erff(v * 0.70710678118f));
    v = (acc.w - mean) * rstd * gg.w + bb.w; o.w = 0.5f * v * (1.0f + erff(v * 0.70710678118f));
    *(float4*)(h + base) = o;
}

// ------------- LN (wave per token): optional h+=pos, y=bf16(LN(h)) ---------
__global__ __launch_bounds__(256) void ln4_kernel(
    float* __restrict__ h, const float* __restrict__ pos,
    const float* __restrict__ g, const float* __restrict__ bb,
    bf16* __restrict__ y)
{
    int wave = threadIdx.x >> 6, lane = threadIdx.x & 63;
    int t = blockIdx.x * 4 + wave;
    int s = t % S_;
    long base = (long)t * E_ + lane * 4;

    float4 v = *(const float4*)(h + base);
    if (pos) {
        float4 pv = *(const float4*)(pos + (long)s * E_ + lane * 4);
        v.x += pv.x; v.y += pv.y; v.z += pv.z; v.w += pv.w;
        *(float4*)(h + base) = v;
    }
    float sum = v.x + v.y + v.z + v.w;
    float sq  = v.x*v.x + v.y*v.y + v.z*v.z + v.w*v.w;
#pragma unroll
    for (int off = 1; off < 64; off <<= 1) {
        sum += __shfl_xor(sum, off);
        sq  += __shfl_xor(sq,  off);
    }
    float mean = sum * (1.0f / E_);
    float var  = sq * (1.0f / E_) - mean * mean;
    float rstd = rsqrtf(var + EPS_);
    float4 gg = *(const float4*)(g + lane * 4);
    float4 b4 = *(const float4*)(bb + lane * 4);
    bf16 o[4];
    o[0] = __float2bfloat16((v.x - mean) * rstd * gg.x + b4.x);
    o[1] = __float2bfloat16((v.y - mean) * rstd * gg.y + b4.y);
    o[2] = __float2bfloat16((v.z - mean) * rstd * gg.z + b4.z);
    o[3] = __float2bfloat16((v.w - mean) * rstd * gg.w + b4.w);
    *(uint2*)(y + base) = *(uint2*)o;
}

// ---------- Single-launch weight pack (LDS 32x32 transpose) ----------------
__global__ __launch_bounds__(256) void pack_all(
    const float* __restrict__ Wq, const float* __restrict__ Wk,
    const float* __restrict__ Wv, const float* __restrict__ bq,
    const float* __restrict__ bk, const float* __restrict__ bv,
    const float* __restrict__ Wo, const float* __restrict__ W1,
    const float* __restrict__ W2,
    bf16* __restrict__ Wqkvt, float* __restrict__ bqkv,
    bf16* __restrict__ Wot, bf16* __restrict__ W1t, bf16* __restrict__ W2t)
{
    __shared__ float tile[32][33];
    int id = blockIdx.x;
    int tx = threadIdx.x & 31, ty = threadIdx.x >> 5;   // 32x8
    const float* src; bf16* dst;
    int c0, k0, Nsrc, Kd, row0;

    if (id < 768) {                       // QKV: 4l x 8k x 24n
        int l = id / 192, r = id % 192;
        int nt = r % 24, kt2 = r / 24;
        int n0 = nt * 32; k0 = kt2 * 32;
        Nsrc = 256; Kd = 256; row0 = n0;
        if (n0 < 256)      { src = Wq + (long)l * 65536; c0 = n0; }
        else if (n0 < 512) { src = Wk + (long)l * 65536; c0 = n0 - 256; }
        else               { src = Wv + (long)l * 65536; c0 = n0 - 512; }
        dst = Wqkvt + (long)l * 768 * 256;
        if (kt2 == 0 && ty == 0) {
            const float* bsrc = (n0 < 256) ? bq + l * 256 + c0
                              : (n0 < 512) ? bk + l * 256 + c0 : bv + l * 256 + c0;
            bqkv[l * 768 + n0 + tx] = bsrc[tx];
        }
    } else if (id < 1024) {               // Wo
        int r = id - 768; int l = r / 64; r %= 64;
        int nt = r & 7, kt2 = r >> 3;
        c0 = nt * 32; k0 = kt2 * 32; Nsrc = 256; Kd = 256; row0 = c0;
        src = Wo + (long)l * 65536; dst = Wot + (long)l * 65536;
    } else if (id < 2048) {               // W1
        int r = id - 1024; int l = r / 256; r %= 256;
        int nt = r % 32, kt2 = r / 32;
        c0 = nt * 32; k0 = kt2 * 32; Nsrc = 1024; Kd = 256; row0 = c0;
        src = W1 + (long)l * 262144; dst = W1t + (long)l * 262144;
    } else {                              // W2
        int r = id - 2048; int l = r / 256; r %= 256;
        int nt = r & 7, kt2 = r >> 3;
        c0 = nt * 32; k0 = kt2 * 32; Nsrc = 256; Kd = 1024; row0 = c0;
        src = W2 + (long)l * 262144; dst = W2t + (long)l * 262144;
    }
#pragma unroll
    for (int i = 0; i < 4; ++i)
        tile[ty + i * 8][tx] = src[(long)(k0 + ty + i * 8) * Nsrc + c0 + tx];
    __syncthreads();
#pragma unroll
    for (int i = 0; i < 4; ++i)
        dst[(long)(row0 + ty + i * 8) * Kd + k0 + tx] = __float2bfloat16(tile[tx][ty + i * 8]);
}

// ---- bf16 MFMA GEMM 128x128 tile, DMA staging + double buffer -------------
__global__ __launch_bounds__(256) void gemm_bf16_128(
    const bf16* __restrict__ A, const bf16* __restrict__ Wt,
    const float* __restrict__ bias,
    bf16* __restrict__ outB, bf16* __restrict__ vTout,
    int M, int K, int N, int act)
{
    __shared__ bf16 As[2][128 * 64];   // 2 x 16 KB
    __shared__ bf16 Bs[2][128 * 64];   // 2 x 16 KB
    int tid = threadIdx.x;
    int wave = tid >> 6, lane = tid & 63;
    int quad = lane >> 4, l16 = lane & 15;
    int wr = (wave >> 1) * 64, wc = (wave & 1) * 64;
    int row0 = blockIdx.y * 128;
    int col0 = blockIdx.x * 128;

    int sr = lane >> 3;       // row within 8-row DMA group
    int sc = lane & 7;        // 16-B chunk within row

    f32x4 acc[4][4];
#pragma unroll
    for (int i = 0; i < 4; ++i)
#pragma unroll
        for (int j = 0; j < 4; ++j) acc[i][j] = (f32x4){0.f,0.f,0.f,0.f};

    int nk = K >> 6;
    // prologue: DMA tile 0 into buffer 0
#pragma unroll
    for (int gi = 0; gi < 4; ++gi) {
        int gg = wave * 4 + gi;
        int rr = gg * 8 + sr;
        int cs = (sc - rr) & 7;
        dma16(A  + (long)(row0 + rr) * K + cs * 8, &As[0][gg * 8 * 64]);
        dma16(Wt + (long)(col0 + rr) * K + cs * 8, &Bs[0][gg * 8 * 64]);
    }
    for (int kt = 0; kt < nk; ++kt) {
        __syncthreads();                       // drains DMA for buf(kt&1)
        int buf = kt & 1;
        if (kt < nk - 1) {                     // DMA next tile into other buf
            int k1 = (kt + 1) << 6;
            int nb = buf ^ 1;
#pragma unroll
            for (int gi = 0; gi < 4; ++gi) {
                int gg = wave * 4 + gi;
                int rr = gg * 8 + sr;
                int cs = (sc - rr) & 7;
                dma16(A  + (long)(row0 + rr) * K + k1 + cs * 8, &As[nb][gg * 8 * 64]);
                dma16(Wt + (long)(col0 + rr) * K + k1 + cs * 8, &Bs[nb][gg * 8 * 64]);
            }
        }
#pragma unroll
        for (int ks8 = 0; ks8 < 8; ks8 += 4) {
            bf16x8 af[4], bfr[4];
#pragma unroll
            for (int i = 0; i < 4; ++i) {
                int rr = wr + i * 16 + l16;
                af[i] = *(const bf16x8*)&As[buf][rr * 64 + (((quad + ks8) + rr) & 7) * 8];
            }
#pragma unroll
            for (int j = 0; j < 4; ++j) {
                int rr = wc + j * 16 + l16;
                bfr[j] = *(const bf16x8*)&Bs[buf][rr * 64 + (((quad + ks8) + rr) & 7) * 8];
            }
#pragma unroll
            for (int i = 0; i < 4; ++i)
#pragma unroll
                for (int j = 0; j < 4; ++j)
                    acc[i][j] = __builtin_amdgcn_mfma_f32_16x16x32_bf16(af[i], bfr[j], acc[i][j], 0, 0, 0);
        }
    }
#pragma unroll
    for (int i = 0; i < 4; ++i) {
#pragma unroll
        for (int j = 0; j < 4; ++j) {
            int col = col0 + wc + j * 16 + l16;
#pragma unroll
            for (int r = 0; r < 4; ++r) {
                int m = row0 + wr + i * 16 + quad * 4 + r;
                if (m >= M) continue;
                float v = acc[i][j][r] + bias[col];
                if (act == 1) v = 0.5f * v * (1.0f + erff(v * 0.70710678118f));
                bf16 bvv = __float2bfloat16(v);
                outB[(long)m * N + col] = bvv;
                if (vTout && col >= 512) {   // V cols -> vT[bh][d][key]
                    int b2 = m / S_;
                    int key = m - b2 * S_;
                    int cc = col - 512;
                    vTout[((long)(b2 * 8 + (cc >> 5)) * 32 + (cc & 31)) * SP_ + key] = bvv;
                }
            }
        }
    }
}

// ---- bf16 MFMA GEMM 64x64 tile, DMA staging + double buffer ---------------
__global__ __launch_bounds__(256) void gemm_bf16(
    const bf16* __restrict__ A, const bf16* __restrict__ Wt,
    const float* __restrict__ bias, const float* __restrict__ res,
    float* __restrict__ outF, bf16* __restrict__ outB,
    int M, int K, int N, int act)
{
    __shared__ bf16 As[2][64 * 64];    // 2 x 8 KB
    __shared__ bf16 Bs[2][64 * 64];    // 2 x 8 KB
    int tid = threadIdx.x;
    int wave = tid >> 6, lane = tid & 63;
    int quad = lane >> 4, l16 = lane & 15;
    int row0 = blockIdx.y * 64;
    int col0 = blockIdx.x * 64;

    int sr = lane >> 3;
    int sc = lane & 7;

    f32x4 acc[4] = {{0.f,0.f,0.f,0.f},{0.f,0.f,0.f,0.f},{0.f,0.f,0.f,0.f},{0.f,0.f,0.f,0.f}};
    int nk = K >> 6;

    // prologue: DMA tile 0 into buffer 0
#pragma unroll
    for (int gi = 0; gi < 4; ++gi) {
        int id = wave * 4 + gi;           // 0..15
        int rr = (id & 7) * 8 + sr;
        int cs = (sc - rr) & 7;
        if (id < 8) dma16(A  + (long)(row0 + rr) * K + cs * 8, &As[0][(id & 7) * 8 * 64]);
        else        dma16(Wt + (long)(col0 + rr) * K + cs * 8, &Bs[0][(id & 7) * 8 * 64]);
    }
    for (int kt = 0; kt < nk; ++kt) {
        __syncthreads();
        int buf = kt & 1;
        if (kt < nk - 1) {
            int k1 = (kt + 1) << 6;
            int nb = buf ^ 1;
#pragma unroll
            for (int gi = 0; gi < 4; ++gi) {
                int id = wave * 4 + gi;
                int rr = (id & 7) * 8 + sr;
                int cs = (sc - rr) & 7;
                if (id < 8) dma16(A  + (long)(row0 + rr) * K + k1 + cs * 8, &As[nb][(id & 7) * 8 * 64]);
                else        dma16(Wt + (long)(col0 + rr) * K + k1 + cs * 8, &Bs[nb][(id & 7) * 8 * 64]);
            }
        }
#pragma unroll
        for (int ks8 = 0; ks8 < 8; ks8 += 4) {
            int rra = wave * 16 + l16;
            bf16x8 af = *(const bf16x8*)&As[buf][rra * 64 + (((quad + ks8) + rra) & 7) * 8];
#pragma unroll
            for (int nt = 0; nt < 4; ++nt) {
                int rrb = nt * 16 + l16;
                bf16x8 bf = *(const bf16x8*)&Bs[buf][rrb * 64 + (((quad + ks8) + rrb) & 7) * 8];
                acc[nt] = __builtin_amdgcn_mfma_f32_16x16x32_bf16(af, bf, acc[nt], 0, 0, 0);
            }
        }
    }
#pragma unroll
    for (int nt = 0; nt < 4; ++nt) {
        int col = col0 + nt * 16 + l16;
#pragma unroll
        for (int r = 0; r < 4; ++r) {
            int m = row0 + wave * 16 + quad * 4 + r;
            if (m >= M) continue;
            float v = acc[nt][r] + bias[col];
            if (act == 1) v = 0.5f * v * (1.0f + erff(v * 0.70710678118f));
            if (res)  v += res[(long)m * N + col];
            if (outF) outF[(long)m * N + col] = v;
            if (outB) outB[(long)m * N + col] = __float2bfloat16(v);
        }
    }
}

// --------------- MFMA flash attention v6 -----------------------------------
// R15 structure (scalar P writes) with Pa stride 80->72 (4-way instead of
// 8-way write aliasing) and no score clamp (validated in R16).
#define NQT4 9   // ceil(S_/128)
__global__ __launch_bounds__(256) void attn_mfma6_kernel(
    const bf16* __restrict__ qkv, const bf16* __restrict__ vT,
    bf16* __restrict__ ob)
{
    __shared__ bf16 Ks[2][64 * 40];    // [key][d], row 80 B
    __shared__ bf16 Vs[2][32 * 80];    // [d][key], row 160 B
    __shared__ bf16 Pa[4][32 * 72];    // per-wave P [q][key], row 144 B

    int tid = threadIdx.x;
    int wave = tid >> 6, lane = tid & 63;
    int quad = lane >> 4, l16 = lane & 15;
    int bh = blockIdx.x / NQT4, qt = blockIdx.x % NQT4;
    int b = bh >> 3, hh = bh & 7;
    int q0 = qt * 128;
    long bS = (long)b * S_;
    bf16* Pw = Pa[wave];
    const bf16* vTb = vT + (long)bh * 32 * SP_;
    uint4 z4 = make_uint4(0,0,0,0);

    int skey = tid >> 2, sdg = tid & 3;
    int svd = tid >> 3, svc = tid & 7;

    bf16x8 aq[2];
#pragma unroll
    for (int f = 0; f < 2; ++f) {
        bf16x8 a = {0,0,0,0,0,0,0,0};
        int gq = q0 + wave * 32 + f * 16 + l16;
        if (gq < S_) a = *(const bf16x8*)(qkv + (bS + gq) * 768 + hh * 32 + quad * 8);
        aq[f] = a;
    }

    f32x4 o00 = {0.f,0.f,0.f,0.f}, o01 = {0.f,0.f,0.f,0.f};
    f32x4 o10 = {0.f,0.f,0.f,0.f}, o11 = {0.f,0.f,0.f,0.f};
    float lsum[2][4] = {{0.f,0.f,0.f,0.f},{0.f,0.f,0.f,0.f}};
    f32x4 zf = {0.f,0.f,0.f,0.f};

    {   // prologue: stage tile 0
        int gk = skey;
        uint4 kv = z4;
        if (gk < S_) kv = *(const uint4*)(qkv + (bS + gk) * 768 + 256 + hh * 32 + sdg * 8);
        *(uint4*)&Ks[0][skey * 40 + sdg * 8] = kv;
        *(uint4*)&Vs[0][svd * 80 + svc * 8] = *(const uint4*)(vTb + (long)svd * SP_ + svc * 8);
    }

    for (int kt = 0; kt < 17; ++kt) {
        int j0 = kt * 64;
        int bb = kt & 1;
        __syncthreads();

        if (kt < 16) {
            int j1 = j0 + 64;
            int gk = j1 + skey;
            uint4 kv = z4;
            if (gk < S_) kv = *(const uint4*)(qkv + (bS + gk) * 768 + 256 + hh * 32 + sdg * 8);
            *(uint4*)&Ks[bb ^ 1][skey * 40 + sdg * 8] = kv;
            *(uint4*)&Vs[bb ^ 1][svd * 80 + svc * 8] =
                *(const uint4*)(vTb + (long)svd * SP_ + j1 + svc * 8);
        }

        bf16x8 bk[4];
#pragma unroll
        for (int t4 = 0; t4 < 4; ++t4)
            bk[t4] = *(const bf16x8*)&Ks[bb][(t4 * 16 + l16) * 40 + quad * 8];

#pragma unroll
        for (int f = 0; f < 2; ++f) {
            f32x4 sc[4];
#pragma unroll
            for (int t4 = 0; t4 < 4; ++t4)
                sc[t4] = __builtin_amdgcn_mfma_f32_16x16x32_bf16(aq[f], bk[t4], zf, 0, 0, 0);
            if (kt < 16) {               // full tile: no validity masking
#pragma unroll
                for (int t4 = 0; t4 < 4; ++t4)
#pragma unroll
                    for (int r = 0; r < 4; ++r) {
                        float p = __expf(sc[t4][r]);
                        lsum[f][r] += p;
                        Pw[(f * 16 + quad * 4 + r) * 72 + t4 * 16 + l16] = __float2bfloat16(p);
                    }
            } else {                     // masked tail tile
#pragma unroll
                for (int t4 = 0; t4 < 4; ++t4) {
                    bool valid = (j0 + t4 * 16 + l16) < S_;
#pragma unroll
                    for (int r = 0; r < 4; ++r) {
                        float p = valid ? __expf(sc[t4][r]) : 0.f;
                        lsum[f][r] += p;
                        Pw[(f * 16 + quad * 4 + r) * 72 + t4 * 16 + l16] = __float2bfloat16(p);
                    }
                }
            }
        }
#pragma unroll
        for (int ks2 = 0; ks2 < 64; ks2 += 32) {
            bf16x8 bv0 = *(const bf16x8*)&Vs[bb][l16 * 80 + ks2 + quad * 8];
            bf16x8 bv1 = *(const bf16x8*)&Vs[bb][(16 + l16) * 80 + ks2 + quad * 8];
            bf16x8 ap0 = *(const bf16x8*)&Pw[l16 * 72 + ks2 + quad * 8];
            bf16x8 ap1 = *(const bf16x8*)&Pw[(16 + l16) * 72 + ks2 + quad * 8];
            o00 = __builtin_amdgcn_mfma_f32_16x16x32_bf16(ap0, bv0, o00, 0, 0, 0);
            o01 = __builtin_amdgcn_mfma_f32_16x16x32_bf16(ap0, bv1, o01, 0, 0, 0);
            o10 = __builtin_amdgcn_mfma_f32_16x16x32_bf16(ap1, bv0, o10, 0, 0, 0);
            o11 = __builtin_amdgcn_mfma_f32_16x16x32_bf16(ap1, bv1, o11, 0, 0, 0);
        }
    }

#pragma unroll
    for (int f = 0; f < 2; ++f) {
        f32x4 oa = f ? o10 : o00;
        f32x4 obv = f ? o11 : o01;
#pragma unroll
        for (int r = 0; r < 4; ++r) {
            float t = lsum[f][r];
            t += __shfl_xor(t, 1); t += __shfl_xor(t, 2);
            t += __shfl_xor(t, 4); t += __shfl_xor(t, 8);
            float inv = 1.0f / (t * 16.0f);
            int gq = q0 + wave * 32 + f * 16 + quad * 4 + r;
            if (gq < S_) {
                long base = (bS + gq) * 256 + hh * 32;
                ob[base + l16]      = __float2bfloat16(oa[r] * inv);
                ob[base + 16 + l16] = __float2bfloat16(obv[r] * inv);
            }
        }
    }
}

// --------------- Pool: partial[b][sc][e] = sum over 65-row chunk -----------
__global__ __launch_bounds__(256) void pool_kernel(const float* __restrict__ h,
                                                   float* __restrict__ partial)
{
    int b = blockIdx.x >> 4, sc = blockIdx.x & 15;
    int e = threadIdx.x;
    int s0 = sc * 65, s1 = min(S_, s0 + 65);
    float acc = 0.f;
    for (int s = s0; s < s1; ++s) acc += h[((long)b * S_ + s) * E_ + e];
    partial[((long)b * 16 + sc) * E_ + e] = acc;
}

// --------------- Classifier final: Linear -> LN -> Linear -----------------
__global__ __launch_bounds__(256) void cls_final(
    const float* __restrict__ partial, const float* __restrict__ Wc1,
    const float* __restrict__ bc1, const float* __restrict__ lg,
    const float* __restrict__ lb, const float* __restrict__ Wc2,
    const float* __restrict__ bc2, float* __restrict__ out)
{
    int b = blockIdx.x;
    int e = threadIdx.x;
    __shared__ float p[256];
    __shared__ float red[256];
    __shared__ float lnv[256];

    float acc = 0.f;
#pragma unroll
    for (int sc = 0; sc < 16; ++sc) acc += partial[((long)b * 16 + sc) * E_ + e];
    p[e] = acc * (1.0f / S_);
    __syncthreads();

    float c1 = bc1[e];
    for (int kk = 0; kk < E_; ++kk) c1 += p[kk] * Wc1[kk * E_ + e];

    red[e] = c1; __syncthreads();
    for (int st = 128; st; st >>= 1) { if (e < st) red[e] += red[e + st]; __syncthreads(); }
    float mean = red[0] * (1.0f / E_); __syncthreads();
    float d = c1 - mean;
    red[e] = d * d; __syncthreads();
    for (int st = 128; st; st >>= 1) { if (e < st) red[e] += red[e + st]; __syncthreads(); }
    float var = red[0] * (1.0f / E_);
    lnv[e] = d * rsqrtf(var + EPS_) * lg[e] + lb[e];
    __syncthreads();

    if (e < NC_) {
        float oacc = bc2[e];
        for (int kk = 0; kk < E_; ++kk) oacc += lnv[kk] * Wc2[kk * NC_ + e];
        out[b * NC_ + e] = oacc;
    }
}

extern "C" void kernel_launch(void* const* d_in, const int* in_sizes, int n_in,
                              void* d_out, int out_size, void* d_ws, size_t ws_size,
                              hipStream_t stream)
{
    const float* x      = (const float*)d_in[0];
    const float* W_emb  = (const float*)d_in[1];
    const float* b_emb  = (const float*)d_in[2];
    const float* g_emb  = (const float*)d_in[3];
    const float* be_emb = (const float*)d_in[4];
    const float* cls    = (const float*)d_in[5];
    const float* pos    = (const float*)d_in[6];
    const float* ln1_g  = (const float*)d_in[7];
    const float* ln1_b  = (const float*)d_in[8];
    const float* Wq     = (const float*)d_in[9];
    const float* bq     = (const float*)d_in[10];
    const float* Wk     = (const float*)d_in[11];
    const float* bk     = (const float*)d_in[12];
    const float* Wv     = (const float*)d_in[13];
    const float* bv     = (const float*)d_in[14];
    const float* Wo     = (const float*)d_in[15];
    const float* bo     = (const float*)d_in[16];
    const float* ln2_g  = (const float*)d_in[17];
    const float* ln2_b  = (const float*)d_in[18];
    const float* W1     = (const float*)d_in[19];
    const float* b1     = (const float*)d_in[20];
    const float* W2     = (const float*)d_in[21];
    const float* b2     = (const float*)d_in[22];
    const float* Wc1    = (const float*)d_in[23];
    const float* bc1    = (const float*)d_in[24];
    const float* lnc_g  = (const float*)d_in[25];
    const float* lnc_b  = (const float*)d_in[26];
    const float* Wc2    = (const float*)d_in[27];
    const float* bc2    = (const float*)d_in[28];
    float* out = (float*)d_out;

    char* p = (char*)d_ws;
    float* h    = (float*)p; p += (long)M_ * 256 * 4;
    bf16* y     = (bf16*)p;  p += (long)M_ * 256 * 2;
    bf16* qkv   = (bf16*)p;  p += (long)M_ * 768 * 2;
    bf16* obuf  = (bf16*)p;  p += (long)M_ * 256 * 2;
    bf16* tb    = (bf16*)p;  p += (long)M_ * 1024 * 2;
    bf16* Wqkvt = (bf16*)p;  p += (long)L_ * 768 * 256 * 2;
    bf16* Wot   = (bf16*)p;  p += (long)L_ * 256 * 256 * 2;
    bf16* W1t   = (bf16*)p;  p += (long)L_ * 1024 * 256 * 2;
    bf16* W2t   = (bf16*)p;  p += (long)L_ * 256 * 1024 * 2;
    float* bqkv = (float*)p; p += (long)L_ * 768 * 4;
    float* pool = (float*)p; p += (long)B_ * 16 * 256 * 4;
    bf16* vT    = (bf16*)p;  p += (long)64 * 32 * SP_ * 2;

    // ---- weight packing (1 launch) ----
    pack_all<<<3072, 256, 0, stream>>>(Wq, Wk, Wv, bq, bk, bv, Wo, W1, W2,
                                       Wqkvt, bqkv, Wot, W1t, W2t);

    embed4_kernel<<<M_ / 4, 256, 0, stream>>>(x, W_emb, b_emb, g_emb, be_emb, cls, h);

    dim3 gQKV(6, 65), gMLP1(8, 65), gEE(4, 129);
    for (int l = 0; l < L_; ++l) {
        // h += pos; y = LN1(h)
        ln4_kernel<<<M_ / 4, 256, 0, stream>>>(h, pos, ln1_g + l * E_, ln1_b + l * E_, y);
        // qkv = y @ Wqkv + b (V cols also -> vT, transposed)
        gemm_bf16_128<<<gQKV, 256, 0, stream>>>(y, Wqkvt + (long)l * 768 * 256, bqkv + l * 768,
                                                qkv, vT, M_, 256, 768, 0);
        attn_mfma6_kernel<<<64 * NQT4, 256, 0, stream>>>(qkv, vT, obuf);
        // h += o @ Wo + bo
        gemm_bf16<<<gEE, 256, 0, stream>>>(obuf, Wot + (long)l * 65536, bo + l * E_,
                                           h, h, nullptr, M_, 256, 256, 0);
        // y = LN2(h); tb = GELU(y @ W1 + b1)
        ln4_kernel<<<M_ / 4, 256, 0, stream>>>(h, nullptr, ln2_g + l * E_, ln2_b + l * E_, y);
        gemm_bf16_128<<<gMLP1, 256, 0, stream>>>(y, W1t + (long)l * 262144, b1 + l * XE_,
                                                 tb, nullptr, M_, 256, 1024, 1);
        // h += tb @ W2 + b2
        gemm_bf16<<<gEE, 256, 0, stream>>>(tb, W2t + (long)l * 262144, b2 + l * E_,
                                           h, h, nullptr, M_, 1024, 256, 0);
    }

    pool_kernel<<<B_ * 16, 256, 0, stream>>>(h, pool);
    cls_final<<<B_, 256, 0, stream>>>(pool, Wc1, bc1, lnc_g, lnc_b, Wc2, bc2, out);
}

// Round 18
// 681.485 us; speedup vs baseline: 1.2050x; 1.0581x over previous
//
#include <hip/hip_runtime.h>
#include <hip/hip_bf16.h>
#include <math.h>

// Problem constants
#define B_  8
#define N_  1024
#define C_  12
#define E_  256
#define H_  8
#define D_  32      // E/H
#define L_  4
#define XE_ 1024    // X*E
#define NC_ 5
#define S_  1025    // N+1
#define M_  8200    // B*S
#define EPS_ 1e-5f
#define SP_ 1088    // padded key-stride for vT (17*64, 16B-aligned)

typedef short bf16x8 __attribute__((ext_vector_type(8)));
typedef float f32x4 __attribute__((ext_vector_type(4)));
typedef __hip_bfloat16 bf16;

// async global->LDS DMA, 16 B per lane; LDS dest = wave-uniform base + lane*16
typedef __attribute__((address_space(1))) const unsigned int* as1_cuint;
typedef __attribute__((address_space(3))) unsigned int* as3_uint;
__device__ __forceinline__ void dma16(const void* g, void* l) {
    __builtin_amdgcn_global_load_lds((as1_cuint)g, (as3_uint)l, 16, 0, 0);
}

// ---------------- Embedding (wave per token): x@W+b -> LN -> GELU ----------
__global__ __launch_bounds__(256) void embed4_kernel(
    const float* __restrict__ x, const float* __restrict__ Wemb,
    const float* __restrict__ bemb, const float* __restrict__ g,
    const float* __restrict__ be, const float* __restrict__ cls,
    float* __restrict__ h)
{
    int wave = threadIdx.x >> 6, lane = threadIdx.x & 63;
    int t = blockIdx.x * 4 + wave;          // M_ = 4*2050 exactly
    int b = t / S_, s = t % S_;
    long base = (long)t * E_ + lane * 4;

    if (s == 0) {
        *(float4*)(h + base) = *(const float4*)(cls + lane * 4);
        return;
    }
    const float* xr = x + ((long)b * N_ + (s - 1)) * C_;
    float xv[C_];
#pragma unroll
    for (int c = 0; c < C_; ++c) xv[c] = xr[c];

    float4 acc = *(const float4*)(bemb + lane * 4);
#pragma unroll
    for (int c = 0; c < C_; ++c) {
        float4 w = *(const float4*)(Wemb + c * E_ + lane * 4);
        acc.x += xv[c] * w.x; acc.y += xv[c] * w.y;
        acc.z += xv[c] * w.z; acc.w += xv[c] * w.w;
    }
    float sum = acc.x + acc.y + acc.z + acc.w;
    float sq  = acc.x*acc.x + acc.y*acc.y + acc.z*acc.z + acc.w*acc.w;
#pragma unroll
    for (int off = 1; off < 64; off <<= 1) {
        sum += __shfl_xor(sum, off);
        sq  += __shfl_xor(sq,  off);
    }
    float mean = sum * (1.0f / E_);
    float var  = sq * (1.0f / E_) - mean * mean;
    float rstd = rsqrtf(var + EPS_);
    float4 gg = *(const float4*)(g + lane * 4);
    float4 bb = *(const float4*)(be + lane * 4);
    float4 o;
    float v;
    v = (acc.x - mean) * rstd * gg.x + bb.x; o.x = 0.5f * v * (1.0f + erff(v * 0.70710678118f));
    v = (acc.y - mean) * rstd * gg.y + bb.y; o.y = 0.5f * v * (1.0f + erff(v * 0.70710678118f));
    v = (acc.z - mean) * rstd * gg.z + bb.z; o.z = 0.5f * v * (1.0f + erff(v * 0.70710678118f));
    v = (acc.w - mean) * rstd * gg.w + bb.w; o.w = 0.5f * v * (1.0f + erff(v * 0.70710678118f));
    *(float4*)(h + base) = o;
}

// ------------- LN (wave per token): optional h+=pos, y=bf16(LN(h)) ---------
__global__ __launch_bounds__(256) void ln4_kernel(
    float* __restrict__ h, const float* __restrict__ pos,
    const float* __restrict__ g, const float* __restrict__ bb,
    bf16* __restrict__ y)
{
    int wave = threadIdx.x >> 6, lane = threadIdx.x & 63;
    int t = blockIdx.x * 4 + wave;
    int s = t % S_;
    long base = (long)t * E_ + lane * 4;

    float4 v = *(const float4*)(h + base);
    if (pos) {
        float4 pv = *(const float4*)(pos + (long)s * E_ + lane * 4);
        v.x += pv.x; v.y += pv.y; v.z += pv.z; v.w += pv.w;
        *(float4*)(h + base) = v;
    }
    float sum = v.x + v.y + v.z + v.w;
    float sq  = v.x*v.x + v.y*v.y + v.z*v.z + v.w*v.w;
#pragma unroll
    for (int off = 1; off < 64; off <<= 1) {
        sum += __shfl_xor(sum, off);
        sq  += __shfl_xor(sq,  off);
    }
    float mean = sum * (1.0f / E_);
    float var  = sq * (1.0f / E_) - mean * mean;
    float rstd = rsqrtf(var + EPS_);
    float4 gg = *(const float4*)(g + lane * 4);
    float4 b4 = *(const float4*)(bb + lane * 4);
    bf16 o[4];
    o[0] = __float2bfloat16((v.x - mean) * rstd * gg.x + b4.x);
    o[1] = __float2bfloat16((v.y - mean) * rstd * gg.y + b4.y);
    o[2] = __float2bfloat16((v.z - mean) * rstd * gg.z + b4.z);
    o[3] = __float2bfloat16((v.w - mean) * rstd * gg.w + b4.w);
    *(uint2*)(y + base) = *(uint2*)o;
}

// ---------- Single-launch weight pack (LDS 32x32 transpose) ----------------
__global__ __launch_bounds__(256) void pack_all(
    const float* __restrict__ Wq, const float* __restrict__ Wk,
    const float* __restrict__ Wv, const float* __restrict__ bq,
    const float* __restrict__ bk, const float* __restrict__ bv,
    const float* __restrict__ Wo, const float* __restrict__ W1,
    const float* __restrict__ W2,
    bf16* __restrict__ Wqkvt, float* __restrict__ bqkv,
    bf16* __restrict__ Wot, bf16* __restrict__ W1t, bf16* __restrict__ W2t)
{
    __shared__ float tile[32][33];
    int id = blockIdx.x;
    int tx = threadIdx.x & 31, ty = threadIdx.x >> 5;   // 32x8
    const float* src; bf16* dst;
    int c0, k0, Nsrc, Kd, row0;

    if (id < 768) {                       // QKV: 4l x 8k x 24n
        int l = id / 192, r = id % 192;
        int nt = r % 24, kt2 = r / 24;
        int n0 = nt * 32; k0 = kt2 * 32;
        Nsrc = 256; Kd = 256; row0 = n0;
        if (n0 < 256)      { src = Wq + (long)l * 65536; c0 = n0; }
        else if (n0 < 512) { src = Wk + (long)l * 65536; c0 = n0 - 256; }
        else               { src = Wv + (long)l * 65536; c0 = n0 - 512; }
        dst = Wqkvt + (long)l * 768 * 256;
        if (kt2 == 0 && ty == 0) {
            const float* bsrc = (n0 < 256) ? bq + l * 256 + c0
                              : (n0 < 512) ? bk + l * 256 + c0 : bv + l * 256 + c0;
            bqkv[l * 768 + n0 + tx] = bsrc[tx];
        }
    } else if (id < 1024) {               // Wo
        int r = id - 768; int l = r / 64; r %= 64;
        int nt = r & 7, kt2 = r >> 3;
        c0 = nt * 32; k0 = kt2 * 32; Nsrc = 256; Kd = 256; row0 = c0;
        src = Wo + (long)l * 65536; dst = Wot + (long)l * 65536;
    } else if (id < 2048) {               // W1
        int r = id - 1024; int l = r / 256; r %= 256;
        int nt = r % 32, kt2 = r / 32;
        c0 = nt * 32; k0 = kt2 * 32; Nsrc = 1024; Kd = 256; row0 = c0;
        src = W1 + (long)l * 262144; dst = W1t + (long)l * 262144;
    } else {                              // W2
        int r = id - 2048; int l = r / 256; r %= 256;
        int nt = r & 7, kt2 = r >> 3;
        c0 = nt * 32; k0 = kt2 * 32; Nsrc = 256; Kd = 1024; row0 = c0;
        src = W2 + (long)l * 262144; dst = W2t + (long)l * 262144;
    }
#pragma unroll
    for (int i = 0; i < 4; ++i)
        tile[ty + i * 8][tx] = src[(long)(k0 + ty + i * 8) * Nsrc + c0 + tx];
    __syncthreads();
#pragma unroll
    for (int i = 0; i < 4; ++i)
        dst[(long)(row0 + ty + i * 8) * Kd + k0 + tx] = __float2bfloat16(tile[tx][ty + i * 8]);
}

// ---- bf16 MFMA GEMM 64x64 tile, DMA staging + double buffer ---------------
// XOR-rotate swizzle on the GLOBAL chunk index: LDS[r][c] holds global chunk
// (c - r) & 7 of row r; frag reads fetch chunk ((kc + r) & 7). 32 KB LDS ->
// 5 blocks/CU; large grids supply the TLP that hides DMA latency.
__global__ __launch_bounds__(256) void gemm_bf16(
    const bf16* __restrict__ A, const bf16* __restrict__ Wt,
    const float* __restrict__ bias, const float* __restrict__ res,
    float* __restrict__ outF, bf16* __restrict__ outB,
    bf16* __restrict__ vTout, int M, int K, int N, int act)
{
    __shared__ bf16 As[2][64 * 64];    // 2 x 8 KB
    __shared__ bf16 Bs[2][64 * 64];    // 2 x 8 KB
    int tid = threadIdx.x;
    int wave = tid >> 6, lane = tid & 63;
    int quad = lane >> 4, l16 = lane & 15;
    int row0 = blockIdx.y * 64;
    int col0 = blockIdx.x * 64;

    int sr = lane >> 3;
    int sc = lane & 7;

    f32x4 acc[4] = {{0.f,0.f,0.f,0.f},{0.f,0.f,0.f,0.f},{0.f,0.f,0.f,0.f},{0.f,0.f,0.f,0.f}};
    int nk = K >> 6;

    // prologue: DMA tile 0 into buffer 0 (16 groups of 8 rows: 0..7 A, 8..15 B)
#pragma unroll
    for (int gi = 0; gi < 4; ++gi) {
        int id = wave * 4 + gi;           // 0..15
        int rr = (id & 7) * 8 + sr;
        int cs = (sc - rr) & 7;
        if (id < 8) dma16(A  + (long)(row0 + rr) * K + cs * 8, &As[0][(id & 7) * 8 * 64]);
        else        dma16(Wt + (long)(col0 + rr) * K + cs * 8, &Bs[0][(id & 7) * 8 * 64]);
    }
    for (int kt = 0; kt < nk; ++kt) {
        __syncthreads();
        int buf = kt & 1;
        if (kt < nk - 1) {
            int k1 = (kt + 1) << 6;
            int nb = buf ^ 1;
#pragma unroll
            for (int gi = 0; gi < 4; ++gi) {
                int id = wave * 4 + gi;
                int rr = (id & 7) * 8 + sr;
                int cs = (sc - rr) & 7;
                if (id < 8) dma16(A  + (long)(row0 + rr) * K + k1 + cs * 8, &As[nb][(id & 7) * 8 * 64]);
                else        dma16(Wt + (long)(col0 + rr) * K + k1 + cs * 8, &Bs[nb][(id & 7) * 8 * 64]);
            }
        }
#pragma unroll
        for (int ks8 = 0; ks8 < 8; ks8 += 4) {
            int rra = wave * 16 + l16;
            bf16x8 af = *(const bf16x8*)&As[buf][rra * 64 + (((quad + ks8) + rra) & 7) * 8];
#pragma unroll
            for (int nt = 0; nt < 4; ++nt) {
                int rrb = nt * 16 + l16;
                bf16x8 bf = *(const bf16x8*)&Bs[buf][rrb * 64 + (((quad + ks8) + rrb) & 7) * 8];
                acc[nt] = __builtin_amdgcn_mfma_f32_16x16x32_bf16(af, bf, acc[nt], 0, 0, 0);
            }
        }
    }
#pragma unroll
    for (int nt = 0; nt < 4; ++nt) {
        int col = col0 + nt * 16 + l16;
#pragma unroll
        for (int r = 0; r < 4; ++r) {
            int m = row0 + wave * 16 + quad * 4 + r;
            if (m >= M) continue;
            float v = acc[nt][r] + bias[col];
            if (act == 1) v = 0.5f * v * (1.0f + erff(v * 0.70710678118f));
            if (res)  v += res[(long)m * N + col];
            if (outF) outF[(long)m * N + col] = v;
            bf16 bvv = __float2bfloat16(v);
            if (outB) outB[(long)m * N + col] = bvv;
            if (vTout && col >= 512) {    // V cols -> vT[bh][d][key]
                int b2 = m / S_;
                int key = m - b2 * S_;
                int cc = col - 512;
                vTout[((long)(b2 * 8 + (cc >> 5)) * 32 + (cc & 31)) * SP_ + key] = bvv;
            }
        }
    }
}

// --------------- MFMA flash attention v6 (R17, best) -----------------------
#define NQT4 9   // ceil(S_/128)
__global__ __launch_bounds__(256) void attn_mfma6_kernel(
    const bf16* __restrict__ qkv, const bf16* __restrict__ vT,
    bf16* __restrict__ ob)
{
    __shared__ bf16 Ks[2][64 * 40];    // [key][d], row 80 B
    __shared__ bf16 Vs[2][32 * 80];    // [d][key], row 160 B
    __shared__ bf16 Pa[4][32 * 72];    // per-wave P [q][key], row 144 B

    int tid = threadIdx.x;
    int wave = tid >> 6, lane = tid & 63;
    int quad = lane >> 4, l16 = lane & 15;
    int bh = blockIdx.x / NQT4, qt = blockIdx.x % NQT4;
    int b = bh >> 3, hh = bh & 7;
    int q0 = qt * 128;
    long bS = (long)b * S_;
    bf16* Pw = Pa[wave];
    const bf16* vTb = vT + (long)bh * 32 * SP_;
    uint4 z4 = make_uint4(0,0,0,0);

    int skey = tid >> 2, sdg = tid & 3;
    int svd = tid >> 3, svc = tid & 7;

    bf16x8 aq[2];
#pragma unroll
    for (int f = 0; f < 2; ++f) {
        bf16x8 a = {0,0,0,0,0,0,0,0};
        int gq = q0 + wave * 32 + f * 16 + l16;
        if (gq < S_) a = *(const bf16x8*)(qkv + (bS + gq) * 768 + hh * 32 + quad * 8);
        aq[f] = a;
    }

    f32x4 o00 = {0.f,0.f,0.f,0.f}, o01 = {0.f,0.f,0.f,0.f};
    f32x4 o10 = {0.f,0.f,0.f,0.f}, o11 = {0.f,0.f,0.f,0.f};
    float lsum[2][4] = {{0.f,0.f,0.f,0.f},{0.f,0.f,0.f,0.f}};
    f32x4 zf = {0.f,0.f,0.f,0.f};

    {   // prologue: stage tile 0
        int gk = skey;
        uint4 kv = z4;
        if (gk < S_) kv = *(const uint4*)(qkv + (bS + gk) * 768 + 256 + hh * 32 + sdg * 8);
        *(uint4*)&Ks[0][skey * 40 + sdg * 8] = kv;
        *(uint4*)&Vs[0][svd * 80 + svc * 8] = *(const uint4*)(vTb + (long)svd * SP_ + svc * 8);
    }

    for (int kt = 0; kt < 17; ++kt) {
        int j0 = kt * 64;
        int bb = kt & 1;
        __syncthreads();

        if (kt < 16) {
            int j1 = j0 + 64;
            int gk = j1 + skey;
            uint4 kv = z4;
            if (gk < S_) kv = *(const uint4*)(qkv + (bS + gk) * 768 + 256 + hh * 32 + sdg * 8);
            *(uint4*)&Ks[bb ^ 1][skey * 40 + sdg * 8] = kv;
            *(uint4*)&Vs[bb ^ 1][svd * 80 + svc * 8] =
                *(const uint4*)(vTb + (long)svd * SP_ + j1 + svc * 8);
        }

        bf16x8 bk[4];
#pragma unroll
        for (int t4 = 0; t4 < 4; ++t4)
            bk[t4] = *(const bf16x8*)&Ks[bb][(t4 * 16 + l16) * 40 + quad * 8];

#pragma unroll
        for (int f = 0; f < 2; ++f) {
            f32x4 sc[4];
#pragma unroll
            for (int t4 = 0; t4 < 4; ++t4)
                sc[t4] = __builtin_amdgcn_mfma_f32_16x16x32_bf16(aq[f], bk[t4], zf, 0, 0, 0);
            if (kt < 16) {               // full tile: no validity masking
#pragma unroll
                for (int t4 = 0; t4 < 4; ++t4)
#pragma unroll
                    for (int r = 0; r < 4; ++r) {
                        float p = __expf(sc[t4][r]);
                        lsum[f][r] += p;
                        Pw[(f * 16 + quad * 4 + r) * 72 + t4 * 16 + l16] = __float2bfloat16(p);
                    }
            } else {                     // masked tail tile
#pragma unroll
                for (int t4 = 0; t4 < 4; ++t4) {
                    bool valid = (j0 + t4 * 16 + l16) < S_;
#pragma unroll
                    for (int r = 0; r < 4; ++r) {
                        float p = valid ? __expf(sc[t4][r]) : 0.f;
                        lsum[f][r] += p;
                        Pw[(f * 16 + quad * 4 + r) * 72 + t4 * 16 + l16] = __float2bfloat16(p);
                    }
                }
            }
        }
#pragma unroll
        for (int ks2 = 0; ks2 < 64; ks2 += 32) {
            bf16x8 bv0 = *(const bf16x8*)&Vs[bb][l16 * 80 + ks2 + quad * 8];
            bf16x8 bv1 = *(const bf16x8*)&Vs[bb][(16 + l16) * 80 + ks2 + quad * 8];
            bf16x8 ap0 = *(const bf16x8*)&Pw[l16 * 72 + ks2 + quad * 8];
            bf16x8 ap1 = *(const bf16x8*)&Pw[(16 + l16) * 72 + ks2 + quad * 8];
            o00 = __builtin_amdgcn_mfma_f32_16x16x32_bf16(ap0, bv0, o00, 0, 0, 0);
            o01 = __builtin_amdgcn_mfma_f32_16x16x32_bf16(ap0, bv1, o01, 0, 0, 0);
            o10 = __builtin_amdgcn_mfma_f32_16x16x32_bf16(ap1, bv0, o10, 0, 0, 0);
            o11 = __builtin_amdgcn_mfma_f32_16x16x32_bf16(ap1, bv1, o11, 0, 0, 0);
        }
    }

#pragma unroll
    for (int f = 0; f < 2; ++f) {
        f32x4 oa = f ? o10 : o00;
        f32x4 obv = f ? o11 : o01;
#pragma unroll
        for (int r = 0; r < 4; ++r) {
            float t = lsum[f][r];
            t += __shfl_xor(t, 1); t += __shfl_xor(t, 2);
            t += __shfl_xor(t, 4); t += __shfl_xor(t, 8);
            float inv = 1.0f / (t * 16.0f);
            int gq = q0 + wave * 32 + f * 16 + quad * 4 + r;
            if (gq < S_) {
                long base = (bS + gq) * 256 + hh * 32;
                ob[base + l16]      = __float2bfloat16(oa[r] * inv);
                ob[base + 16 + l16] = __float2bfloat16(obv[r] * inv);
            }
        }
    }
}

// --------------- Pool: partial[b][sc][e] = sum over 65-row chunk -----------
__global__ __launch_bounds__(256) void pool_kernel(const float* __restrict__ h,
                                                   float* __restrict__ partial)
{
    int b = blockIdx.x >> 4, sc = blockIdx.x & 15;
    int e = threadIdx.x;
    int s0 = sc * 65, s1 = min(S_, s0 + 65);
    float acc = 0.f;
    for (int s = s0; s < s1; ++s) acc += h[((long)b * S_ + s) * E_ + e];
    partial[((long)b * 16 + sc) * E_ + e] = acc;
}

// --------------- Classifier final: Linear -> LN -> Linear -----------------
__global__ __launch_bounds__(256) void cls_final(
    const float* __restrict__ partial, const float* __restrict__ Wc1,
    const float* __restrict__ bc1, const float* __restrict__ lg,
    const float* __restrict__ lb, const float* __restrict__ Wc2,
    const float* __restrict__ bc2, float* __restrict__ out)
{
    int b = blockIdx.x;
    int e = threadIdx.x;
    __shared__ float p[256];
    __shared__ float red[256];
    __shared__ float lnv[256];

    float acc = 0.f;
#pragma unroll
    for (int sc = 0; sc < 16; ++sc) acc += partial[((long)b * 16 + sc) * E_ + e];
    p[e] = acc * (1.0f / S_);
    __syncthreads();

    float c1 = bc1[e];
    for (int kk = 0; kk < E_; ++kk) c1 += p[kk] * Wc1[kk * E_ + e];

    red[e] = c1; __syncthreads();
    for (int st = 128; st; st >>= 1) { if (e < st) red[e] += red[e + st]; __syncthreads(); }
    float mean = red[0] * (1.0f / E_); __syncthreads();
    float d = c1 - mean;
    red[e] = d * d; __syncthreads();
    for (int st = 128; st; st >>= 1) { if (e < st) red[e] += red[e + st]; __syncthreads(); }
    float var = red[0] * (1.0f / E_);
    lnv[e] = d * rsqrtf(var + EPS_) * lg[e] + lb[e];
    __syncthreads();

    if (e < NC_) {
        float oacc = bc2[e];
        for (int kk = 0; kk < E_; ++kk) oacc += lnv[kk] * Wc2[kk * NC_ + e];
        out[b * NC_ + e] = oacc;
    }
}

extern "C" void kernel_launch(void* const* d_in, const int* in_sizes, int n_in,
                              void* d_out, int out_size, void* d_ws, size_t ws_size,
                              hipStream_t stream)
{
    const float* x      = (const float*)d_in[0];
    const float* W_emb  = (const float*)d_in[1];
    const float* b_emb  = (const float*)d_in[2];
    const float* g_emb  = (const float*)d_in[3];
    const float* be_emb = (const float*)d_in[4];
    const float* cls    = (const float*)d_in[5];
    const float* pos    = (const float*)d_in[6];
    const float* ln1_g  = (const float*)d_in[7];
    const float* ln1_b  = (const float*)d_in[8];
    const float* Wq     = (const float*)d_in[9];
    const float* bq     = (const float*)d_in[10];
    const float* Wk     = (const float*)d_in[11];
    const float* bk     = (const float*)d_in[12];
    const float* Wv     = (const float*)d_in[13];
    const float* bv     = (const float*)d_in[14];
    const float* Wo     = (const float*)d_in[15];
    const float* bo     = (const float*)d_in[16];
    const float* ln2_g  = (const float*)d_in[17];
    const float* ln2_b  = (const float*)d_in[18];
    const float* W1     = (const float*)d_in[19];
    const float* b1     = (const float*)d_in[20];
    const float* W2     = (const float*)d_in[21];
    const float* b2     = (const float*)d_in[22];
    const float* Wc1    = (const float*)d_in[23];
    const float* bc1    = (const float*)d_in[24];
    const float* lnc_g  = (const float*)d_in[25];
    const float* lnc_b  = (const float*)d_in[26];
    const float* Wc2    = (const float*)d_in[27];
    const float* bc2    = (const float*)d_in[28];
    float* out = (float*)d_out;

    char* p = (char*)d_ws;
    float* h    = (float*)p; p += (long)M_ * 256 * 4;
    bf16* y     = (bf16*)p;  p += (long)M_ * 256 * 2;
    bf16* qkv   = (bf16*)p;  p += (long)M_ * 768 * 2;
    bf16* obuf  = (bf16*)p;  p += (long)M_ * 256 * 2;
    bf16* tb    = (bf16*)p;  p += (long)M_ * 1024 * 2;
    bf16* Wqkvt = (bf16*)p;  p += (long)L_ * 768 * 256 * 2;
    bf16* Wot   = (bf16*)p;  p += (long)L_ * 256 * 256 * 2;
    bf16* W1t   = (bf16*)p;  p += (long)L_ * 1024 * 256 * 2;
    bf16* W2t   = (bf16*)p;  p += (long)L_ * 256 * 1024 * 2;
    float* bqkv = (float*)p; p += (long)L_ * 768 * 4;
    float* pool = (float*)p; p += (long)B_ * 16 * 256 * 4;
    bf16* vT    = (bf16*)p;  p += (long)64 * 32 * SP_ * 2;

    // ---- weight packing (1 launch) ----
    pack_all<<<3072, 256, 0, stream>>>(Wq, Wk, Wv, bq, bk, bv, Wo, W1, W2,
                                       Wqkvt, bqkv, Wot, W1t, W2t);

    embed4_kernel<<<M_ / 4, 256, 0, stream>>>(x, W_emb, b_emb, g_emb, be_emb, cls, h);

    dim3 gQKV(12, 129), gMLP1(16, 129), gEE(4, 129);
    for (int l = 0; l < L_; ++l) {
        // h += pos; y = LN1(h)
        ln4_kernel<<<M_ / 4, 256, 0, stream>>>(h, pos, ln1_g + l * E_, ln1_b + l * E_, y);
        // qkv = y @ Wqkv + b (V cols also -> vT, transposed)
        gemm_bf16<<<gQKV, 256, 0, stream>>>(y, Wqkvt + (long)l * 768 * 256, bqkv + l * 768,
                                            nullptr, nullptr, qkv, vT, M_, 256, 768, 0);
        attn_mfma6_kernel<<<64 * NQT4, 256, 0, stream>>>(qkv, vT, obuf);
        // h += o @ Wo + bo
        gemm_bf16<<<gEE, 256, 0, stream>>>(obuf, Wot + (long)l * 65536, bo + l * E_,
                                           h, h, nullptr, nullptr, M_, 256, 256, 0);
        // y = LN2(h); tb = GELU(y @ W1 + b1)
        ln4_kernel<<<M_ / 4, 256, 0, stream>>>(h, nullptr, ln2_g + l * E_, ln2_b + l * E_, y);
        gemm_bf16<<<gMLP1, 256, 0, stream>>>(y, W1t + (long)l * 262144, b1 + l * XE_,
                                             nullptr, nullptr, tb, nullptr, M_, 256, 1024, 1);
        // h += tb @ W2 + b2
        gemm_bf16<<<gEE, 256, 0, stream>>>(tb, W2t + (long)l * 262144, b2 + l * E_,
                                           h, h, nullptr, nullptr, M_, 1024, 256, 0);
    }

    pool_kernel<<<B_ * 16, 256, 0, stream>>>(h, pool);
    cls_final<<<B_, 256, 0, stream>>>(pool, Wc1, bc1, lnc_g, lnc_b, Wc2, bc2, out);
}

// Round 19
// 665.498 us; speedup vs baseline: 1.2339x; 1.0240x over previous
//
#include <hip/hip_runtime.h>
#include <hip/hip_bf16.h>
#include <math.h>

// Problem constants
#define B_  8
#define N_  1024
#define C_  12
#define E_  256
#define H_  8
#define D_  32      // E/H
#define L_  4
#define XE_ 1024    // X*E
#define NC_ 5
#define S_  1025    // N+1
#define M_  8200    // B*S
#define EPS_ 1e-5f
#define SP_ 1088    // padded key-stride for vT (17*64, 16B-aligned)

typedef short bf16x8 __attribute__((ext_vector_type(8)));
typedef float f32x4 __attribute__((ext_vector_type(4)));
typedef __hip_bfloat16 bf16;

// async global->LDS DMA, 16 B per lane; LDS dest = wave-uniform base + lane*16
typedef __attribute__((address_space(1))) const unsigned int* as1_cuint;
typedef __attribute__((address_space(3))) unsigned int* as3_uint;
__device__ __forceinline__ void dma16(const void* g, void* l) {
    __builtin_amdgcn_global_load_lds((as1_cuint)g, (as3_uint)l, 16, 0, 0);
}

// ---------------- Embedding (wave per token): x@W+b -> LN -> GELU ----------
__global__ __launch_bounds__(256) void embed4_kernel(
    const float* __restrict__ x, const float* __restrict__ Wemb,
    const float* __restrict__ bemb, const float* __restrict__ g,
    const float* __restrict__ be, const float* __restrict__ cls,
    float* __restrict__ h)
{
    int wave = threadIdx.x >> 6, lane = threadIdx.x & 63;
    int t = blockIdx.x * 4 + wave;          // M_ = 4*2050 exactly
    int b = t / S_, s = t % S_;
    long base = (long)t * E_ + lane * 4;

    if (s == 0) {
        *(float4*)(h + base) = *(const float4*)(cls + lane * 4);
        return;
    }
    const float* xr = x + ((long)b * N_ + (s - 1)) * C_;
    float xv[C_];
#pragma unroll
    for (int c = 0; c < C_; ++c) xv[c] = xr[c];

    float4 acc = *(const float4*)(bemb + lane * 4);
#pragma unroll
    for (int c = 0; c < C_; ++c) {
        float4 w = *(const float4*)(Wemb + c * E_ + lane * 4);
        acc.x += xv[c] * w.x; acc.y += xv[c] * w.y;
        acc.z += xv[c] * w.z; acc.w += xv[c] * w.w;
    }
    float sum = acc.x + acc.y + acc.z + acc.w;
    float sq  = acc.x*acc.x + acc.y*acc.y + acc.z*acc.z + acc.w*acc.w;
#pragma unroll
    for (int off = 1; off < 64; off <<= 1) {
        sum += __shfl_xor(sum, off);
        sq  += __shfl_xor(sq,  off);
    }
    float mean = sum * (1.0f / E_);
    float var  = sq * (1.0f / E_) - mean * mean;
    float rstd = rsqrtf(var + EPS_);
    float4 gg = *(const float4*)(g + lane * 4);
    float4 bb = *(const float4*)(be + lane * 4);
    float4 o;
    float v;
    v = (acc.x - mean) * rstd * gg.x + bb.x; o.x = 0.5f * v * (1.0f + erff(v * 0.70710678118f));
    v = (acc.y - mean) * rstd * gg.y + bb.y; o.y = 0.5f * v * (1.0f + erff(v * 0.70710678118f));
    v = (acc.z - mean) * rstd * gg.z + bb.z; o.z = 0.5f * v * (1.0f + erff(v * 0.70710678118f));
    v = (acc.w - mean) * rstd * gg.w + bb.w; o.w = 0.5f * v * (1.0f + erff(v * 0.70710678118f));
    *(float4*)(h + base) = o;
}

// ------------- LN (wave per token): optional h+=pos, y=bf16(LN(h)) ---------
__global__ __launch_bounds__(256) void ln4_kernel(
    float* __restrict__ h, const float* __restrict__ pos,
    const float* __restrict__ g, const float* __restrict__ bb,
    bf16* __restrict__ y)
{
    int wave = threadIdx.x >> 6, lane = threadIdx.x & 63;
    int t = blockIdx.x * 4 + wave;
    int s = t % S_;
    long base = (long)t * E_ + lane * 4;

    float4 v = *(const float4*)(h + base);
    if (pos) {
        float4 pv = *(const float4*)(pos + (long)s * E_ + lane * 4);
        v.x += pv.x; v.y += pv.y; v.z += pv.z; v.w += pv.w;
        *(float4*)(h + base) = v;
    }
    float sum = v.x + v.y + v.z + v.w;
    float sq  = v.x*v.x + v.y*v.y + v.z*v.z + v.w*v.w;
#pragma unroll
    for (int off = 1; off < 64; off <<= 1) {
        sum += __shfl_xor(sum, off);
        sq  += __shfl_xor(sq,  off);
    }
    float mean = sum * (1.0f / E_);
    float var  = sq * (1.0f / E_) - mean * mean;
    float rstd = rsqrtf(var + EPS_);
    float4 gg = *(const float4*)(g + lane * 4);
    float4 b4 = *(const float4*)(bb + lane * 4);
    bf16 o[4];
    o[0] = __float2bfloat16((v.x - mean) * rstd * gg.x + b4.x);
    o[1] = __float2bfloat16((v.y - mean) * rstd * gg.y + b4.y);
    o[2] = __float2bfloat16((v.z - mean) * rstd * gg.z + b4.z);
    o[3] = __float2bfloat16((v.w - mean) * rstd * gg.w + b4.w);
    *(uint2*)(y + base) = *(uint2*)o;
}

// ---------- Single-launch weight pack (LDS 32x32 transpose) ----------------
__global__ __launch_bounds__(256) void pack_all(
    const float* __restrict__ Wq, const float* __restrict__ Wk,
    const float* __restrict__ Wv, const float* __restrict__ bq,
    const float* __restrict__ bk, const float* __restrict__ bv,
    const float* __restrict__ Wo, const float* __restrict__ W1,
    const float* __restrict__ W2,
    bf16* __restrict__ Wqkvt, float* __restrict__ bqkv,
    bf16* __restrict__ Wot, bf16* __restrict__ W1t, bf16* __restrict__ W2t)
{
    __shared__ float tile[32][33];
    int id = blockIdx.x;
    int tx = threadIdx.x & 31, ty = threadIdx.x >> 5;   // 32x8
    const float* src; bf16* dst;
    int c0, k0, Nsrc, Kd, row0;

    if (id < 768) {                       // QKV: 4l x 8k x 24n
        int l = id / 192, r = id % 192;
        int nt = r % 24, kt2 = r / 24;
        int n0 = nt * 32; k0 = kt2 * 32;
        Nsrc = 256; Kd = 256; row0 = n0;
        if (n0 < 256)      { src = Wq + (long)l * 65536; c0 = n0; }
        else if (n0 < 512) { src = Wk + (long)l * 65536; c0 = n0 - 256; }
        else               { src = Wv + (long)l * 65536; c0 = n0 - 512; }
        dst = Wqkvt + (long)l * 768 * 256;
        if (kt2 == 0 && ty == 0) {
            const float* bsrc = (n0 < 256) ? bq + l * 256 + c0
                              : (n0 < 512) ? bk + l * 256 + c0 : bv + l * 256 + c0;
            bqkv[l * 768 + n0 + tx] = bsrc[tx];
        }
    } else if (id < 1024) {               // Wo
        int r = id - 768; int l = r / 64; r %= 64;
        int nt = r & 7, kt2 = r >> 3;
        c0 = nt * 32; k0 = kt2 * 32; Nsrc = 256; Kd = 256; row0 = c0;
        src = Wo + (long)l * 65536; dst = Wot + (long)l * 65536;
    } else if (id < 2048) {               // W1
        int r = id - 1024; int l = r / 256; r %= 256;
        int nt = r % 32, kt2 = r / 32;
        c0 = nt * 32; k0 = kt2 * 32; Nsrc = 1024; Kd = 256; row0 = c0;
        src = W1 + (long)l * 262144; dst = W1t + (long)l * 262144;
    } else {                              // W2
        int r = id - 2048; int l = r / 256; r %= 256;
        int nt = r & 7, kt2 = r >> 3;
        c0 = nt * 32; k0 = kt2 * 32; Nsrc = 256; Kd = 1024; row0 = c0;
        src = W2 + (long)l * 262144; dst = W2t + (long)l * 262144;
    }
#pragma unroll
    for (int i = 0; i < 4; ++i)
        tile[ty + i * 8][tx] = src[(long)(k0 + ty + i * 8) * Nsrc + c0 + tx];
    __syncthreads();
#pragma unroll
    for (int i = 0; i < 4; ++i)
        dst[(long)(row0 + ty + i * 8) * Kd + k0 + tx] = __float2bfloat16(tile[tx][ty + i * 8]);
}

// ---- bf16 MFMA GEMM 64x64 tile, DMA staging + double buffer ---------------
__global__ __launch_bounds__(256) void gemm_bf16(
    const bf16* __restrict__ A, const bf16* __restrict__ Wt,
    const float* __restrict__ bias, const float* __restrict__ res,
    float* __restrict__ outF, bf16* __restrict__ outB,
    bf16* __restrict__ vTout, int M, int K, int N, int act)
{
    __shared__ bf16 As[2][64 * 64];    // 2 x 8 KB
    __shared__ bf16 Bs[2][64 * 64];    // 2 x 8 KB
    int tid = threadIdx.x;
    int wave = tid >> 6, lane = tid & 63;
    int quad = lane >> 4, l16 = lane & 15;
    int row0 = blockIdx.y * 64;
    int col0 = blockIdx.x * 64;

    int sr = lane >> 3;
    int sc = lane & 7;

    f32x4 acc[4] = {{0.f,0.f,0.f,0.f},{0.f,0.f,0.f,0.f},{0.f,0.f,0.f,0.f},{0.f,0.f,0.f,0.f}};
    int nk = K >> 6;

    // prologue: DMA tile 0 into buffer 0 (16 groups of 8 rows: 0..7 A, 8..15 B)
#pragma unroll
    for (int gi = 0; gi < 4; ++gi) {
        int id = wave * 4 + gi;           // 0..15
        int rr = (id & 7) * 8 + sr;
        int cs = (sc - rr) & 7;
        if (id < 8) dma16(A  + (long)(row0 + rr) * K + cs * 8, &As[0][(id & 7) * 8 * 64]);
        else        dma16(Wt + (long)(col0 + rr) * K + cs * 8, &Bs[0][(id & 7) * 8 * 64]);
    }
    for (int kt = 0; kt < nk; ++kt) {
        __syncthreads();
        int buf = kt & 1;
        if (kt < nk - 1) {
            int k1 = (kt + 1) << 6;
            int nb = buf ^ 1;
#pragma unroll
            for (int gi = 0; gi < 4; ++gi) {
                int id = wave * 4 + gi;
                int rr = (id & 7) * 8 + sr;
                int cs = (sc - rr) & 7;
                if (id < 8) dma16(A  + (long)(row0 + rr) * K + k1 + cs * 8, &As[nb][(id & 7) * 8 * 64]);
                else        dma16(Wt + (long)(col0 + rr) * K + k1 + cs * 8, &Bs[nb][(id & 7) * 8 * 64]);
            }
        }
#pragma unroll
        for (int ks8 = 0; ks8 < 8; ks8 += 4) {
            int rra = wave * 16 + l16;
            bf16x8 af = *(const bf16x8*)&As[buf][rra * 64 + (((quad + ks8) + rra) & 7) * 8];
#pragma unroll
            for (int nt = 0; nt < 4; ++nt) {
                int rrb = nt * 16 + l16;
                bf16x8 bf = *(const bf16x8*)&Bs[buf][rrb * 64 + (((quad + ks8) + rrb) & 7) * 8];
                acc[nt] = __builtin_amdgcn_mfma_f32_16x16x32_bf16(af, bf, acc[nt], 0, 0, 0);
            }
        }
    }
#pragma unroll
    for (int nt = 0; nt < 4; ++nt) {
        int col = col0 + nt * 16 + l16;
#pragma unroll
        for (int r = 0; r < 4; ++r) {
            int m = row0 + wave * 16 + quad * 4 + r;
            if (m >= M) continue;
            float v = acc[nt][r] + bias[col];
            if (act == 1) v = 0.5f * v * (1.0f + erff(v * 0.70710678118f));
            if (res)  v += res[(long)m * N + col];
            if (outF) outF[(long)m * N + col] = v;
            bf16 bvv = __float2bfloat16(v);
            if (outB) outB[(long)m * N + col] = bvv;
            if (vTout && col >= 512) {    // V cols -> vT[bh][d][key]
                int b2 = m / S_;
                int key = m - b2 * S_;
                int cc = col - 512;
                vTout[((long)(b2 * 8 + (cc >> 5)) * 32 + (cc & 31)) * SP_ + key] = bvv;
            }
        }
    }
}

// --------------- MFMA flash attention v7: 64-query tiles -------------------
// One Q-frag per wave (4 waves = 64 q rows/block); grid 1088 = 4.25 blk/CU,
// LDS 29.7 KB -> 5 resident blocks/CU. Same staging/layouts as v6 otherwise.
#define NQT 17
__global__ __launch_bounds__(256) void attn_mfma7_kernel(
    const bf16* __restrict__ qkv, const bf16* __restrict__ vT,
    bf16* __restrict__ ob)
{
    __shared__ bf16 Ks[2][64 * 40];    // [key][d], row 80 B
    __shared__ bf16 Vs[2][32 * 80];    // [d][key], row 160 B
    __shared__ bf16 Pa[4][16 * 72];    // per-wave P [q][key], row 144 B

    int tid = threadIdx.x;
    int wave = tid >> 6, lane = tid & 63;
    int quad = lane >> 4, l16 = lane & 15;
    int bh = blockIdx.x / NQT, qt = blockIdx.x % NQT;
    int b = bh >> 3, hh = bh & 7;
    int q0 = qt * 64;
    long bS = (long)b * S_;
    bf16* Pw = Pa[wave];
    const bf16* vTb = vT + (long)bh * 32 * SP_;
    uint4 z4 = make_uint4(0,0,0,0);

    int skey = tid >> 2, sdg = tid & 3;
    int svd = tid >> 3, svc = tid & 7;

    // Q-frag (register-resident): A[m=q(l16)][k=d(quad*8+j)]
    bf16x8 aq = {0,0,0,0,0,0,0,0};
    {
        int gq = q0 + wave * 16 + l16;
        if (gq < S_) aq = *(const bf16x8*)(qkv + (bS + gq) * 768 + hh * 32 + quad * 8);
    }

    f32x4 o0 = {0.f,0.f,0.f,0.f}, o1 = {0.f,0.f,0.f,0.f};
    float lsum[4] = {0.f,0.f,0.f,0.f};
    f32x4 zf = {0.f,0.f,0.f,0.f};

    {   // prologue: stage tile 0
        int gk = skey;
        uint4 kv = z4;
        if (gk < S_) kv = *(const uint4*)(qkv + (bS + gk) * 768 + 256 + hh * 32 + sdg * 8);
        *(uint4*)&Ks[0][skey * 40 + sdg * 8] = kv;
        *(uint4*)&Vs[0][svd * 80 + svc * 8] = *(const uint4*)(vTb + (long)svd * SP_ + svc * 8);
    }

    for (int kt = 0; kt < NQT; ++kt) {
        int j0 = kt * 64;
        int bb = kt & 1;
        __syncthreads();

        if (kt < NQT - 1) {
            int j1 = j0 + 64;
            int gk = j1 + skey;
            uint4 kv = z4;
            if (gk < S_) kv = *(const uint4*)(qkv + (bS + gk) * 768 + 256 + hh * 32 + sdg * 8);
            *(uint4*)&Ks[bb ^ 1][skey * 40 + sdg * 8] = kv;
            *(uint4*)&Vs[bb ^ 1][svd * 80 + svc * 8] =
                *(const uint4*)(vTb + (long)svd * SP_ + j1 + svc * 8);
        }

        // scores: 4 mfma -> S[16q x 64k]
        f32x4 sc[4];
#pragma unroll
        for (int t4 = 0; t4 < 4; ++t4) {
            bf16x8 bk = *(const bf16x8*)&Ks[bb][(t4 * 16 + l16) * 40 + quad * 8];
            sc[t4] = __builtin_amdgcn_mfma_f32_16x16x32_bf16(aq, bk, zf, 0, 0, 0);
        }
        if (kt < NQT - 1) {              // full tile: no validity masking
#pragma unroll
            for (int t4 = 0; t4 < 4; ++t4)
#pragma unroll
                for (int r = 0; r < 4; ++r) {
                    float p = __expf(sc[t4][r]);
                    lsum[r] += p;
                    Pw[(quad * 4 + r) * 72 + t4 * 16 + l16] = __float2bfloat16(p);
                }
        } else {                         // masked tail tile
#pragma unroll
            for (int t4 = 0; t4 < 4; ++t4) {
                bool valid = (j0 + t4 * 16 + l16) < S_;
#pragma unroll
                for (int r = 0; r < 4; ++r) {
                    float p = valid ? __expf(sc[t4][r]) : 0.f;
                    lsum[r] += p;
                    Pw[(quad * 4 + r) * 72 + t4 * 16 + l16] = __float2bfloat16(p);
                }
            }
        }
        // PV: o += P @ V  (V[d][key] rows; d halves 0-15, 16-31)
#pragma unroll
        for (int ks2 = 0; ks2 < 64; ks2 += 32) {
            bf16x8 ap = *(const bf16x8*)&Pw[l16 * 72 + ks2 + quad * 8];
            bf16x8 bv0 = *(const bf16x8*)&Vs[bb][l16 * 80 + ks2 + quad * 8];
            o0 = __builtin_amdgcn_mfma_f32_16x16x32_bf16(ap, bv0, o0, 0, 0, 0);
            bf16x8 bv1 = *(const bf16x8*)&Vs[bb][(16 + l16) * 80 + ks2 + quad * 8];
            o1 = __builtin_amdgcn_mfma_f32_16x16x32_bf16(ap, bv1, o1, 0, 0, 0);
        }
    }

    // normalize (1/(l*16), /sqrt(E) AFTER softmax) and store
#pragma unroll
    for (int r = 0; r < 4; ++r) {
        float t = lsum[r];
        t += __shfl_xor(t, 1); t += __shfl_xor(t, 2);
        t += __shfl_xor(t, 4); t += __shfl_xor(t, 8);
        float inv = 1.0f / (t * 16.0f);
        int gq = q0 + wave * 16 + quad * 4 + r;
        if (gq < S_) {
            long base = (bS + gq) * 256 + hh * 32;
            ob[base + l16]      = __float2bfloat16(o0[r] * inv);
            ob[base + 16 + l16] = __float2bfloat16(o1[r] * inv);
        }
    }
}

// --------------- Pool: partial[b][sc][e] = sum over 65-row chunk -----------
__global__ __launch_bounds__(256) void pool_kernel(const float* __restrict__ h,
                                                   float* __restrict__ partial)
{
    int b = blockIdx.x >> 4, sc = blockIdx.x & 15;
    int e = threadIdx.x;
    int s0 = sc * 65, s1 = min(S_, s0 + 65);
    float acc = 0.f;
    for (int s = s0; s < s1; ++s) acc += h[((long)b * S_ + s) * E_ + e];
    partial[((long)b * 16 + sc) * E_ + e] = acc;
}

// --------------- Classifier final: Linear -> LN -> Linear -----------------
__global__ __launch_bounds__(256) void cls_final(
    const float* __restrict__ partial, const float* __restrict__ Wc1,
    const float* __restrict__ bc1, const float* __restrict__ lg,
    const float* __restrict__ lb, const float* __restrict__ Wc2,
    const float* __restrict__ bc2, float* __restrict__ out)
{
    int b = blockIdx.x;
    int e = threadIdx.x;
    __shared__ float p[256];
    __shared__ float red[256];
    __shared__ float lnv[256];

    float acc = 0.f;
#pragma unroll
    for (int sc = 0; sc < 16; ++sc) acc += partial[((long)b * 16 + sc) * E_ + e];
    p[e] = acc * (1.0f / S_);
    __syncthreads();

    float c1 = bc1[e];
    for (int kk = 0; kk < E_; ++kk) c1 += p[kk] * Wc1[kk * E_ + e];

    red[e] = c1; __syncthreads();
    for (int st = 128; st; st >>= 1) { if (e < st) red[e] += red[e + st]; __syncthreads(); }
    float mean = red[0] * (1.0f / E_); __syncthreads();
    float d = c1 - mean;
    red[e] = d * d; __syncthreads();
    for (int st = 128; st; st >>= 1) { if (e < st) red[e] += red[e + st]; __syncthreads(); }
    float var = red[0] * (1.0f / E_);
    lnv[e] = d * rsqrtf(var + EPS_) * lg[e] + lb[e];
    __syncthreads();

    if (e < NC_) {
        float oacc = bc2[e];
        for (int kk = 0; kk < E_; ++kk) oacc += lnv[kk] * Wc2[kk * NC_ + e];
        out[b * NC_ + e] = oacc;
    }
}

extern "C" void kernel_launch(void* const* d_in, const int* in_sizes, int n_in,
                              void* d_out, int out_size, void* d_ws, size_t ws_size,
                              hipStream_t stream)
{
    const float* x      = (const float*)d_in[0];
    const float* W_emb  = (const float*)d_in[1];
    const float* b_emb  = (const float*)d_in[2];
    const float* g_emb  = (const float*)d_in[3];
    const float* be_emb = (const float*)d_in[4];
    const float* cls    = (const float*)d_in[5];
    const float* pos    = (const float*)d_in[6];
    const float* ln1_g  = (const float*)d_in[7];
    const float* ln1_b  = (const float*)d_in[8];
    const float* Wq     = (const float*)d_in[9];
    const float* bq     = (const float*)d_in[10];
    const float* Wk     = (const float*)d_in[11];
    const float* bk     = (const float*)d_in[12];
    const float* Wv     = (const float*)d_in[13];
    const float* bv     = (const float*)d_in[14];
    const float* Wo     = (const float*)d_in[15];
    const float* bo     = (const float*)d_in[16];
    const float* ln2_g  = (const float*)d_in[17];
    const float* ln2_b  = (const float*)d_in[18];
    const float* W1     = (const float*)d_in[19];
    const float* b1     = (const float*)d_in[20];
    const float* W2     = (const float*)d_in[21];
    const float* b2     = (const float*)d_in[22];
    const float* Wc1    = (const float*)d_in[23];
    const float* bc1    = (const float*)d_in[24];
    const float* lnc_g  = (const float*)d_in[25];
    const float* lnc_b  = (const float*)d_in[26];
    const float* Wc2    = (const float*)d_in[27];
    const float* bc2    = (const float*)d_in[28];
    float* out = (float*)d_out;

    char* p = (char*)d_ws;
    float* h    = (float*)p; p += (long)M_ * 256 * 4;
    bf16* y     = (bf16*)p;  p += (long)M_ * 256 * 2;
    bf16* qkv   = (bf16*)p;  p += (long)M_ * 768 * 2;
    bf16* obuf  = (bf16*)p;  p += (long)M_ * 256 * 2;
    bf16* tb    = (bf16*)p;  p += (long)M_ * 1024 * 2;
    bf16* Wqkvt = (bf16*)p;  p += (long)L_ * 768 * 256 * 2;
    bf16* Wot   = (bf16*)p;  p += (long)L_ * 256 * 256 * 2;
    bf16* W1t   = (bf16*)p;  p += (long)L_ * 1024 * 256 * 2;
    bf16* W2t   = (bf16*)p;  p += (long)L_ * 256 * 1024 * 2;
    float* bqkv = (float*)p; p += (long)L_ * 768 * 4;
    float* pool = (float*)p; p += (long)B_ * 16 * 256 * 4;
    bf16* vT    = (bf16*)p;  p += (long)64 * 32 * SP_ * 2;

    // ---- weight packing (1 launch) ----
    pack_all<<<3072, 256, 0, stream>>>(Wq, Wk, Wv, bq, bk, bv, Wo, W1, W2,
                                       Wqkvt, bqkv, Wot, W1t, W2t);

    embed4_kernel<<<M_ / 4, 256, 0, stream>>>(x, W_emb, b_emb, g_emb, be_emb, cls, h);

    dim3 gQKV(12, 129), gMLP1(16, 129), gEE(4, 129);
    for (int l = 0; l < L_; ++l) {
        // h += pos; y = LN1(h)
        ln4_kernel<<<M_ / 4, 256, 0, stream>>>(h, pos, ln1_g + l * E_, ln1_b + l * E_, y);
        // qkv = y @ Wqkv + b (V cols also -> vT, transposed)
        gemm_bf16<<<gQKV, 256, 0, stream>>>(y, Wqkvt + (long)l * 768 * 256, bqkv + l * 768,
                                            nullptr, nullptr, qkv, vT, M_, 256, 768, 0);
        attn_mfma7_kernel<<<64 * NQT, 256, 0, stream>>>(qkv, vT, obuf);
        // h += o @ Wo + bo
        gemm_bf16<<<gEE, 256, 0, stream>>>(obuf, Wot + (long)l * 65536, bo + l * E_,
                                           h, h, nullptr, nullptr, M_, 256, 256, 0);
        // y = LN2(h); tb = GELU(y @ W1 + b1)
        ln4_kernel<<<M_ / 4, 256, 0, stream>>>(h, nullptr, ln2_g + l * E_, ln2_b + l * E_, y);
        gemm_bf16<<<gMLP1, 256, 0, stream>>>(y, W1t + (long)l * 262144, b1 + l * XE_,
                                             nullptr, nullptr, tb, nullptr, M_, 256, 1024, 1);
        // h += tb @ W2 + b2
        gemm_bf16<<<gEE, 256, 0, stream>>>(tb, W2t + (long)l * 262144, b2 + l * E_,
                                           h, h, nullptr, nullptr, M_, 1024, 256, 0);
    }

    pool_kernel<<<B_ * 16, 256, 0, stream>>>(h, pool);
    cls_final<<<B_, 256, 0, stream>>>(pool, Wc1, bc1, lnc_g, lnc_b, Wc2, bc2, out);
}

// Round 20
// 659.407 us; speedup vs baseline: 1.2453x; 1.0092x over previous
//
#include <hip/hip_runtime.h>
#include <hip/hip_bf16.h>
#include <math.h>

// Problem constants
#define B_  8
#define N_  1024
#define C_  12
#define E_  256
#define H_  8
#define D_  32      // E/H
#define L_  4
#define XE_ 1024    // X*E
#define NC_ 5
#define S_  1025    // N+1
#define M_  8200    // B*S
#define EPS_ 1e-5f
#define SP_ 1088    // padded key-stride for vT (17*64, 16B-aligned)

typedef short bf16x8 __attribute__((ext_vector_type(8)));
typedef float f32x4 __attribute__((ext_vector_type(4)));
typedef __hip_bfloat16 bf16;

// async global->LDS DMA, 16 B per lane; LDS dest = wave-uniform base + lane*16
typedef __attribute__((address_space(1))) const unsigned int* as1_cuint;
typedef __attribute__((address_space(3))) unsigned int* as3_uint;
__device__ __forceinline__ void dma16(const void* g, void* l) {
    __builtin_amdgcn_global_load_lds((as1_cuint)g, (as3_uint)l, 16, 0, 0);
}

// ---------------- Embedding (wave per token): x@W+b -> LN -> GELU ----------
__global__ __launch_bounds__(256) void embed4_kernel(
    const float* __restrict__ x, const float* __restrict__ Wemb,
    const float* __restrict__ bemb, const float* __restrict__ g,
    const float* __restrict__ be, const float* __restrict__ cls,
    float* __restrict__ h)
{
    int wave = threadIdx.x >> 6, lane = threadIdx.x & 63;
    int t = blockIdx.x * 4 + wave;          // M_ = 4*2050 exactly
    int b = t / S_, s = t % S_;
    long base = (long)t * E_ + lane * 4;

    if (s == 0) {
        *(float4*)(h + base) = *(const float4*)(cls + lane * 4);
        return;
    }
    const float* xr = x + ((long)b * N_ + (s - 1)) * C_;
    float xv[C_];
#pragma unroll
    for (int c = 0; c < C_; ++c) xv[c] = xr[c];

    float4 acc = *(const float4*)(bemb + lane * 4);
#pragma unroll
    for (int c = 0; c < C_; ++c) {
        float4 w = *(const float4*)(Wemb + c * E_ + lane * 4);
        acc.x += xv[c] * w.x; acc.y += xv[c] * w.y;
        acc.z += xv[c] * w.z; acc.w += xv[c] * w.w;
    }
    float sum = acc.x + acc.y + acc.z + acc.w;
    float sq  = acc.x*acc.x + acc.y*acc.y + acc.z*acc.z + acc.w*acc.w;
#pragma unroll
    for (int off = 1; off < 64; off <<= 1) {
        sum += __shfl_xor(sum, off);
        sq  += __shfl_xor(sq,  off);
    }
    float mean = sum * (1.0f / E_);
    float var  = sq * (1.0f / E_) - mean * mean;
    float rstd = rsqrtf(var + EPS_);
    float4 gg = *(const float4*)(g + lane * 4);
    float4 bb = *(const float4*)(be + lane * 4);
    float4 o;
    float v;
    v = (acc.x - mean) * rstd * gg.x + bb.x; o.x = 0.5f * v * (1.0f + erff(v * 0.70710678118f));
    v = (acc.y - mean) * rstd * gg.y + bb.y; o.y = 0.5f * v * (1.0f + erff(v * 0.70710678118f));
    v = (acc.z - mean) * rstd * gg.z + bb.z; o.z = 0.5f * v * (1.0f + erff(v * 0.70710678118f));
    v = (acc.w - mean) * rstd * gg.w + bb.w; o.w = 0.5f * v * (1.0f + erff(v * 0.70710678118f));
    *(float4*)(h + base) = o;
}

// ------------- LN (wave per token): optional h+=pos, y=bf16(LN(h)) ---------
__global__ __launch_bounds__(256) void ln4_kernel(
    float* __restrict__ h, const float* __restrict__ pos,
    const float* __restrict__ g, const float* __restrict__ bb,
    bf16* __restrict__ y)
{
    int wave = threadIdx.x >> 6, lane = threadIdx.x & 63;
    int t = blockIdx.x * 4 + wave;
    int s = t % S_;
    long base = (long)t * E_ + lane * 4;

    float4 v = *(const float4*)(h + base);
    if (pos) {
        float4 pv = *(const float4*)(pos + (long)s * E_ + lane * 4);
        v.x += pv.x; v.y += pv.y; v.z += pv.z; v.w += pv.w;
        *(float4*)(h + base) = v;
    }
    float sum = v.x + v.y + v.z + v.w;
    float sq  = v.x*v.x + v.y*v.y + v.z*v.z + v.w*v.w;
#pragma unroll
    for (int off = 1; off < 64; off <<= 1) {
        sum += __shfl_xor(sum, off);
        sq  += __shfl_xor(sq,  off);
    }
    float mean = sum * (1.0f / E_);
    float var  = sq * (1.0f / E_) - mean * mean;
    float rstd = rsqrtf(var + EPS_);
    float4 gg = *(const float4*)(g + lane * 4);
    float4 b4 = *(const float4*)(bb + lane * 4);
    bf16 o[4];
    o[0] = __float2bfloat16((v.x - mean) * rstd * gg.x + b4.x);
    o[1] = __float2bfloat16((v.y - mean) * rstd * gg.y + b4.y);
    o[2] = __float2bfloat16((v.z - mean) * rstd * gg.z + b4.z);
    o[3] = __float2bfloat16((v.w - mean) * rstd * gg.w + b4.w);
    *(uint2*)(y + base) = *(uint2*)o;
}

// ---------- Single-launch weight pack (LDS 32x32 transpose) ----------------
__global__ __launch_bounds__(256) void pack_all(
    const float* __restrict__ Wq, const float* __restrict__ Wk,
    const float* __restrict__ Wv, const float* __restrict__ bq,
    const float* __restrict__ bk, const float* __restrict__ bv,
    const float* __restrict__ Wo, const float* __restrict__ W1,
    const float* __restrict__ W2,
    bf16* __restrict__ Wqkvt, float* __restrict__ bqkv,
    bf16* __restrict__ Wot, bf16* __restrict__ W1t, bf16* __restrict__ W2t)
{
    __shared__ float tile[32][33];
    int id = blockIdx.x;
    int tx = threadIdx.x & 31, ty = threadIdx.x >> 5;   // 32x8
    const float* src; bf16* dst;
    int c0, k0, Nsrc, Kd, row0;

    if (id < 768) {                       // QKV: 4l x 8k x 24n
        int l = id / 192, r = id % 192;
        int nt = r % 24, kt2 = r / 24;
        int n0 = nt * 32; k0 = kt2 * 32;
        Nsrc = 256; Kd = 256; row0 = n0;
        if (n0 < 256)      { src = Wq + (long)l * 65536; c0 = n0; }
        else if (n0 < 512) { src = Wk + (long)l * 65536; c0 = n0 - 256; }
        else               { src = Wv + (long)l * 65536; c0 = n0 - 512; }
        dst = Wqkvt + (long)l * 768 * 256;
        if (kt2 == 0 && ty == 0) {
            const float* bsrc = (n0 < 256) ? bq + l * 256 + c0
                              : (n0 < 512) ? bk + l * 256 + c0 : bv + l * 256 + c0;
            bqkv[l * 768 + n0 + tx] = bsrc[tx];
        }
    } else if (id < 1024) {               // Wo
        int r = id - 768; int l = r / 64; r %= 64;
        int nt = r & 7, kt2 = r >> 3;
        c0 = nt * 32; k0 = kt2 * 32; Nsrc = 256; Kd = 256; row0 = c0;
        src = Wo + (long)l * 65536; dst = Wot + (long)l * 65536;
    } else if (id < 2048) {               // W1
        int r = id - 1024; int l = r / 256; r %= 256;
        int nt = r % 32, kt2 = r / 32;
        c0 = nt * 32; k0 = kt2 * 32; Nsrc = 1024; Kd = 256; row0 = c0;
        src = W1 + (long)l * 262144; dst = W1t + (long)l * 262144;
    } else {                              // W2
        int r = id - 2048; int l = r / 256; r %= 256;
        int nt = r & 7, kt2 = r >> 3;
        c0 = nt * 32; k0 = kt2 * 32; Nsrc = 256; Kd = 1024; row0 = c0;
        src = W2 + (long)l * 262144; dst = W2t + (long)l * 262144;
    }
#pragma unroll
    for (int i = 0; i < 4; ++i)
        tile[ty + i * 8][tx] = src[(long)(k0 + ty + i * 8) * Nsrc + c0 + tx];
    __syncthreads();
#pragma unroll
    for (int i = 0; i < 4; ++i)
        dst[(long)(row0 + ty + i * 8) * Kd + k0 + tx] = __float2bfloat16(tile[tx][ty + i * 8]);
}

// ---- bf16 MFMA GEMM, 64-row x NT-col tile, DMA staging + double buffer ----
// XOR-rotate swizzle on global chunk index (validated R14). NT in {32,64}.
// NT=32 halves per-block work -> 2x grid for TLP on low-parallelism shapes.
template<int NT>
__global__ __launch_bounds__(256) void gemm_bf16_t(
    const bf16* __restrict__ A, const bf16* __restrict__ Wt,
    const float* __restrict__ bias, const float* __restrict__ res,
    float* __restrict__ outF, bf16* __restrict__ outB,
    bf16* __restrict__ vTout, int M, int K, int N, int act)
{
    __shared__ bf16 As[2][64 * 64];        // 2 x 8 KB
    __shared__ bf16 Bs[2][NT * 64];        // 2 x (NT/64)*8 KB
    int tid = threadIdx.x;
    int wave = tid >> 6, lane = tid & 63;
    int quad = lane >> 4, l16 = lane & 15;
    int row0 = blockIdx.y * 64;
    int col0 = blockIdx.x * NT;

    int sr = lane >> 3;
    int sc = lane & 7;
    const int NB = 8 + NT / 8;             // total DMA groups (A:8, B:NT/8)

    f32x4 acc[NT / 16];
#pragma unroll
    for (int i = 0; i < NT / 16; ++i) acc[i] = (f32x4){0.f,0.f,0.f,0.f};
    int nk = K >> 6;

    // prologue: DMA tile 0 into buffer 0
#pragma unroll
    for (int gi = 0; gi < 4; ++gi) {
        int id = wave * 4 + gi;            // 0..15
        if (id >= NB) continue;
        int rr = (id < 8 ? id : id - 8) * 8 + sr;
        int cs = (sc - rr) & 7;
        if (id < 8) dma16(A  + (long)(row0 + rr) * K + cs * 8, &As[0][(id) * 8 * 64]);
        else        dma16(Wt + (long)(col0 + rr) * K + cs * 8, &Bs[0][(id - 8) * 8 * 64]);
    }
    for (int kt = 0; kt < nk; ++kt) {
        __syncthreads();
        int buf = kt & 1;
        if (kt < nk - 1) {
            int k1 = (kt + 1) << 6;
            int nb = buf ^ 1;
#pragma unroll
            for (int gi = 0; gi < 4; ++gi) {
                int id = wave * 4 + gi;
                if (id >= NB) continue;
                int rr = (id < 8 ? id : id - 8) * 8 + sr;
                int cs = (sc - rr) & 7;
                if (id < 8) dma16(A  + (long)(row0 + rr) * K + k1 + cs * 8, &As[nb][(id) * 8 * 64]);
                else        dma16(Wt + (long)(col0 + rr) * K + k1 + cs * 8, &Bs[nb][(id - 8) * 8 * 64]);
            }
        }
#pragma unroll
        for (int ks8 = 0; ks8 < 8; ks8 += 4) {
            int rra = wave * 16 + l16;
            bf16x8 af = *(const bf16x8*)&As[buf][rra * 64 + (((quad + ks8) + rra) & 7) * 8];
#pragma unroll
            for (int nt = 0; nt < NT / 16; ++nt) {
                int rrb = nt * 16 + l16;
                bf16x8 bf = *(const bf16x8*)&Bs[buf][rrb * 64 + (((quad + ks8) + rrb) & 7) * 8];
                acc[nt] = __builtin_amdgcn_mfma_f32_16x16x32_bf16(af, bf, acc[nt], 0, 0, 0);
            }
        }
    }
#pragma unroll
    for (int nt = 0; nt < NT / 16; ++nt) {
        int col = col0 + nt * 16 + l16;
#pragma unroll
        for (int r = 0; r < 4; ++r) {
            int m = row0 + wave * 16 + quad * 4 + r;
            if (m >= M) continue;
            float v = acc[nt][r] + bias[col];
            if (act == 1) v = 0.5f * v * (1.0f + erff(v * 0.70710678118f));
            if (res)  v += res[(long)m * N + col];
            if (outF) outF[(long)m * N + col] = v;
            bf16 bvv = __float2bfloat16(v);
            if (outB) outB[(long)m * N + col] = bvv;
            if (vTout && col >= 512) {     // V cols -> vT[bh][d][key]
                int b2 = m / S_;
                int key = m - b2 * S_;
                int cc = col - 512;
                vTout[((long)(b2 * 8 + (cc >> 5)) * 32 + (cc & 31)) * SP_ + key] = bvv;
            }
        }
    }
}

// --------------- MFMA flash attention v7: 64-query tiles (R19) -------------
#define NQT 17
__global__ __launch_bounds__(256) void attn_mfma7_kernel(
    const bf16* __restrict__ qkv, const bf16* __restrict__ vT,
    bf16* __restrict__ ob)
{
    __shared__ bf16 Ks[2][64 * 40];    // [key][d], row 80 B
    __shared__ bf16 Vs[2][32 * 80];    // [d][key], row 160 B
    __shared__ bf16 Pa[4][16 * 72];    // per-wave P [q][key], row 144 B

    int tid = threadIdx.x;
    int wave = tid >> 6, lane = tid & 63;
    int quad = lane >> 4, l16 = lane & 15;
    int bh = blockIdx.x / NQT, qt = blockIdx.x % NQT;
    int b = bh >> 3, hh = bh & 7;
    int q0 = qt * 64;
    long bS = (long)b * S_;
    bf16* Pw = Pa[wave];
    const bf16* vTb = vT + (long)bh * 32 * SP_;
    uint4 z4 = make_uint4(0,0,0,0);

    int skey = tid >> 2, sdg = tid & 3;
    int svd = tid >> 3, svc = tid & 7;

    bf16x8 aq = {0,0,0,0,0,0,0,0};
    {
        int gq = q0 + wave * 16 + l16;
        if (gq < S_) aq = *(const bf16x8*)(qkv + (bS + gq) * 768 + hh * 32 + quad * 8);
    }

    f32x4 o0 = {0.f,0.f,0.f,0.f}, o1 = {0.f,0.f,0.f,0.f};
    float lsum[4] = {0.f,0.f,0.f,0.f};
    f32x4 zf = {0.f,0.f,0.f,0.f};

    {   // prologue: stage tile 0
        int gk = skey;
        uint4 kv = z4;
        if (gk < S_) kv = *(const uint4*)(qkv + (bS + gk) * 768 + 256 + hh * 32 + sdg * 8);
        *(uint4*)&Ks[0][skey * 40 + sdg * 8] = kv;
        *(uint4*)&Vs[0][svd * 80 + svc * 8] = *(const uint4*)(vTb + (long)svd * SP_ + svc * 8);
    }

    for (int kt = 0; kt < NQT; ++kt) {
        int j0 = kt * 64;
        int bb = kt & 1;
        __syncthreads();

        if (kt < NQT - 1) {
            int j1 = j0 + 64;
            int gk = j1 + skey;
            uint4 kv = z4;
            if (gk < S_) kv = *(const uint4*)(qkv + (bS + gk) * 768 + 256 + hh * 32 + sdg * 8);
            *(uint4*)&Ks[bb ^ 1][skey * 40 + sdg * 8] = kv;
            *(uint4*)&Vs[bb ^ 1][svd * 80 + svc * 8] =
                *(const uint4*)(vTb + (long)svd * SP_ + j1 + svc * 8);
        }

        f32x4 sc[4];
#pragma unroll
        for (int t4 = 0; t4 < 4; ++t4) {
            bf16x8 bk = *(const bf16x8*)&Ks[bb][(t4 * 16 + l16) * 40 + quad * 8];
            sc[t4] = __builtin_amdgcn_mfma_f32_16x16x32_bf16(aq, bk, zf, 0, 0, 0);
        }
        if (kt < NQT - 1) {
#pragma unroll
            for (int t4 = 0; t4 < 4; ++t4)
#pragma unroll
                for (int r = 0; r < 4; ++r) {
                    float p = __expf(sc[t4][r]);
                    lsum[r] += p;
                    Pw[(quad * 4 + r) * 72 + t4 * 16 + l16] = __float2bfloat16(p);
                }
        } else {
#pragma unroll
            for (int t4 = 0; t4 < 4; ++t4) {
                bool valid = (j0 + t4 * 16 + l16) < S_;
#pragma unroll
                for (int r = 0; r < 4; ++r) {
                    float p = valid ? __expf(sc[t4][r]) : 0.f;
                    lsum[r] += p;
                    Pw[(quad * 4 + r) * 72 + t4 * 16 + l16] = __float2bfloat16(p);
                }
            }
        }
#pragma unroll
        for (int ks2 = 0; ks2 < 64; ks2 += 32) {
            bf16x8 ap = *(const bf16x8*)&Pw[l16 * 72 + ks2 + quad * 8];
            bf16x8 bv0 = *(const bf16x8*)&Vs[bb][l16 * 80 + ks2 + quad * 8];
            o0 = __builtin_amdgcn_mfma_f32_16x16x32_bf16(ap, bv0, o0, 0, 0, 0);
            bf16x8 bv1 = *(const bf16x8*)&Vs[bb][(16 + l16) * 80 + ks2 + quad * 8];
            o1 = __builtin_amdgcn_mfma_f32_16x16x32_bf16(ap, bv1, o1, 0, 0, 0);
        }
    }

#pragma unroll
    for (int r = 0; r < 4; ++r) {
        float t = lsum[r];
        t += __shfl_xor(t, 1); t += __shfl_xor(t, 2);
        t += __shfl_xor(t, 4); t += __shfl_xor(t, 8);
        float inv = 1.0f / (t * 16.0f);
        int gq = q0 + wave * 16 + quad * 4 + r;
        if (gq < S_) {
            long base = (bS + gq) * 256 + hh * 32;
            ob[base + l16]      = __float2bfloat16(o0[r] * inv);
            ob[base + 16 + l16] = __float2bfloat16(o1[r] * inv);
        }
    }
}

// --------------- Pool: partial[b][sc][e] = sum over 65-row chunk -----------
__global__ __launch_bounds__(256) void pool_kernel(const float* __restrict__ h,
                                                   float* __restrict__ partial)
{
    int b = blockIdx.x >> 4, sc = blockIdx.x & 15;
    int e = threadIdx.x;
    int s0 = sc * 65, s1 = min(S_, s0 + 65);
    float acc = 0.f;
    for (int s = s0; s < s1; ++s) acc += h[((long)b * S_ + s) * E_ + e];
    partial[((long)b * 16 + sc) * E_ + e] = acc;
}

// --------------- Classifier final: Linear -> LN -> Linear -----------------
__global__ __launch_bounds__(256) void cls_final(
    const float* __restrict__ partial, const float* __restrict__ Wc1,
    const float* __restrict__ bc1, const float* __restrict__ lg,
    const float* __restrict__ lb, const float* __restrict__ Wc2,
    const float* __restrict__ bc2, float* __restrict__ out)
{
    int b = blockIdx.x;
    int e = threadIdx.x;
    __shared__ float p[256];
    __shared__ float red[256];
    __shared__ float lnv[256];

    float acc = 0.f;
#pragma unroll
    for (int sc = 0; sc < 16; ++sc) acc += partial[((long)b * 16 + sc) * E_ + e];
    p[e] = acc * (1.0f / S_);
    __syncthreads();

    float c1 = bc1[e];
    for (int kk = 0; kk < E_; ++kk) c1 += p[kk] * Wc1[kk * E_ + e];

    red[e] = c1; __syncthreads();
    for (int st = 128; st; st >>= 1) { if (e < st) red[e] += red[e + st]; __syncthreads(); }
    float mean = red[0] * (1.0f / E_); __syncthreads();
    float d = c1 - mean;
    red[e] = d * d; __syncthreads();
    for (int st = 128; st; st >>= 1) { if (e < st) red[e] += red[e + st]; __syncthreads(); }
    float var = red[0] * (1.0f / E_);
    lnv[e] = d * rsqrtf(var + EPS_) * lg[e] + lb[e];
    __syncthreads();

    if (e < NC_) {
        float oacc = bc2[e];
        for (int kk = 0; kk < E_; ++kk) oacc += lnv[kk] * Wc2[kk * NC_ + e];
        out[b * NC_ + e] = oacc;
    }
}

extern "C" void kernel_launch(void* const* d_in, const int* in_sizes, int n_in,
                              void* d_out, int out_size, void* d_ws, size_t ws_size,
                              hipStream_t stream)
{
    const float* x      = (const float*)d_in[0];
    const float* W_emb  = (const float*)d_in[1];
    const float* b_emb  = (const float*)d_in[2];
    const float* g_emb  = (const float*)d_in[3];
    const float* be_emb = (const float*)d_in[4];
    const float* cls    = (const float*)d_in[5];
    const float* pos    = (const float*)d_in[6];
    const float* ln1_g  = (const float*)d_in[7];
    const float* ln1_b  = (const float*)d_in[8];
    const float* Wq     = (const float*)d_in[9];
    const float* bq     = (const float*)d_in[10];
    const float* Wk     = (const float*)d_in[11];
    const float* bk     = (const float*)d_in[12];
    const float* Wv     = (const float*)d_in[13];
    const float* bv     = (const float*)d_in[14];
    const float* Wo     = (const float*)d_in[15];
    const float* bo     = (const float*)d_in[16];
    const float* ln2_g  = (const float*)d_in[17];
    const float* ln2_b  = (const float*)d_in[18];
    const float* W1     = (const float*)d_in[19];
    const float* b1     = (const float*)d_in[20];
    const float* W2     = (const float*)d_in[21];
    const float* b2     = (const float*)d_in[22];
    const float* Wc1    = (const float*)d_in[23];
    const float* bc1    = (const float*)d_in[24];
    const float* lnc_g  = (const float*)d_in[25];
    const float* lnc_b  = (const float*)d_in[26];
    const float* Wc2    = (const float*)d_in[27];
    const float* bc2    = (const float*)d_in[28];
    float* out = (float*)d_out;

    char* p = (char*)d_ws;
    float* h    = (float*)p; p += (long)M_ * 256 * 4;
    bf16* y     = (bf16*)p;  p += (long)M_ * 256 * 2;
    bf16* qkv   = (bf16*)p;  p += (long)M_ * 768 * 2;
    bf16* obuf  = (bf16*)p;  p += (long)M_ * 256 * 2;
    bf16* tb    = (bf16*)p;  p += (long)M_ * 1024 * 2;
    bf16* Wqkvt = (bf16*)p;  p += (long)L_ * 768 * 256 * 2;
    bf16* Wot   = (bf16*)p;  p += (long)L_ * 256 * 256 * 2;
    bf16* W1t   = (bf16*)p;  p += (long)L_ * 1024 * 256 * 2;
    bf16* W2t   = (bf16*)p;  p += (long)L_ * 256 * 1024 * 2;
    float* bqkv = (float*)p; p += (long)L_ * 768 * 4;
    float* pool = (float*)p; p += (long)B_ * 16 * 256 * 4;
    bf16* vT    = (bf16*)p;  p += (long)64 * 32 * SP_ * 2;

    // ---- weight packing (1 launch) ----
    pack_all<<<3072, 256, 0, stream>>>(Wq, Wk, Wv, bq, bk, bv, Wo, W1, W2,
                                       Wqkvt, bqkv, Wot, W1t, W2t);

    embed4_kernel<<<M_ / 4, 256, 0, stream>>>(x, W_emb, b_emb, g_emb, be_emb, cls, h);

    dim3 gQKV(12, 129), gMLP1(16, 129), gEE32(8, 129);
    for (int l = 0; l < L_; ++l) {
        // h += pos; y = LN1(h)
        ln4_kernel<<<M_ / 4, 256, 0, stream>>>(h, pos, ln1_g + l * E_, ln1_b + l * E_, y);
        // qkv = y @ Wqkv + b (V cols also -> vT, transposed)
        gemm_bf16_t<64><<<gQKV, 256, 0, stream>>>(y, Wqkvt + (long)l * 768 * 256, bqkv + l * 768,
                                                  nullptr, nullptr, qkv, vT, M_, 256, 768, 0);
        attn_mfma7_kernel<<<64 * NQT, 256, 0, stream>>>(qkv, vT, obuf);
        // h += o @ Wo + bo   (32-col tiles: 2x grid for TLP)
        gemm_bf16_t<32><<<gEE32, 256, 0, stream>>>(obuf, Wot + (long)l * 65536, bo + l * E_,
                                                   h, h, nullptr, nullptr, M_, 256, 256, 0);
        // y = LN2(h); tb = GELU(y @ W1 + b1)
        ln4_kernel<<<M_ / 4, 256, 0, stream>>>(h, nullptr, ln2_g + l * E_, ln2_b + l * E_, y);
        gemm_bf16_t<64><<<gMLP1, 256, 0, stream>>>(y, W1t + (long)l * 262144, b1 + l * XE_,
                                                   nullptr, nullptr, tb, nullptr, M_, 256, 1024, 1);
        // h += tb @ W2 + b2  (32-col tiles)
        gemm_bf16_t<32><<<gEE32, 256, 0, stream>>>(tb, W2t + (long)l * 262144, b2 + l * E_,
                                                   h, h, nullptr, nullptr, M_, 1024, 256, 0);
    }

    pool_kernel<<<B_ * 16, 256, 0, stream>>>(h, pool);
    cls_final<<<B_, 256, 0, stream>>>(pool, Wc1, bc1, lnc_g, lnc_b, Wc2, bc2, out);
}

// Round 21
// 619.456 us; speedup vs baseline: 1.3256x; 1.0645x over previous
//
#include <hip/hip_runtime.h>
#include <hip/hip_bf16.h>
#include <math.h>

// Problem constants
#define B_  8
#define N_  1024
#define C_  12
#define E_  256
#define H_  8
#define D_  32      // E/H
#define L_  4
#define XE_ 1024    // X*E
#define NC_ 5
#define S_  1025    // N+1
#define M_  8200    // B*S
#define EPS_ 1e-5f
#define SP_ 1088    // padded key-stride for vT (17*64, 16B-aligned)

typedef short bf16x8 __attribute__((ext_vector_type(8)));
typedef float f32x4 __attribute__((ext_vector_type(4)));
typedef __hip_bfloat16 bf16;

// async global->LDS DMA, 16 B per lane; LDS dest = wave-uniform base + lane*16
typedef __attribute__((address_space(1))) const unsigned int* as1_cuint;
typedef __attribute__((address_space(3))) unsigned int* as3_uint;
__device__ __forceinline__ void dma16(const void* g, void* l) {
    __builtin_amdgcn_global_load_lds((as1_cuint)g, (as3_uint)l, 16, 0, 0);
}

// ---------------- Embedding (wave per token): x@W+b -> LN -> GELU ----------
__global__ __launch_bounds__(256) void embed4_kernel(
    const float* __restrict__ x, const float* __restrict__ Wemb,
    const float* __restrict__ bemb, const float* __restrict__ g,
    const float* __restrict__ be, const float* __restrict__ cls,
    float* __restrict__ h)
{
    int wave = threadIdx.x >> 6, lane = threadIdx.x & 63;
    int t = blockIdx.x * 4 + wave;          // M_ = 4*2050 exactly
    int b = t / S_, s = t % S_;
    long base = (long)t * E_ + lane * 4;

    if (s == 0) {
        *(float4*)(h + base) = *(const float4*)(cls + lane * 4);
        return;
    }
    const float* xr = x + ((long)b * N_ + (s - 1)) * C_;
    float xv[C_];
#pragma unroll
    for (int c = 0; c < C_; ++c) xv[c] = xr[c];

    float4 acc = *(const float4*)(bemb + lane * 4);
#pragma unroll
    for (int c = 0; c < C_; ++c) {
        float4 w = *(const float4*)(Wemb + c * E_ + lane * 4);
        acc.x += xv[c] * w.x; acc.y += xv[c] * w.y;
        acc.z += xv[c] * w.z; acc.w += xv[c] * w.w;
    }
    float sum = acc.x + acc.y + acc.z + acc.w;
    float sq  = acc.x*acc.x + acc.y*acc.y + acc.z*acc.z + acc.w*acc.w;
#pragma unroll
    for (int off = 1; off < 64; off <<= 1) {
        sum += __shfl_xor(sum, off);
        sq  += __shfl_xor(sq,  off);
    }
    float mean = sum * (1.0f / E_);
    float var  = sq * (1.0f / E_) - mean * mean;
    float rstd = rsqrtf(var + EPS_);
    float4 gg = *(const float4*)(g + lane * 4);
    float4 bb = *(const float4*)(be + lane * 4);
    float4 o;
    float v;
    v = (acc.x - mean) * rstd * gg.x + bb.x; o.x = 0.5f * v * (1.0f + erff(v * 0.70710678118f));
    v = (acc.y - mean) * rstd * gg.y + bb.y; o.y = 0.5f * v * (1.0f + erff(v * 0.70710678118f));
    v = (acc.z - mean) * rstd * gg.z + bb.z; o.z = 0.5f * v * (1.0f + erff(v * 0.70710678118f));
    v = (acc.w - mean) * rstd * gg.w + bb.w; o.w = 0.5f * v * (1.0f + erff(v * 0.70710678118f));
    *(float4*)(h + base) = o;
}

// ------------- LN (wave per token): optional h+=pos, y=bf16(LN(h)) ---------
__global__ __launch_bounds__(256) void ln4_kernel(
    float* __restrict__ h, const float* __restrict__ pos,
    const float* __restrict__ g, const float* __restrict__ bb,
    bf16* __restrict__ y)
{
    int wave = threadIdx.x >> 6, lane = threadIdx.x & 63;
    int t = blockIdx.x * 4 + wave;
    int s = t % S_;
    long base = (long)t * E_ + lane * 4;

    float4 v = *(const float4*)(h + base);
    if (pos) {
        float4 pv = *(const float4*)(pos + (long)s * E_ + lane * 4);
        v.x += pv.x; v.y += pv.y; v.z += pv.z; v.w += pv.w;
        *(float4*)(h + base) = v;
    }
    float sum = v.x + v.y + v.z + v.w;
    float sq  = v.x*v.x + v.y*v.y + v.z*v.z + v.w*v.w;
#pragma unroll
    for (int off = 1; off < 64; off <<= 1) {
        sum += __shfl_xor(sum, off);
        sq  += __shfl_xor(sq,  off);
    }
    float mean = sum * (1.0f / E_);
    float var  = sq * (1.0f / E_) - mean * mean;
    float rstd = rsqrtf(var + EPS_);
    float4 gg = *(const float4*)(g + lane * 4);
    float4 b4 = *(const float4*)(bb + lane * 4);
    bf16 o[4];
    o[0] = __float2bfloat16((v.x - mean) * rstd * gg.x + b4.x);
    o[1] = __float2bfloat16((v.y - mean) * rstd * gg.y + b4.y);
    o[2] = __float2bfloat16((v.z - mean) * rstd * gg.z + b4.z);
    o[3] = __float2bfloat16((v.w - mean) * rstd * gg.w + b4.w);
    *(uint2*)(y + base) = *(uint2*)o;
}

// ---------- Single-launch weight pack (LDS 32x32 transpose) ----------------
__global__ __launch_bounds__(256) void pack_all(
    const float* __restrict__ Wq, const float* __restrict__ Wk,
    const float* __restrict__ Wv, const float* __restrict__ bq,
    const float* __restrict__ bk, const float* __restrict__ bv,
    const float* __restrict__ Wo, const float* __restrict__ W1,
    const float* __restrict__ W2,
    bf16* __restrict__ Wqkvt, float* __restrict__ bqkv,
    bf16* __restrict__ Wot, bf16* __restrict__ W1t, bf16* __restrict__ W2t)
{
    __shared__ float tile[32][33];
    int id = blockIdx.x;
    int tx = threadIdx.x & 31, ty = threadIdx.x >> 5;   // 32x8
    const float* src; bf16* dst;
    int c0, k0, Nsrc, Kd, row0;

    if (id < 768) {                       // QKV: 4l x 8k x 24n
        int l = id / 192, r = id % 192;
        int nt = r % 24, kt2 = r / 24;
        int n0 = nt * 32; k0 = kt2 * 32;
        Nsrc = 256; Kd = 256; row0 = n0;
        if (n0 < 256)      { src = Wq + (long)l * 65536; c0 = n0; }
        else if (n0 < 512) { src = Wk + (long)l * 65536; c0 = n0 - 256; }
        else               { src = Wv + (long)l * 65536; c0 = n0 - 512; }
        dst = Wqkvt + (long)l * 768 * 256;
        if (kt2 == 0 && ty == 0) {
            const float* bsrc = (n0 < 256) ? bq + l * 256 + c0
                              : (n0 < 512) ? bk + l * 256 + c0 : bv + l * 256 + c0;
            bqkv[l * 768 + n0 + tx] = bsrc[tx];
        }
    } else if (id < 1024) {               // Wo
        int r = id - 768; int l = r / 64; r %= 64;
        int nt = r & 7, kt2 = r >> 3;
        c0 = nt * 32; k0 = kt2 * 32; Nsrc = 256; Kd = 256; row0 = c0;
        src = Wo + (long)l * 65536; dst = Wot + (long)l * 65536;
    } else if (id < 2048) {               // W1
        int r = id - 1024; int l = r / 256; r %= 256;
        int nt = r % 32, kt2 = r / 32;
        c0 = nt * 32; k0 = kt2 * 32; Nsrc = 1024; Kd = 256; row0 = c0;
        src = W1 + (long)l * 262144; dst = W1t + (long)l * 262144;
    } else {                              // W2
        int r = id - 2048; int l = r / 256; r %= 256;
        int nt = r & 7, kt2 = r >> 3;
        c0 = nt * 32; k0 = kt2 * 32; Nsrc = 256; Kd = 1024; row0 = c0;
        src = W2 + (long)l * 262144; dst = W2t + (long)l * 262144;
    }
#pragma unroll
    for (int i = 0; i < 4; ++i)
        tile[ty + i * 8][tx] = src[(long)(k0 + ty + i * 8) * Nsrc + c0 + tx];
    __syncthreads();
#pragma unroll
    for (int i = 0; i < 4; ++i)
        dst[(long)(row0 + ty + i * 8) * Kd + k0 + tx] = __float2bfloat16(tile[tx][ty + i * 8]);
}

// ---- bf16 MFMA GEMM, 64-row x 64-col tile, DMA staging + double buffer ----
__global__ __launch_bounds__(256) void gemm_bf16_64(
    const bf16* __restrict__ A, const bf16* __restrict__ Wt,
    const float* __restrict__ bias, const float* __restrict__ res,
    float* __restrict__ outF, bf16* __restrict__ outB,
    bf16* __restrict__ vTout, int M, int K, int N, int act)
{
    __shared__ bf16 As[2][64 * 64];    // 2 x 8 KB
    __shared__ bf16 Bs[2][64 * 64];    // 2 x 8 KB
    int tid = threadIdx.x;
    int wave = tid >> 6, lane = tid & 63;
    int quad = lane >> 4, l16 = lane & 15;
    int row0 = blockIdx.y * 64;
    int col0 = blockIdx.x * 64;

    int sr = lane >> 3;
    int sc = lane & 7;

    f32x4 acc[4] = {{0.f,0.f,0.f,0.f},{0.f,0.f,0.f,0.f},{0.f,0.f,0.f,0.f},{0.f,0.f,0.f,0.f}};
    int nk = K >> 6;

#pragma unroll
    for (int gi = 0; gi < 4; ++gi) {
        int id = wave * 4 + gi;           // 0..15 (A:0-7, B:8-15)
        int rr = (id & 7) * 8 + sr;
        int cs = (sc - rr) & 7;
        if (id < 8) dma16(A  + (long)(row0 + rr) * K + cs * 8, &As[0][(id & 7) * 8 * 64]);
        else        dma16(Wt + (long)(col0 + rr) * K + cs * 8, &Bs[0][(id & 7) * 8 * 64]);
    }
    for (int kt = 0; kt < nk; ++kt) {
        __syncthreads();
        int buf = kt & 1;
        if (kt < nk - 1) {
            int k1 = (kt + 1) << 6;
            int nb = buf ^ 1;
#pragma unroll
            for (int gi = 0; gi < 4; ++gi) {
                int id = wave * 4 + gi;
                int rr = (id & 7) * 8 + sr;
                int cs = (sc - rr) & 7;
                if (id < 8) dma16(A  + (long)(row0 + rr) * K + k1 + cs * 8, &As[nb][(id & 7) * 8 * 64]);
                else        dma16(Wt + (long)(col0 + rr) * K + k1 + cs * 8, &Bs[nb][(id & 7) * 8 * 64]);
            }
        }
#pragma unroll
        for (int ks8 = 0; ks8 < 8; ks8 += 4) {
            int rra = wave * 16 + l16;
            bf16x8 af = *(const bf16x8*)&As[buf][rra * 64 + (((quad + ks8) + rra) & 7) * 8];
#pragma unroll
            for (int nt = 0; nt < 4; ++nt) {
                int rrb = nt * 16 + l16;
                bf16x8 bf = *(const bf16x8*)&Bs[buf][rrb * 64 + (((quad + ks8) + rrb) & 7) * 8];
                acc[nt] = __builtin_amdgcn_mfma_f32_16x16x32_bf16(af, bf, acc[nt], 0, 0, 0);
            }
        }
    }
#pragma unroll
    for (int nt = 0; nt < 4; ++nt) {
        int col = col0 + nt * 16 + l16;
#pragma unroll
        for (int r = 0; r < 4; ++r) {
            int m = row0 + wave * 16 + quad * 4 + r;
            if (m >= M) continue;
            float v = acc[nt][r] + bias[col];
            if (act == 1) v = 0.5f * v * (1.0f + erff(v * 0.70710678118f));
            if (res)  v += res[(long)m * N + col];
            if (outF) outF[(long)m * N + col] = v;
            bf16 bvv = __float2bfloat16(v);
            if (outB) outB[(long)m * N + col] = bvv;
            if (vTout && col >= 512) {    // V cols -> vT[bh][d][key]
                int b2 = m / S_;
                int key = m - b2 * S_;
                int cc = col - 512;
                vTout[((long)(b2 * 8 + (cc >> 5)) * 32 + (cc & 31)) * SP_ + key] = bvv;
            }
        }
    }
}

// ---- bf16 MFMA GEMM, 32-row x 64-col tile (Wo / MLP2) ---------------------
// Wave w: row-frag (w&1), col-half (w>>1)*32 (2 frags). LDS 24 KB -> 6/CU.
// Grid (N/64, ceil(M/32)) = 1028 blocks for N=256.
__global__ __launch_bounds__(256) void gemm_bf16_32x64(
    const bf16* __restrict__ A, const bf16* __restrict__ Wt,
    const float* __restrict__ bias, const float* __restrict__ res,
    float* __restrict__ outF, bf16* __restrict__ outB,
    int M, int K, int N, int act)
{
    __shared__ bf16 As[2][32 * 64];    // 2 x 4 KB
    __shared__ bf16 Bs[2][64 * 64];    // 2 x 8 KB
    int tid = threadIdx.x;
    int wave = tid >> 6, lane = tid & 63;
    int quad = lane >> 4, l16 = lane & 15;
    int rw = wave & 1, cw = wave >> 1;
    int row0 = blockIdx.y * 32;
    int col0 = blockIdx.x * 64;

    int sr = lane >> 3;
    int sc = lane & 7;

    f32x4 acc[2] = {{0.f,0.f,0.f,0.f},{0.f,0.f,0.f,0.f}};
    int nk = K >> 6;

    // 12 DMA groups: 0..3 A (32 rows), 4..11 B (64 rows); 3 per wave
#pragma unroll
    for (int gi = 0; gi < 3; ++gi) {
        int id = wave * 3 + gi;           // 0..11
        if (id < 4) {
            int rr = id * 8 + sr;
            int cs = (sc - rr) & 7;
            dma16(A + (long)(row0 + rr) * K + cs * 8, &As[0][id * 8 * 64]);
        } else {
            int rr = (id - 4) * 8 + sr;
            int cs = (sc - rr) & 7;
            dma16(Wt + (long)(col0 + rr) * K + cs * 8, &Bs[0][(id - 4) * 8 * 64]);
        }
    }
    for (int kt = 0; kt < nk; ++kt) {
        __syncthreads();
        int buf = kt & 1;
        if (kt < nk - 1) {
            int k1 = (kt + 1) << 6;
            int nb = buf ^ 1;
#pragma unroll
            for (int gi = 0; gi < 3; ++gi) {
                int id = wave * 3 + gi;
                if (id < 4) {
                    int rr = id * 8 + sr;
                    int cs = (sc - rr) & 7;
                    dma16(A + (long)(row0 + rr) * K + k1 + cs * 8, &As[nb][id * 8 * 64]);
                } else {
                    int rr = (id - 4) * 8 + sr;
                    int cs = (sc - rr) & 7;
                    dma16(Wt + (long)(col0 + rr) * K + k1 + cs * 8, &Bs[nb][(id - 4) * 8 * 64]);
                }
            }
        }
#pragma unroll
        for (int ks8 = 0; ks8 < 8; ks8 += 4) {
            int rra = rw * 16 + l16;
            bf16x8 af = *(const bf16x8*)&As[buf][rra * 64 + (((quad + ks8) + rra) & 7) * 8];
#pragma unroll
            for (int nt = 0; nt < 2; ++nt) {
                int rrb = cw * 32 + nt * 16 + l16;
                bf16x8 bf = *(const bf16x8*)&Bs[buf][rrb * 64 + (((quad + ks8) + rrb) & 7) * 8];
                acc[nt] = __builtin_amdgcn_mfma_f32_16x16x32_bf16(af, bf, acc[nt], 0, 0, 0);
            }
        }
    }
#pragma unroll
    for (int nt = 0; nt < 2; ++nt) {
        int col = col0 + cw * 32 + nt * 16 + l16;
#pragma unroll
        for (int r = 0; r < 4; ++r) {
            int m = row0 + rw * 16 + quad * 4 + r;
            if (m >= M) continue;
            float v = acc[nt][r] + bias[col];
            if (act == 1) v = 0.5f * v * (1.0f + erff(v * 0.70710678118f));
            if (res)  v += res[(long)m * N + col];
            if (outF) outF[(long)m * N + col] = v;
            if (outB) outB[(long)m * N + col] = __float2bfloat16(v);
        }
    }
}

// --------------- MFMA flash attention v8: 64-q tiles, Vs stride 72 ---------
#define NQT 17
__global__ __launch_bounds__(256) void attn_mfma8_kernel(
    const bf16* __restrict__ qkv, const bf16* __restrict__ vT,
    bf16* __restrict__ ob)
{
    __shared__ bf16 Ks[2][64 * 40];    // [key][d], row 80 B
    __shared__ bf16 Vs[2][32 * 72];    // [d][key], row 144 B (2-way banks)
    __shared__ bf16 Pa[4][16 * 72];    // per-wave P [q][key], row 144 B

    int tid = threadIdx.x;
    int wave = tid >> 6, lane = tid & 63;
    int quad = lane >> 4, l16 = lane & 15;
    int bh = blockIdx.x / NQT, qt = blockIdx.x % NQT;
    int b = bh >> 3, hh = bh & 7;
    int q0 = qt * 64;
    long bS = (long)b * S_;
    bf16* Pw = Pa[wave];
    const bf16* vTb = vT + (long)bh * 32 * SP_;
    uint4 z4 = make_uint4(0,0,0,0);

    int skey = tid >> 2, sdg = tid & 3;
    int svd = tid >> 3, svc = tid & 7;

    bf16x8 aq = {0,0,0,0,0,0,0,0};
    {
        int gq = q0 + wave * 16 + l16;
        if (gq < S_) aq = *(const bf16x8*)(qkv + (bS + gq) * 768 + hh * 32 + quad * 8);
    }

    f32x4 o0 = {0.f,0.f,0.f,0.f}, o1 = {0.f,0.f,0.f,0.f};
    float lsum[4] = {0.f,0.f,0.f,0.f};
    f32x4 zf = {0.f,0.f,0.f,0.f};

    {   // prologue: stage tile 0
        int gk = skey;
        uint4 kv = z4;
        if (gk < S_) kv = *(const uint4*)(qkv + (bS + gk) * 768 + 256 + hh * 32 + sdg * 8);
        *(uint4*)&Ks[0][skey * 40 + sdg * 8] = kv;
        *(uint4*)&Vs[0][svd * 72 + svc * 8] = *(const uint4*)(vTb + (long)svd * SP_ + svc * 8);
    }

    for (int kt = 0; kt < NQT; ++kt) {
        int j0 = kt * 64;
        int bb = kt & 1;
        __syncthreads();

        if (kt < NQT - 1) {
            int j1 = j0 + 64;
            int gk = j1 + skey;
            uint4 kv = z4;
            if (gk < S_) kv = *(const uint4*)(qkv + (bS + gk) * 768 + 256 + hh * 32 + sdg * 8);
            *(uint4*)&Ks[bb ^ 1][skey * 40 + sdg * 8] = kv;
            *(uint4*)&Vs[bb ^ 1][svd * 72 + svc * 8] =
                *(const uint4*)(vTb + (long)svd * SP_ + j1 + svc * 8);
        }

        f32x4 sc[4];
#pragma unroll
        for (int t4 = 0; t4 < 4; ++t4) {
            bf16x8 bk = *(const bf16x8*)&Ks[bb][(t4 * 16 + l16) * 40 + quad * 8];
            sc[t4] = __builtin_amdgcn_mfma_f32_16x16x32_bf16(aq, bk, zf, 0, 0, 0);
        }
        if (kt < NQT - 1) {
#pragma unroll
            for (int t4 = 0; t4 < 4; ++t4)
#pragma unroll
                for (int r = 0; r < 4; ++r) {
                    float p = __expf(sc[t4][r]);
                    lsum[r] += p;
                    Pw[(quad * 4 + r) * 72 + t4 * 16 + l16] = __float2bfloat16(p);
                }
        } else {
#pragma unroll
            for (int t4 = 0; t4 < 4; ++t4) {
                bool valid = (j0 + t4 * 16 + l16) < S_;
#pragma unroll
                for (int r = 0; r < 4; ++r) {
                    float p = valid ? __expf(sc[t4][r]) : 0.f;
                    lsum[r] += p;
                    Pw[(quad * 4 + r) * 72 + t4 * 16 + l16] = __float2bfloat16(p);
                }
            }
        }
#pragma unroll
        for (int ks2 = 0; ks2 < 64; ks2 += 32) {
            bf16x8 ap = *(const bf16x8*)&Pw[l16 * 72 + ks2 + quad * 8];
            bf16x8 bv0 = *(const bf16x8*)&Vs[bb][l16 * 72 + ks2 + quad * 8];
            o0 = __builtin_amdgcn_mfma_f32_16x16x32_bf16(ap, bv0, o0, 0, 0, 0);
            bf16x8 bv1 = *(const bf16x8*)&Vs[bb][(16 + l16) * 72 + ks2 + quad * 8];
            o1 = __builtin_amdgcn_mfma_f32_16x16x32_bf16(ap, bv1, o1, 0, 0, 0);
        }
    }

#pragma unroll
    for (int r = 0; r < 4; ++r) {
        float t = lsum[r];
        t += __shfl_xor(t, 1); t += __shfl_xor(t, 2);
        t += __shfl_xor(t, 4); t += __shfl_xor(t, 8);
        float inv = 1.0f / (t * 16.0f);
        int gq = q0 + wave * 16 + quad * 4 + r;
        if (gq < S_) {
            long base = (bS + gq) * 256 + hh * 32;
            ob[base + l16]      = __float2bfloat16(o0[r] * inv);
            ob[base + 16 + l16] = __float2bfloat16(o1[r] * inv);
        }
    }
}

// --------------- Pool: partial[b][sc][e] = sum over 65-row chunk -----------
__global__ __launch_bounds__(256) void pool_kernel(const float* __restrict__ h,
                                                   float* __restrict__ partial)
{
    int b = blockIdx.x >> 4, sc = blockIdx.x & 15;
    int e = threadIdx.x;
    int s0 = sc * 65, s1 = min(S_, s0 + 65);
    float acc = 0.f;
    for (int s = s0; s < s1; ++s) acc += h[((long)b * S_ + s) * E_ + e];
    partial[((long)b * 16 + sc) * E_ + e] = acc;
}

// --------------- Classifier final: Linear -> LN -> Linear -----------------
__global__ __launch_bounds__(256) void cls_final(
    const float* __restrict__ partial, const float* __restrict__ Wc1,
    const float* __restrict__ bc1, const float* __restrict__ lg,
    const float* __restrict__ lb, const float* __restrict__ Wc2,
    const float* __restrict__ bc2, float* __restrict__ out)
{
    int b = blockIdx.x;
    int e = threadIdx.x;
    __shared__ float p[256];
    __shared__ float red[256];
    __shared__ float lnv[256];

    float acc = 0.f;
#pragma unroll
    for (int sc = 0; sc < 16; ++sc) acc += partial[((long)b * 16 + sc) * E_ + e];
    p[e] = acc * (1.0f / S_);
    __syncthreads();

    float c1 = bc1[e];
    for (int kk = 0; kk < E_; ++kk) c1 += p[kk] * Wc1[kk * E_ + e];

    red[e] = c1; __syncthreads();
    for (int st = 128; st; st >>= 1) { if (e < st) red[e] += red[e + st]; __syncthreads(); }
    float mean = red[0] * (1.0f / E_); __syncthreads();
    float d = c1 - mean;
    red[e] = d * d; __syncthreads();
    for (int st = 128; st; st >>= 1) { if (e < st) red[e] += red[e + st]; __syncthreads(); }
    float var = red[0] * (1.0f / E_);
    lnv[e] = d * rsqrtf(var + EPS_) * lg[e] + lb[e];
    __syncthreads();

    if (e < NC_) {
        float oacc = bc2[e];
        for (int kk = 0; kk < E_; ++kk) oacc += lnv[kk] * Wc2[kk * NC_ + e];
        out[b * NC_ + e] = oacc;
    }
}

extern "C" void kernel_launch(void* const* d_in, const int* in_sizes, int n_in,
                              void* d_out, int out_size, void* d_ws, size_t ws_size,
                              hipStream_t stream)
{
    const float* x      = (const float*)d_in[0];
    const float* W_emb  = (const float*)d_in[1];
    const float* b_emb  = (const float*)d_in[2];
    const float* g_emb  = (const float*)d_in[3];
    const float* be_emb = (const float*)d_in[4];
    const float* cls    = (const float*)d_in[5];
    const float* pos    = (const float*)d_in[6];
    const float* ln1_g  = (const float*)d_in[7];
    const float* ln1_b  = (const float*)d_in[8];
    const float* Wq     = (const float*)d_in[9];
    const float* bq     = (const float*)d_in[10];
    const float* Wk     = (const float*)d_in[11];
    const float* bk     = (const float*)d_in[12];
    const float* Wv     = (const float*)d_in[13];
    const float* bv     = (const float*)d_in[14];
    const float* Wo     = (const float*)d_in[15];
    const float* bo     = (const float*)d_in[16];
    const float* ln2_g  = (const float*)d_in[17];
    const float* ln2_b  = (const float*)d_in[18];
    const float* W1     = (const float*)d_in[19];
    const float* b1     = (const float*)d_in[20];
    const float* W2     = (const float*)d_in[21];
    const float* b2     = (const float*)d_in[22];
    const float* Wc1    = (const float*)d_in[23];
    const float* bc1    = (const float*)d_in[24];
    const float* lnc_g  = (const float*)d_in[25];
    const float* lnc_b  = (const float*)d_in[26];
    const float* Wc2    = (const float*)d_in[27];
    const float* bc2    = (const float*)d_in[28];
    float* out = (float*)d_out;

    char* p = (char*)d_ws;
    float* h    = (float*)p; p += (long)M_ * 256 * 4;
    bf16* y     = (bf16*)p;  p += (long)M_ * 256 * 2;
    bf16* qkv   = (bf16*)p;  p += (long)M_ * 768 * 2;
    bf16* obuf  = (bf16*)p;  p += (long)M_ * 256 * 2;
    bf16* tb    = (bf16*)p;  p += (long)M_ * 1024 * 2;
    bf16* Wqkvt = (bf16*)p;  p += (long)L_ * 768 * 256 * 2;
    bf16* Wot   = (bf16*)p;  p += (long)L_ * 256 * 256 * 2;
    bf16* W1t   = (bf16*)p;  p += (long)L_ * 1024 * 256 * 2;
    bf16* W2t   = (bf16*)p;  p += (long)L_ * 256 * 1024 * 2;
    float* bqkv = (float*)p; p += (long)L_ * 768 * 4;
    float* pool = (float*)p; p += (long)B_ * 16 * 256 * 4;
    bf16* vT    = (bf16*)p;  p += (long)64 * 32 * SP_ * 2;

    // ---- weight packing (1 launch) ----
    pack_all<<<3072, 256, 0, stream>>>(Wq, Wk, Wv, bq, bk, bv, Wo, W1, W2,
                                       Wqkvt, bqkv, Wot, W1t, W2t);

    embed4_kernel<<<M_ / 4, 256, 0, stream>>>(x, W_emb, b_emb, g_emb, be_emb, cls, h);

    dim3 gQKV(12, 129), gMLP1(16, 129), gEE(4, 257);
    for (int l = 0; l < L_; ++l) {
        // h += pos; y = LN1(h)
        ln4_kernel<<<M_ / 4, 256, 0, stream>>>(h, pos, ln1_g + l * E_, ln1_b + l * E_, y);
        // qkv = y @ Wqkv + b (V cols also -> vT, transposed)
        gemm_bf16_64<<<gQKV, 256, 0, stream>>>(y, Wqkvt + (long)l * 768 * 256, bqkv + l * 768,
                                               nullptr, nullptr, qkv, vT, M_, 256, 768, 0);
        attn_mfma8_kernel<<<64 * NQT, 256, 0, stream>>>(qkv, vT, obuf);
        // h += o @ Wo + bo   (32x64 tiles)
        gemm_bf16_32x64<<<gEE, 256, 0, stream>>>(obuf, Wot + (long)l * 65536, bo + l * E_,
                                                 h, h, nullptr, M_, 256, 256, 0);
        // y = LN2(h); tb = GELU(y @ W1 + b1)
        ln4_kernel<<<M_ / 4, 256, 0, stream>>>(h, nullptr, ln2_g + l * E_, ln2_b + l * E_, y);
        gemm_bf16_64<<<gMLP1, 256, 0, stream>>>(y, W1t + (long)l * 262144, b1 + l * XE_,
                                                nullptr, nullptr, tb, nullptr, M_, 256, 1024, 1);
        // h += tb @ W2 + b2  (32x64 tiles)
        gemm_bf16_32x64<<<gEE, 256, 0, stream>>>(tb, W2t + (long)l * 262144, b2 + l * E_,
                                                 h, h, nullptr, M_, 1024, 256, 0);
    }

    pool_kernel<<<B_ * 16, 256, 0, stream>>>(h, pool);
    cls_final<<<B_, 256, 0, stream>>>(pool, Wc1, bc1, lnc_g, lnc_b, Wc2, bc2, out);
}

// Round 22
// 593.502 us; speedup vs baseline: 1.3836x; 1.0437x over previous
//
#include <hip/hip_runtime.h>
#include <hip/hip_bf16.h>
#include <math.h>

// Problem constants
#define B_  8
#define N_  1024
#define C_  12
#define E_  256
#define H_  8
#define D_  32      // E/H
#define L_  4
#define XE_ 1024    // X*E
#define NC_ 5
#define S_  1025    // N+1
#define M_  8200    // B*S
#define EPS_ 1e-5f
#define SP_ 1088    // padded key-stride for vT (17*64, 16B-aligned)

typedef short bf16x8 __attribute__((ext_vector_type(8)));
typedef float f32x4 __attribute__((ext_vector_type(4)));
typedef __hip_bfloat16 bf16;

// async global->LDS DMA, 16 B per lane; LDS dest = wave-uniform base + lane*16
typedef __attribute__((address_space(1))) const unsigned int* as1_cuint;
typedef __attribute__((address_space(3))) unsigned int* as3_uint;
__device__ __forceinline__ void dma16(const void* g, void* l) {
    __builtin_amdgcn_global_load_lds((as1_cuint)g, (as3_uint)l, 16, 0, 0);
}

// ---------------- Embedding (wave per token): x@W+b -> LN -> GELU ----------
__global__ __launch_bounds__(256) void embed4_kernel(
    const float* __restrict__ x, const float* __restrict__ Wemb,
    const float* __restrict__ bemb, const float* __restrict__ g,
    const float* __restrict__ be, const float* __restrict__ cls,
    float* __restrict__ h)
{
    int wave = threadIdx.x >> 6, lane = threadIdx.x & 63;
    int t = blockIdx.x * 4 + wave;          // M_ = 4*2050 exactly
    int b = t / S_, s = t % S_;
    long base = (long)t * E_ + lane * 4;

    if (s == 0) {
        *(float4*)(h + base) = *(const float4*)(cls + lane * 4);
        return;
    }
    const float* xr = x + ((long)b * N_ + (s - 1)) * C_;
    float xv[C_];
#pragma unroll
    for (int c = 0; c < C_; ++c) xv[c] = xr[c];

    float4 acc = *(const float4*)(bemb + lane * 4);
#pragma unroll
    for (int c = 0; c < C_; ++c) {
        float4 w = *(const float4*)(Wemb + c * E_ + lane * 4);
        acc.x += xv[c] * w.x; acc.y += xv[c] * w.y;
        acc.z += xv[c] * w.z; acc.w += xv[c] * w.w;
    }
    float sum = acc.x + acc.y + acc.z + acc.w;
    float sq  = acc.x*acc.x + acc.y*acc.y + acc.z*acc.z + acc.w*acc.w;
#pragma unroll
    for (int off = 1; off < 64; off <<= 1) {
        sum += __shfl_xor(sum, off);
        sq  += __shfl_xor(sq,  off);
    }
    float mean = sum * (1.0f / E_);
    float var  = sq * (1.0f / E_) - mean * mean;
    float rstd = rsqrtf(var + EPS_);
    float4 gg = *(const float4*)(g + lane * 4);
    float4 bb = *(const float4*)(be + lane * 4);
    float4 o;
    float v;
    v = (acc.x - mean) * rstd * gg.x + bb.x; o.x = 0.5f * v * (1.0f + erff(v * 0.70710678118f));
    v = (acc.y - mean) * rstd * gg.y + bb.y; o.y = 0.5f * v * (1.0f + erff(v * 0.70710678118f));
    v = (acc.z - mean) * rstd * gg.z + bb.z; o.z = 0.5f * v * (1.0f + erff(v * 0.70710678118f));
    v = (acc.w - mean) * rstd * gg.w + bb.w; o.w = 0.5f * v * (1.0f + erff(v * 0.70710678118f));
    *(float4*)(h + base) = o;
}

// ------------- LN (wave per token): optional h+=pos, y=bf16(LN(h)) ---------
__global__ __launch_bounds__(256) void ln4_kernel(
    float* __restrict__ h, const float* __restrict__ pos,
    const float* __restrict__ g, const float* __restrict__ bb,
    bf16* __restrict__ y)
{
    int wave = threadIdx.x >> 6, lane = threadIdx.x & 63;
    int t = blockIdx.x * 4 + wave;
    int s = t % S_;
    long base = (long)t * E_ + lane * 4;

    float4 v = *(const float4*)(h + base);
    if (pos) {
        float4 pv = *(const float4*)(pos + (long)s * E_ + lane * 4);
        v.x += pv.x; v.y += pv.y; v.z += pv.z; v.w += pv.w;
        *(float4*)(h + base) = v;
    }
    float sum = v.x + v.y + v.z + v.w;
    float sq  = v.x*v.x + v.y*v.y + v.z*v.z + v.w*v.w;
#pragma unroll
    for (int off = 1; off < 64; off <<= 1) {
        sum += __shfl_xor(sum, off);
        sq  += __shfl_xor(sq,  off);
    }
    float mean = sum * (1.0f / E_);
    float var  = sq * (1.0f / E_) - mean * mean;
    float rstd = rsqrtf(var + EPS_);
    float4 gg = *(const float4*)(g + lane * 4);
    float4 b4 = *(const float4*)(bb + lane * 4);
    bf16 o[4];
    o[0] = __float2bfloat16((v.x - mean) * rstd * gg.x + b4.x);
    o[1] = __float2bfloat16((v.y - mean) * rstd * gg.y + b4.y);
    o[2] = __float2bfloat16((v.z - mean) * rstd * gg.z + b4.z);
    o[3] = __float2bfloat16((v.w - mean) * rstd * gg.w + b4.w);
    *(uint2*)(y + base) = *(uint2*)o;
}

// ---------- Single-launch weight pack (LDS 32x32 transpose) ----------------
__global__ __launch_bounds__(256) void pack_all(
    const float* __restrict__ Wq, const float* __restrict__ Wk,
    const float* __restrict__ Wv, const float* __restrict__ bq,
    const float* __restrict__ bk, const float* __restrict__ bv,
    const float* __restrict__ Wo, const float* __restrict__ W1,
    const float* __restrict__ W2,
    bf16* __restrict__ Wqkvt, float* __restrict__ bqkv,
    bf16* __restrict__ Wot, bf16* __restrict__ W1t, bf16* __restrict__ W2t)
{
    __shared__ float tile[32][33];
    int id = blockIdx.x;
    int tx = threadIdx.x & 31, ty = threadIdx.x >> 5;   // 32x8
    const float* src; bf16* dst;
    int c0, k0, Nsrc, Kd, row0;

    if (id < 768) {                       // QKV: 4l x 8k x 24n
        int l = id / 192, r = id % 192;
        int nt = r % 24, kt2 = r / 24;
        int n0 = nt * 32; k0 = kt2 * 32;
        Nsrc = 256; Kd = 256; row0 = n0;
        if (n0 < 256)      { src = Wq + (long)l * 65536; c0 = n0; }
        else if (n0 < 512) { src = Wk + (long)l * 65536; c0 = n0 - 256; }
        else               { src = Wv + (long)l * 65536; c0 = n0 - 512; }
        dst = Wqkvt + (long)l * 768 * 256;
        if (kt2 == 0 && ty == 0) {
            const float* bsrc = (n0 < 256) ? bq + l * 256 + c0
                              : (n0 < 512) ? bk + l * 256 + c0 : bv + l * 256 + c0;
            bqkv[l * 768 + n0 + tx] = bsrc[tx];
        }
    } else if (id < 1024) {               // Wo
        int r = id - 768; int l = r / 64; r %= 64;
        int nt = r & 7, kt2 = r >> 3;
        c0 = nt * 32; k0 = kt2 * 32; Nsrc = 256; Kd = 256; row0 = c0;
        src = Wo + (long)l * 65536; dst = Wot + (long)l * 65536;
    } else if (id < 2048) {               // W1
        int r = id - 1024; int l = r / 256; r %= 256;
        int nt = r % 32, kt2 = r / 32;
        c0 = nt * 32; k0 = kt2 * 32; Nsrc = 1024; Kd = 256; row0 = c0;
        src = W1 + (long)l * 262144; dst = W1t + (long)l * 262144;
    } else {                              // W2
        int r = id - 2048; int l = r / 256; r %= 256;
        int nt = r & 7, kt2 = r >> 3;
        c0 = nt * 32; k0 = kt2 * 32; Nsrc = 256; Kd = 1024; row0 = c0;
        src = W2 + (long)l * 262144; dst = W2t + (long)l * 262144;
    }
#pragma unroll
    for (int i = 0; i < 4; ++i)
        tile[ty + i * 8][tx] = src[(long)(k0 + ty + i * 8) * Nsrc + c0 + tx];
    __syncthreads();
#pragma unroll
    for (int i = 0; i < 4; ++i)
        dst[(long)(row0 + ty + i * 8) * Kd + k0 + tx] = __float2bfloat16(tile[tx][ty + i * 8]);
}

// ---- bf16 MFMA GEMM, 32-row x 64-col tile, DMA staging + double buffer ----
// Wave w: row-frag (w&1), col-half (w>>1)*32 (2 frags). LDS 24 KB -> 6/CU.
__global__ __launch_bounds__(256) void gemm_bf16_32x64(
    const bf16* __restrict__ A, const bf16* __restrict__ Wt,
    const float* __restrict__ bias, const float* __restrict__ res,
    float* __restrict__ outF, bf16* __restrict__ outB,
    bf16* __restrict__ vTout, int M, int K, int N, int act)
{
    __shared__ bf16 As[2][32 * 64];    // 2 x 4 KB
    __shared__ bf16 Bs[2][64 * 64];    // 2 x 8 KB
    int tid = threadIdx.x;
    int wave = tid >> 6, lane = tid & 63;
    int quad = lane >> 4, l16 = lane & 15;
    int rw = wave & 1, cw = wave >> 1;
    int row0 = blockIdx.y * 32;
    int col0 = blockIdx.x * 64;

    int sr = lane >> 3;
    int sc = lane & 7;

    f32x4 acc[2] = {{0.f,0.f,0.f,0.f},{0.f,0.f,0.f,0.f}};
    int nk = K >> 6;

    // 12 DMA groups: 0..3 A (32 rows), 4..11 B (64 rows); 3 per wave
#pragma unroll
    for (int gi = 0; gi < 3; ++gi) {
        int id = wave * 3 + gi;           // 0..11
        if (id < 4) {
            int rr = id * 8 + sr;
            int cs = (sc - rr) & 7;
            dma16(A + (long)(row0 + rr) * K + cs * 8, &As[0][id * 8 * 64]);
        } else {
            int rr = (id - 4) * 8 + sr;
            int cs = (sc - rr) & 7;
            dma16(Wt + (long)(col0 + rr) * K + cs * 8, &Bs[0][(id - 4) * 8 * 64]);
        }
    }
    for (int kt = 0; kt < nk; ++kt) {
        __syncthreads();
        int buf = kt & 1;
        if (kt < nk - 1) {
            int k1 = (kt + 1) << 6;
            int nb = buf ^ 1;
#pragma unroll
            for (int gi = 0; gi < 3; ++gi) {
                int id = wave * 3 + gi;
                if (id < 4) {
                    int rr = id * 8 + sr;
                    int cs = (sc - rr) & 7;
                    dma16(A + (long)(row0 + rr) * K + k1 + cs * 8, &As[nb][id * 8 * 64]);
                } else {
                    int rr = (id - 4) * 8 + sr;
                    int cs = (sc - rr) & 7;
                    dma16(Wt + (long)(col0 + rr) * K + k1 + cs * 8, &Bs[nb][(id - 4) * 8 * 64]);
                }
            }
        }
#pragma unroll
        for (int ks8 = 0; ks8 < 8; ks8 += 4) {
            int rra = rw * 16 + l16;
            bf16x8 af = *(const bf16x8*)&As[buf][rra * 64 + (((quad + ks8) + rra) & 7) * 8];
#pragma unroll
            for (int nt = 0; nt < 2; ++nt) {
                int rrb = cw * 32 + nt * 16 + l16;
                bf16x8 bf = *(const bf16x8*)&Bs[buf][rrb * 64 + (((quad + ks8) + rrb) & 7) * 8];
                acc[nt] = __builtin_amdgcn_mfma_f32_16x16x32_bf16(af, bf, acc[nt], 0, 0, 0);
            }
        }
    }
#pragma unroll
    for (int nt = 0; nt < 2; ++nt) {
        int col = col0 + cw * 32 + nt * 16 + l16;
#pragma unroll
        for (int r = 0; r < 4; ++r) {
            int m = row0 + rw * 16 + quad * 4 + r;
            if (m >= M) continue;
            float v = acc[nt][r] + bias[col];
            if (act == 1) v = 0.5f * v * (1.0f + erff(v * 0.70710678118f));
            if (res)  v += res[(long)m * N + col];
            if (outF) outF[(long)m * N + col] = v;
            bf16 bvv = __float2bfloat16(v);
            if (outB) outB[(long)m * N + col] = bvv;
            if (vTout && col >= 512) {    // V cols -> vT[bh][d][key]
                int b2 = m / S_;
                int key = m - b2 * S_;
                int cc = col - 512;
                vTout[((long)(b2 * 8 + (cc >> 5)) * 32 + (cc & 31)) * SP_ + key] = bvv;
            }
        }
    }
}

// --------------- MFMA flash attention v8: 64-q tiles, Vs stride 72 ---------
#define NQT 17
__global__ __launch_bounds__(256) void attn_mfma8_kernel(
    const bf16* __restrict__ qkv, const bf16* __restrict__ vT,
    bf16* __restrict__ ob)
{
    __shared__ bf16 Ks[2][64 * 40];    // [key][d], row 80 B
    __shared__ bf16 Vs[2][32 * 72];    // [d][key], row 144 B (2-way banks)
    __shared__ bf16 Pa[4][16 * 72];    // per-wave P [q][key], row 144 B

    int tid = threadIdx.x;
    int wave = tid >> 6, lane = tid & 63;
    int quad = lane >> 4, l16 = lane & 15;
    int bh = blockIdx.x / NQT, qt = blockIdx.x % NQT;
    int b = bh >> 3, hh = bh & 7;
    int q0 = qt * 64;
    long bS = (long)b * S_;
    bf16* Pw = Pa[wave];
    const bf16* vTb = vT + (long)bh * 32 * SP_;
    uint4 z4 = make_uint4(0,0,0,0);

    int skey = tid >> 2, sdg = tid & 3;
    int svd = tid >> 3, svc = tid & 7;

    bf16x8 aq = {0,0,0,0,0,0,0,0};
    {
        int gq = q0 + wave * 16 + l16;
        if (gq < S_) aq = *(const bf16x8*)(qkv + (bS + gq) * 768 + hh * 32 + quad * 8);
    }

    f32x4 o0 = {0.f,0.f,0.f,0.f}, o1 = {0.f,0.f,0.f,0.f};
    float lsum[4] = {0.f,0.f,0.f,0.f};
    f32x4 zf = {0.f,0.f,0.f,0.f};

    {   // prologue: stage tile 0
        int gk = skey;
        uint4 kv = z4;
        if (gk < S_) kv = *(const uint4*)(qkv + (bS + gk) * 768 + 256 + hh * 32 + sdg * 8);
        *(uint4*)&Ks[0][skey * 40 + sdg * 8] = kv;
        *(uint4*)&Vs[0][svd * 72 + svc * 8] = *(const uint4*)(vTb + (long)svd * SP_ + svc * 8);
    }

    for (int kt = 0; kt < NQT; ++kt) {
        int j0 = kt * 64;
        int bb = kt & 1;
        __syncthreads();

        if (kt < NQT - 1) {
            int j1 = j0 + 64;
            int gk = j1 + skey;
            uint4 kv = z4;
            if (gk < S_) kv = *(const uint4*)(qkv + (bS + gk) * 768 + 256 + hh * 32 + sdg * 8);
            *(uint4*)&Ks[bb ^ 1][skey * 40 + sdg * 8] = kv;
            *(uint4*)&Vs[bb ^ 1][svd * 72 + svc * 8] =
                *(const uint4*)(vTb + (long)svd * SP_ + j1 + svc * 8);
        }

        f32x4 sc[4];
#pragma unroll
        for (int t4 = 0; t4 < 4; ++t4) {
            bf16x8 bk = *(const bf16x8*)&Ks[bb][(t4 * 16 + l16) * 40 + quad * 8];
            sc[t4] = __builtin_amdgcn_mfma_f32_16x16x32_bf16(aq, bk, zf, 0, 0, 0);
        }
        if (kt < NQT - 1) {
#pragma unroll
            for (int t4 = 0; t4 < 4; ++t4)
#pragma unroll
                for (int r = 0; r < 4; ++r) {
                    float p = __expf(sc[t4][r]);
                    lsum[r] += p;
                    Pw[(quad * 4 + r) * 72 + t4 * 16 + l16] = __float2bfloat16(p);
                }
        } else {
#pragma unroll
            for (int t4 = 0; t4 < 4; ++t4) {
                bool valid = (j0 + t4 * 16 + l16) < S_;
#pragma unroll
                for (int r = 0; r < 4; ++r) {
                    float p = valid ? __expf(sc[t4][r]) : 0.f;
                    lsum[r] += p;
                    Pw[(quad * 4 + r) * 72 + t4 * 16 + l16] = __float2bfloat16(p);
                }
            }
        }
#pragma unroll
        for (int ks2 = 0; ks2 < 64; ks2 += 32) {
            bf16x8 ap = *(const bf16x8*)&Pw[l16 * 72 + ks2 + quad * 8];
            bf16x8 bv0 = *(const bf16x8*)&Vs[bb][l16 * 72 + ks2 + quad * 8];
            o0 = __builtin_amdgcn_mfma_f32_16x16x32_bf16(ap, bv0, o0, 0, 0, 0);
            bf16x8 bv1 = *(const bf16x8*)&Vs[bb][(16 + l16) * 72 + ks2 + quad * 8];
            o1 = __builtin_amdgcn_mfma_f32_16x16x32_bf16(ap, bv1, o1, 0, 0, 0);
        }
    }

#pragma unroll
    for (int r = 0; r < 4; ++r) {
        float t = lsum[r];
        t += __shfl_xor(t, 1); t += __shfl_xor(t, 2);
        t += __shfl_xor(t, 4); t += __shfl_xor(t, 8);
        float inv = 1.0f / (t * 16.0f);
        int gq = q0 + wave * 16 + quad * 4 + r;
        if (gq < S_) {
            long base = (bS + gq) * 256 + hh * 32;
            ob[base + l16]      = __float2bfloat16(o0[r] * inv);
            ob[base + 16 + l16] = __float2bfloat16(o1[r] * inv);
        }
    }
}

// --------------- Pool: partial[b][sc][e] = sum over 65-row chunk -----------
__global__ __launch_bounds__(256) void pool_kernel(const float* __restrict__ h,
                                                   float* __restrict__ partial)
{
    int b = blockIdx.x >> 4, sc = blockIdx.x & 15;
    int e = threadIdx.x;
    int s0 = sc * 65, s1 = min(S_, s0 + 65);
    float acc = 0.f;
    for (int s = s0; s < s1; ++s) acc += h[((long)b * S_ + s) * E_ + e];
    partial[((long)b * 16 + sc) * E_ + e] = acc;
}

// --------------- Classifier final: Linear -> LN -> Linear -----------------
__global__ __launch_bounds__(256) void cls_final(
    const float* __restrict__ partial, const float* __restrict__ Wc1,
    const float* __restrict__ bc1, const float* __restrict__ lg,
    const float* __restrict__ lb, const float* __restrict__ Wc2,
    const float* __restrict__ bc2, float* __restrict__ out)
{
    int b = blockIdx.x;
    int e = threadIdx.x;
    __shared__ float p[256];
    __shared__ float red[256];
    __shared__ float lnv[256];

    float acc = 0.f;
#pragma unroll
    for (int sc = 0; sc < 16; ++sc) acc += partial[((long)b * 16 + sc) * E_ + e];
    p[e] = acc * (1.0f / S_);
    __syncthreads();

    float c1 = bc1[e];
    for (int kk = 0; kk < E_; ++kk) c1 += p[kk] * Wc1[kk * E_ + e];

    red[e] = c1; __syncthreads();
    for (int st = 128; st; st >>= 1) { if (e < st) red[e] += red[e + st]; __syncthreads(); }
    float mean = red[0] * (1.0f / E_); __syncthreads();
    float d = c1 - mean;
    red[e] = d * d; __syncthreads();
    for (int st = 128; st; st >>= 1) { if (e < st) red[e] += red[e + st]; __syncthreads(); }
    float var = red[0] * (1.0f / E_);
    lnv[e] = d * rsqrtf(var + EPS_) * lg[e] + lb[e];
    __syncthreads();

    if (e < NC_) {
        float oacc = bc2[e];
        for (int kk = 0; kk < E_; ++kk) oacc += lnv[kk] * Wc2[kk * NC_ + e];
        out[b * NC_ + e] = oacc;
    }
}

extern "C" void kernel_launch(void* const* d_in, const int* in_sizes, int n_in,
                              void* d_out, int out_size, void* d_ws, size_t ws_size,
                              hipStream_t stream)
{
    const float* x      = (const float*)d_in[0];
    const float* W_emb  = (const float*)d_in[1];
    const float* b_emb  = (const float*)d_in[2];
    const float* g_emb  = (const float*)d_in[3];
    const float* be_emb = (const float*)d_in[4];
    const float* cls    = (const float*)d_in[5];
    const float* pos    = (const float*)d_in[6];
    const float* ln1_g  = (const float*)d_in[7];
    const float* ln1_b  = (const float*)d_in[8];
    const float* Wq     = (const float*)d_in[9];
    const float* bq     = (const float*)d_in[10];
    const float* Wk     = (const float*)d_in[11];
    const float* bk     = (const float*)d_in[12];
    const float* Wv     = (const float*)d_in[13];
    const float* bv     = (const float*)d_in[14];
    const float* Wo     = (const float*)d_in[15];
    const float* bo     = (const float*)d_in[16];
    const float* ln2_g  = (const float*)d_in[17];
    const float* ln2_b  = (const float*)d_in[18];
    const float* W1     = (const float*)d_in[19];
    const float* b1     = (const float*)d_in[20];
    const float* W2     = (const float*)d_in[21];
    const float* b2     = (const float*)d_in[22];
    const float* Wc1    = (const float*)d_in[23];
    const float* bc1    = (const float*)d_in[24];
    const float* lnc_g  = (const float*)d_in[25];
    const float* lnc_b  = (const float*)d_in[26];
    const float* Wc2    = (const float*)d_in[27];
    const float* bc2    = (const float*)d_in[28];
    float* out = (float*)d_out;

    char* p = (char*)d_ws;
    float* h    = (float*)p; p += (long)M_ * 256 * 4;
    bf16* y     = (bf16*)p;  p += (long)M_ * 256 * 2;
    bf16* qkv   = (bf16*)p;  p += (long)M_ * 768 * 2;
    bf16* obuf  = (bf16*)p;  p += (long)M_ * 256 * 2;
    bf16* tb    = (bf16*)p;  p += (long)M_ * 1024 * 2;
    bf16* Wqkvt = (bf16*)p;  p += (long)L_ * 768 * 256 * 2;
    bf16* Wot   = (bf16*)p;  p += (long)L_ * 256 * 256 * 2;
    bf16* W1t   = (bf16*)p;  p += (long)L_ * 1024 * 256 * 2;
    bf16* W2t   = (bf16*)p;  p += (long)L_ * 256 * 1024 * 2;
    float* bqkv = (float*)p; p += (long)L_ * 768 * 4;
    float* pool = (float*)p; p += (long)B_ * 16 * 256 * 4;
    bf16* vT    = (bf16*)p;  p += (long)64 * 32 * SP_ * 2;

    // ---- weight packing (1 launch) ----
    pack_all<<<3072, 256, 0, stream>>>(Wq, Wk, Wv, bq, bk, bv, Wo, W1, W2,
                                       Wqkvt, bqkv, Wot, W1t, W2t);

    embed4_kernel<<<M_ / 4, 256, 0, stream>>>(x, W_emb, b_emb, g_emb, be_emb, cls, h);

    dim3 gQKV(12, 257), gMLP1(16, 257), gEE(4, 257);
    for (int l = 0; l < L_; ++l) {
        // h += pos; y = LN1(h)
        ln4_kernel<<<M_ / 4, 256, 0, stream>>>(h, pos, ln1_g + l * E_, ln1_b + l * E_, y);
        // qkv = y @ Wqkv + b (V cols also -> vT, transposed)
        gemm_bf16_32x64<<<gQKV, 256, 0, stream>>>(y, Wqkvt + (long)l * 768 * 256, bqkv + l * 768,
                                                  nullptr, nullptr, qkv, vT, M_, 256, 768, 0);
        attn_mfma8_kernel<<<64 * NQT, 256, 0, stream>>>(qkv, vT, obuf);
        // h += o @ Wo + bo
        gemm_bf16_32x64<<<gEE, 256, 0, stream>>>(obuf, Wot + (long)l * 65536, bo + l * E_,
                                                 h, h, nullptr, nullptr, M_, 256, 256, 0);
        // y = LN2(h); tb = GELU(y @ W1 + b1)
        ln4_kernel<<<M_ / 4, 256, 0, stream>>>(h, nullptr, ln2_g + l * E_, ln2_b + l * E_, y);
        gemm_bf16_32x64<<<gMLP1, 256, 0, stream>>>(y, W1t + (long)l * 262144, b1 + l * XE_,
                                                   nullptr, nullptr, tb, nullptr, M_, 256, 1024, 1);
        // h += tb @ W2 + b2
        gemm_bf16_32x64<<<gEE, 256, 0, stream>>>(tb, W2t + (long)l * 262144, b2 + l * E_,
                                                 h, h, nullptr, nullptr, M_, 1024, 256, 0);
    }

    pool_kernel<<<B_ * 16, 256, 0, stream>>>(h, pool);
    cls_final<<<B_, 256, 0, stream>>>(pool, Wc1, bc1, lnc_g, lnc_b, Wc2, bc2, out);
}

// Round 23
// 574.022 us; speedup vs baseline: 1.4305x; 1.0339x over previous
//
#include <hip/hip_runtime.h>
#include <hip/hip_bf16.h>
#include <math.h>

// Problem constants
#define B_  8
#define N_  1024
#define C_  12
#define E_  256
#define H_  8
#define D_  32      // E/H
#define L_  4
#define XE_ 1024    // X*E
#define NC_ 5
#define S_  1025    // N+1
#define M_  8200    // B*S
#define EPS_ 1e-5f
#define SP_ 1088    // padded key-stride for vT (17*64, 16B-aligned)

typedef short bf16x8 __attribute__((ext_vector_type(8)));
typedef float f32x4 __attribute__((ext_vector_type(4)));
typedef __hip_bfloat16 bf16;

// async global->LDS DMA, 16 B per lane; LDS dest = wave-uniform base + lane*16
typedef __attribute__((address_space(1))) const unsigned int* as1_cuint;
typedef __attribute__((address_space(3))) unsigned int* as3_uint;
__device__ __forceinline__ void dma16(const void* g, void* l) {
    __builtin_amdgcn_global_load_lds((as1_cuint)g, (as3_uint)l, 16, 0, 0);
}

// ---------------- Embedding (wave per token): x@W+b -> LN -> GELU ----------
// h stored bf16 (residual stream; all arithmetic fp32).
__global__ __launch_bounds__(256) void embed4_kernel(
    const float* __restrict__ x, const float* __restrict__ Wemb,
    const float* __restrict__ bemb, const float* __restrict__ g,
    const float* __restrict__ be, const float* __restrict__ cls,
    bf16* __restrict__ h)
{
    int wave = threadIdx.x >> 6, lane = threadIdx.x & 63;
    int t = blockIdx.x * 4 + wave;          // M_ = 4*2050 exactly
    int b = t / S_, s = t % S_;
    long base = (long)t * E_ + lane * 4;

    float4 o;
    if (s == 0) {
        o = *(const float4*)(cls + lane * 4);
    } else {
        const float* xr = x + ((long)b * N_ + (s - 1)) * C_;
        float xv[C_];
#pragma unroll
        for (int c = 0; c < C_; ++c) xv[c] = xr[c];

        float4 acc = *(const float4*)(bemb + lane * 4);
#pragma unroll
        for (int c = 0; c < C_; ++c) {
            float4 w = *(const float4*)(Wemb + c * E_ + lane * 4);
            acc.x += xv[c] * w.x; acc.y += xv[c] * w.y;
            acc.z += xv[c] * w.z; acc.w += xv[c] * w.w;
        }
        float sum = acc.x + acc.y + acc.z + acc.w;
        float sq  = acc.x*acc.x + acc.y*acc.y + acc.z*acc.z + acc.w*acc.w;
#pragma unroll
        for (int off = 1; off < 64; off <<= 1) {
            sum += __shfl_xor(sum, off);
            sq  += __shfl_xor(sq,  off);
        }
        float mean = sum * (1.0f / E_);
        float var  = sq * (1.0f / E_) - mean * mean;
        float rstd = rsqrtf(var + EPS_);
        float4 gg = *(const float4*)(g + lane * 4);
        float4 bb = *(const float4*)(be + lane * 4);
        float v;
        v = (acc.x - mean) * rstd * gg.x + bb.x; o.x = 0.5f * v * (1.0f + erff(v * 0.70710678118f));
        v = (acc.y - mean) * rstd * gg.y + bb.y; o.y = 0.5f * v * (1.0f + erff(v * 0.70710678118f));
        v = (acc.z - mean) * rstd * gg.z + bb.z; o.z = 0.5f * v * (1.0f + erff(v * 0.70710678118f));
        v = (acc.w - mean) * rstd * gg.w + bb.w; o.w = 0.5f * v * (1.0f + erff(v * 0.70710678118f));
    }
    bf16 ob[4];
    ob[0] = __float2bfloat16(o.x); ob[1] = __float2bfloat16(o.y);
    ob[2] = __float2bfloat16(o.z); ob[3] = __float2bfloat16(o.w);
    *(uint2*)(h + base) = *(uint2*)ob;
}

// ------------- LN (wave per token): optional h+=pos (bf16 h), y=LN(h) ------
__global__ __launch_bounds__(256) void ln4_kernel(
    bf16* __restrict__ h, const float* __restrict__ pos,
    const float* __restrict__ g, const float* __restrict__ bb,
    bf16* __restrict__ y)
{
    int wave = threadIdx.x >> 6, lane = threadIdx.x & 63;
    int t = blockIdx.x * 4 + wave;
    int s = t % S_;
    long base = (long)t * E_ + lane * 4;

    uint2 hu = *(const uint2*)(h + base);
    const bf16* hp = (const bf16*)&hu;
    float4 v = make_float4(__bfloat162float(hp[0]), __bfloat162float(hp[1]),
                           __bfloat162float(hp[2]), __bfloat162float(hp[3]));
    if (pos) {
        float4 pv = *(const float4*)(pos + (long)s * E_ + lane * 4);
        v.x += pv.x; v.y += pv.y; v.z += pv.z; v.w += pv.w;
        bf16 hw[4];
        hw[0] = __float2bfloat16(v.x); hw[1] = __float2bfloat16(v.y);
        hw[2] = __float2bfloat16(v.z); hw[3] = __float2bfloat16(v.w);
        *(uint2*)(h + base) = *(uint2*)hw;
    }
    float sum = v.x + v.y + v.z + v.w;
    float sq  = v.x*v.x + v.y*v.y + v.z*v.z + v.w*v.w;
#pragma unroll
    for (int off = 1; off < 64; off <<= 1) {
        sum += __shfl_xor(sum, off);
        sq  += __shfl_xor(sq,  off);
    }
    float mean = sum * (1.0f / E_);
    float var  = sq * (1.0f / E_) - mean * mean;
    float rstd = rsqrtf(var + EPS_);
    float4 gg = *(const float4*)(g + lane * 4);
    float4 b4 = *(const float4*)(bb + lane * 4);
    bf16 o[4];
    o[0] = __float2bfloat16((v.x - mean) * rstd * gg.x + b4.x);
    o[1] = __float2bfloat16((v.y - mean) * rstd * gg.y + b4.y);
    o[2] = __float2bfloat16((v.z - mean) * rstd * gg.z + b4.z);
    o[3] = __float2bfloat16((v.w - mean) * rstd * gg.w + b4.w);
    *(uint2*)(y + base) = *(uint2*)o;
}

// ---------- Single-launch weight pack (LDS 32x32 transpose) ----------------
__global__ __launch_bounds__(256) void pack_all(
    const float* __restrict__ Wq, const float* __restrict__ Wk,
    const float* __restrict__ Wv, const float* __restrict__ bq,
    const float* __restrict__ bk, const float* __restrict__ bv,
    const float* __restrict__ Wo, const float* __restrict__ W1,
    const float* __restrict__ W2,
    bf16* __restrict__ Wqkvt, float* __restrict__ bqkv,
    bf16* __restrict__ Wot, bf16* __restrict__ W1t, bf16* __restrict__ W2t)
{
    __shared__ float tile[32][33];
    int id = blockIdx.x;
    int tx = threadIdx.x & 31, ty = threadIdx.x >> 5;   // 32x8
    const float* src; bf16* dst;
    int c0, k0, Nsrc, Kd, row0;

    if (id < 768) {                       // QKV: 4l x 8k x 24n
        int l = id / 192, r = id % 192;
        int nt = r % 24, kt2 = r / 24;
        int n0 = nt * 32; k0 = kt2 * 32;
        Nsrc = 256; Kd = 256; row0 = n0;
        if (n0 < 256)      { src = Wq + (long)l * 65536; c0 = n0; }
        else if (n0 < 512) { src = Wk + (long)l * 65536; c0 = n0 - 256; }
        else               { src = Wv + (long)l * 65536; c0 = n0 - 512; }
        dst = Wqkvt + (long)l * 768 * 256;
        if (kt2 == 0 && ty == 0) {
            const float* bsrc = (n0 < 256) ? bq + l * 256 + c0
                              : (n0 < 512) ? bk + l * 256 + c0 : bv + l * 256 + c0;
            bqkv[l * 768 + n0 + tx] = bsrc[tx];
        }
    } else if (id < 1024) {               // Wo
        int r = id - 768; int l = r / 64; r %= 64;
        int nt = r & 7, kt2 = r >> 3;
        c0 = nt * 32; k0 = kt2 * 32; Nsrc = 256; Kd = 256; row0 = c0;
        src = Wo + (long)l * 65536; dst = Wot + (long)l * 65536;
    } else if (id < 2048) {               // W1
        int r = id - 1024; int l = r / 256; r %= 256;
        int nt = r % 32, kt2 = r / 32;
        c0 = nt * 32; k0 = kt2 * 32; Nsrc = 1024; Kd = 256; row0 = c0;
        src = W1 + (long)l * 262144; dst = W1t + (long)l * 262144;
    } else {                              // W2
        int r = id - 2048; int l = r / 256; r %= 256;
        int nt = r & 7, kt2 = r >> 3;
        c0 = nt * 32; k0 = kt2 * 32; Nsrc = 256; Kd = 1024; row0 = c0;
        src = W2 + (long)l * 262144; dst = W2t + (long)l * 262144;
    }
#pragma unroll
    for (int i = 0; i < 4; ++i)
        tile[ty + i * 8][tx] = src[(long)(k0 + ty + i * 8) * Nsrc + c0 + tx];
    __syncthreads();
#pragma unroll
    for (int i = 0; i < 4; ++i)
        dst[(long)(row0 + ty + i * 8) * Kd + k0 + tx] = __float2bfloat16(tile[tx][ty + i * 8]);
}

// ---- bf16 MFMA GEMM, 32-row x 64-col tile, DMA staging + double buffer ----
// Wave w: row-frag (w&1), col-half (w>>1)*32 (2 frags). LDS 24 KB -> 6/CU.
// res (bf16, nullable): out = act(A@Wt^T + bias) + res. Output bf16.
__global__ __launch_bounds__(256) void gemm_bf16_32x64(
    const bf16* __restrict__ A, const bf16* __restrict__ Wt,
    const float* __restrict__ bias, const bf16* __restrict__ res,
    bf16* __restrict__ outB, bf16* __restrict__ vTout,
    int M, int K, int N, int act)
{
    __shared__ bf16 As[2][32 * 64];    // 2 x 4 KB
    __shared__ bf16 Bs[2][64 * 64];    // 2 x 8 KB
    int tid = threadIdx.x;
    int wave = tid >> 6, lane = tid & 63;
    int quad = lane >> 4, l16 = lane & 15;
    int rw = wave & 1, cw = wave >> 1;
    int row0 = blockIdx.y * 32;
    int col0 = blockIdx.x * 64;

    int sr = lane >> 3;
    int sc = lane & 7;

    f32x4 acc[2] = {{0.f,0.f,0.f,0.f},{0.f,0.f,0.f,0.f}};
    int nk = K >> 6;

    // 12 DMA groups: 0..3 A (32 rows), 4..11 B (64 rows); 3 per wave
#pragma unroll
    for (int gi = 0; gi < 3; ++gi) {
        int id = wave * 3 + gi;           // 0..11
        if (id < 4) {
            int rr = id * 8 + sr;
            int cs = (sc - rr) & 7;
            dma16(A + (long)(row0 + rr) * K + cs * 8, &As[0][id * 8 * 64]);
        } else {
            int rr = (id - 4) * 8 + sr;
            int cs = (sc - rr) & 7;
            dma16(Wt + (long)(col0 + rr) * K + cs * 8, &Bs[0][(id - 4) * 8 * 64]);
        }
    }
    for (int kt = 0; kt < nk; ++kt) {
        __syncthreads();
        int buf = kt & 1;
        if (kt < nk - 1) {
            int k1 = (kt + 1) << 6;
            int nb = buf ^ 1;
#pragma unroll
            for (int gi = 0; gi < 3; ++gi) {
                int id = wave * 3 + gi;
                if (id < 4) {
                    int rr = id * 8 + sr;
                    int cs = (sc - rr) & 7;
                    dma16(A + (long)(row0 + rr) * K + k1 + cs * 8, &As[nb][id * 8 * 64]);
                } else {
                    int rr = (id - 4) * 8 + sr;
                    int cs = (sc - rr) & 7;
                    dma16(Wt + (long)(col0 + rr) * K + k1 + cs * 8, &Bs[nb][(id - 4) * 8 * 64]);
                }
            }
        }
#pragma unroll
        for (int ks8 = 0; ks8 < 8; ks8 += 4) {
            int rra = rw * 16 + l16;
            bf16x8 af = *(const bf16x8*)&As[buf][rra * 64 + (((quad + ks8) + rra) & 7) * 8];
#pragma unroll
            for (int nt = 0; nt < 2; ++nt) {
                int rrb = cw * 32 + nt * 16 + l16;
                bf16x8 bf = *(const bf16x8*)&Bs[buf][rrb * 64 + (((quad + ks8) + rrb) & 7) * 8];
                acc[nt] = __builtin_amdgcn_mfma_f32_16x16x32_bf16(af, bf, acc[nt], 0, 0, 0);
            }
        }
    }
#pragma unroll
    for (int nt = 0; nt < 2; ++nt) {
        int col = col0 + cw * 32 + nt * 16 + l16;
#pragma unroll
        for (int r = 0; r < 4; ++r) {
            int m = row0 + rw * 16 + quad * 4 + r;
            if (m >= M) continue;
            float v = acc[nt][r] + bias[col];
            if (act == 1) v = 0.5f * v * (1.0f + erff(v * 0.70710678118f));
            if (res)  v += __bfloat162float(res[(long)m * N + col]);
            bf16 bvv = __float2bfloat16(v);
            outB[(long)m * N + col] = bvv;
            if (vTout && col >= 512) {    // V cols -> vT[bh][d][key]
                int b2 = m / S_;
                int key = m - b2 * S_;
                int cc = col - 512;
                vTout[((long)(b2 * 8 + (cc >> 5)) * 32 + (cc & 31)) * SP_ + key] = bvv;
            }
        }
    }
}

// --------------- MFMA flash attention v8: 64-q tiles, Vs stride 72 ---------
#define NQT 17
__global__ __launch_bounds__(256) void attn_mfma8_kernel(
    const bf16* __restrict__ qkv, const bf16* __restrict__ vT,
    bf16* __restrict__ ob)
{
    __shared__ bf16 Ks[2][64 * 40];    // [key][d], row 80 B
    __shared__ bf16 Vs[2][32 * 72];    // [d][key], row 144 B (2-way banks)
    __shared__ bf16 Pa[4][16 * 72];    // per-wave P [q][key], row 144 B

    int tid = threadIdx.x;
    int wave = tid >> 6, lane = tid & 63;
    int quad = lane >> 4, l16 = lane & 15;
    int bh = blockIdx.x / NQT, qt = blockIdx.x % NQT;
    int b = bh >> 3, hh = bh & 7;
    int q0 = qt * 64;
    long bS = (long)b * S_;
    bf16* Pw = Pa[wave];
    const bf16* vTb = vT + (long)bh * 32 * SP_;
    uint4 z4 = make_uint4(0,0,0,0);

    int skey = tid >> 2, sdg = tid & 3;
    int svd = tid >> 3, svc = tid & 7;

    bf16x8 aq = {0,0,0,0,0,0,0,0};
    {
        int gq = q0 + wave * 16 + l16;
        if (gq < S_) aq = *(const bf16x8*)(qkv + (bS + gq) * 768 + hh * 32 + quad * 8);
    }

    f32x4 o0 = {0.f,0.f,0.f,0.f}, o1 = {0.f,0.f,0.f,0.f};
    float lsum[4] = {0.f,0.f,0.f,0.f};
    f32x4 zf = {0.f,0.f,0.f,0.f};

    {   // prologue: stage tile 0
        int gk = skey;
        uint4 kv = z4;
        if (gk < S_) kv = *(const uint4*)(qkv + (bS + gk) * 768 + 256 + hh * 32 + sdg * 8);
        *(uint4*)&Ks[0][skey * 40 + sdg * 8] = kv;
        *(uint4*)&Vs[0][svd * 72 + svc * 8] = *(const uint4*)(vTb + (long)svd * SP_ + svc * 8);
    }

    for (int kt = 0; kt < NQT; ++kt) {
        int j0 = kt * 64;
        int bb = kt & 1;
        __syncthreads();

        if (kt < NQT - 1) {
            int j1 = j0 + 64;
            int gk = j1 + skey;
            uint4 kv = z4;
            if (gk < S_) kv = *(const uint4*)(qkv + (bS + gk) * 768 + 256 + hh * 32 + sdg * 8);
            *(uint4*)&Ks[bb ^ 1][skey * 40 + sdg * 8] = kv;
            *(uint4*)&Vs[bb ^ 1][svd * 72 + svc * 8] =
                *(const uint4*)(vTb + (long)svd * SP_ + j1 + svc * 8);
        }

        f32x4 sc[4];
#pragma unroll
        for (int t4 = 0; t4 < 4; ++t4) {
            bf16x8 bk = *(const bf16x8*)&Ks[bb][(t4 * 16 + l16) * 40 + quad * 8];
            sc[t4] = __builtin_amdgcn_mfma_f32_16x16x32_bf16(aq, bk, zf, 0, 0, 0);
        }
        if (kt < NQT - 1) {
#pragma unroll
            for (int t4 = 0; t4 < 4; ++t4)
#pragma unroll
                for (int r = 0; r < 4; ++r) {
                    float p = __expf(sc[t4][r]);
                    lsum[r] += p;
                    Pw[(quad * 4 + r) * 72 + t4 * 16 + l16] = __float2bfloat16(p);
                }
        } else {
#pragma unroll
            for (int t4 = 0; t4 < 4; ++t4) {
                bool valid = (j0 + t4 * 16 + l16) < S_;
#pragma unroll
                for (int r = 0; r < 4; ++r) {
                    float p = valid ? __expf(sc[t4][r]) : 0.f;
                    lsum[r] += p;
                    Pw[(quad * 4 + r) * 72 + t4 * 16 + l16] = __float2bfloat16(p);
                }
            }
        }
#pragma unroll
        for (int ks2 = 0; ks2 < 64; ks2 += 32) {
            bf16x8 ap = *(const bf16x8*)&Pw[l16 * 72 + ks2 + quad * 8];
            bf16x8 bv0 = *(const bf16x8*)&Vs[bb][l16 * 72 + ks2 + quad * 8];
            o0 = __builtin_amdgcn_mfma_f32_16x16x32_bf16(ap, bv0, o0, 0, 0, 0);
            bf16x8 bv1 = *(const bf16x8*)&Vs[bb][(16 + l16) * 72 + ks2 + quad * 8];
            o1 = __builtin_amdgcn_mfma_f32_16x16x32_bf16(ap, bv1, o1, 0, 0, 0);
        }
    }

#pragma unroll
    for (int r = 0; r < 4; ++r) {
        float t = lsum[r];
        t += __shfl_xor(t, 1); t += __shfl_xor(t, 2);
        t += __shfl_xor(t, 4); t += __shfl_xor(t, 8);
        float inv = 1.0f / (t * 16.0f);
        int gq = q0 + wave * 16 + quad * 4 + r;
        if (gq < S_) {
            long base = (bS + gq) * 256 + hh * 32;
            ob[base + l16]      = __float2bfloat16(o0[r] * inv);
            ob[base + 16 + l16] = __float2bfloat16(o1[r] * inv);
        }
    }
}

// --------------- Pool: partial[b][sc][e] = sum over 65-row chunk -----------
__global__ __launch_bounds__(256) void pool_kernel(const bf16* __restrict__ h,
                                                   float* __restrict__ partial)
{
    int b = blockIdx.x >> 4, sc = blockIdx.x & 15;
    int e = threadIdx.x;
    int s0 = sc * 65, s1 = min(S_, s0 + 65);
    float acc = 0.f;
    for (int s = s0; s < s1; ++s)
        acc += __bfloat162float(h[((long)b * S_ + s) * E_ + e]);
    partial[((long)b * 16 + sc) * E_ + e] = acc;
}

// --------------- Classifier final: Linear -> LN -> Linear -----------------
__global__ __launch_bounds__(256) void cls_final(
    const float* __restrict__ partial, const float* __restrict__ Wc1,
    const float* __restrict__ bc1, const float* __restrict__ lg,
    const float* __restrict__ lb, const float* __restrict__ Wc2,
    const float* __restrict__ bc2, float* __restrict__ out)
{
    int b = blockIdx.x;
    int e = threadIdx.x;
    __shared__ float p[256];
    __shared__ float red[256];
    __shared__ float lnv[256];

    float acc = 0.f;
#pragma unroll
    for (int sc = 0; sc < 16; ++sc) acc += partial[((long)b * 16 + sc) * E_ + e];
    p[e] = acc * (1.0f / S_);
    __syncthreads();

    float c1 = bc1[e];
    for (int kk = 0; kk < E_; ++kk) c1 += p[kk] * Wc1[kk * E_ + e];

    red[e] = c1; __syncthreads();
    for (int st = 128; st; st >>= 1) { if (e < st) red[e] += red[e + st]; __syncthreads(); }
    float mean = red[0] * (1.0f / E_); __syncthreads();
    float d = c1 - mean;
    red[e] = d * d; __syncthreads();
    for (int st = 128; st; st >>= 1) { if (e < st) red[e] += red[e + st]; __syncthreads(); }
    float var = red[0] * (1.0f / E_);
    lnv[e] = d * rsqrtf(var + EPS_) * lg[e] + lb[e];
    __syncthreads();

    if (e < NC_) {
        float oacc = bc2[e];
        for (int kk = 0; kk < E_; ++kk) oacc += lnv[kk] * Wc2[kk * NC_ + e];
        out[b * NC_ + e] = oacc;
    }
}

extern "C" void kernel_launch(void* const* d_in, const int* in_sizes, int n_in,
                              void* d_out, int out_size, void* d_ws, size_t ws_size,
                              hipStream_t stream)
{
    const float* x      = (const float*)d_in[0];
    const float* W_emb  = (const float*)d_in[1];
    const float* b_emb  = (const float*)d_in[2];
    const float* g_emb  = (const float*)d_in[3];
    const float* be_emb = (const float*)d_in[4];
    const float* cls    = (const float*)d_in[5];
    const float* pos    = (const float*)d_in[6];
    const float* ln1_g  = (const float*)d_in[7];
    const float* ln1_b  = (const float*)d_in[8];
    const float* Wq     = (const float*)d_in[9];
    const float* bq     = (const float*)d_in[10];
    const float* Wk     = (const float*)d_in[11];
    const float* bk     = (const float*)d_in[12];
    const float* Wv     = (const float*)d_in[13];
    const float* bv     = (const float*)d_in[14];
    const float* Wo     = (const float*)d_in[15];
    const float* bo     = (const float*)d_in[16];
    const float* ln2_g  = (const float*)d_in[17];
    const float* ln2_b  = (const float*)d_in[18];
    const float* W1     = (const float*)d_in[19];
    const float* b1     = (const float*)d_in[20];
    const float* W2     = (const float*)d_in[21];
    const float* b2     = (const float*)d_in[22];
    const float* Wc1    = (const float*)d_in[23];
    const float* bc1    = (const float*)d_in[24];
    const float* lnc_g  = (const float*)d_in[25];
    const float* lnc_b  = (const float*)d_in[26];
    const float* Wc2    = (const float*)d_in[27];
    const float* bc2    = (const float*)d_in[28];
    float* out = (float*)d_out;

    char* p = (char*)d_ws;
    bf16* h     = (bf16*)p;  p += (long)M_ * 256 * 2;
    bf16* y     = (bf16*)p;  p += (long)M_ * 256 * 2;
    bf16* qkv   = (bf16*)p;  p += (long)M_ * 768 * 2;
    bf16* obuf  = (bf16*)p;  p += (long)M_ * 256 * 2;
    bf16* tb    = (bf16*)p;  p += (long)M_ * 1024 * 2;
    bf16* Wqkvt = (bf16*)p;  p += (long)L_ * 768 * 256 * 2;
    bf16* Wot   = (bf16*)p;  p += (long)L_ * 256 * 256 * 2;
    bf16* W1t   = (bf16*)p;  p += (long)L_ * 1024 * 256 * 2;
    bf16* W2t   = (bf16*)p;  p += (long)L_ * 256 * 1024 * 2;
    float* bqkv = (float*)p; p += (long)L_ * 768 * 4;
    float* pool = (float*)p; p += (long)B_ * 16 * 256 * 4;
    bf16* vT    = (bf16*)p;  p += (long)64 * 32 * SP_ * 2;

    // ---- weight packing (1 launch) ----
    pack_all<<<3072, 256, 0, stream>>>(Wq, Wk, Wv, bq, bk, bv, Wo, W1, W2,
                                       Wqkvt, bqkv, Wot, W1t, W2t);

    embed4_kernel<<<M_ / 4, 256, 0, stream>>>(x, W_emb, b_emb, g_emb, be_emb, cls, h);

    dim3 gQKV(12, 257), gMLP1(16, 257), gEE(4, 257);
    for (int l = 0; l < L_; ++l) {
        // h += pos; y = LN1(h)
        ln4_kernel<<<M_ / 4, 256, 0, stream>>>(h, pos, ln1_g + l * E_, ln1_b + l * E_, y);
        // qkv = y @ Wqkv + b (V cols also -> vT, transposed)
        gemm_bf16_32x64<<<gQKV, 256, 0, stream>>>(y, Wqkvt + (long)l * 768 * 256, bqkv + l * 768,
                                                  nullptr, qkv, vT, M_, 256, 768, 0);
        attn_mfma8_kernel<<<64 * NQT, 256, 0, stream>>>(qkv, vT, obuf);
        // h += o @ Wo + bo
        gemm_bf16_32x64<<<gEE, 256, 0, stream>>>(obuf, Wot + (long)l * 65536, bo + l * E_,
                                                 h, h, nullptr, M_, 256, 256, 0);
        // y = LN2(h); tb = GELU(y @ W1 + b1)
        ln4_kernel<<<M_ / 4, 256, 0, stream>>>(h, nullptr, ln2_g + l * E_, ln2_b + l * E_, y);
        gemm_bf16_32x64<<<gMLP1, 256, 0, stream>>>(y, W1t + (long)l * 262144, b1 + l * XE_,
                                                   nullptr, tb, nullptr, M_, 256, 1024, 1);
        // h += tb @ W2 + b2
        gemm_bf16_32x64<<<gEE, 256, 0, stream>>>(tb, W2t + (long)l * 262144, b2 + l * E_,
                                                 h, h, nullptr, M_, 1024, 256, 0);
    }

    pool_kernel<<<B_ * 16, 256, 0, stream>>>(h, pool);
    cls_final<<<B_, 256, 0, stream>>>(pool, Wc1, bc1, lnc_g, lnc_b, Wc2, bc2, out);
}

// Round 24
// 571.846 us; speedup vs baseline: 1.4360x; 1.0038x over previous
//
#include <hip/hip_runtime.h>
#include <hip/hip_bf16.h>
#include <math.h>

// Problem constants
#define B_  8
#define N_  1024
#define C_  12
#define E_  256
#define H_  8
#define D_  32      // E/H
#define L_  4
#define XE_ 1024    // X*E
#define NC_ 5
#define S_  1025    // N+1
#define M_  8200    // B*S
#define EPS_ 1e-5f
#define SP_ 1088    // padded key-stride for vT (17*64, 16B-aligned)

typedef short bf16x8 __attribute__((ext_vector_type(8)));
typedef float f32x4 __attribute__((ext_vector_type(4)));
typedef __hip_bfloat16 bf16;

// async global->LDS DMA, 16 B per lane; LDS dest = wave-uniform base + lane*16
typedef __attribute__((address_space(1))) const unsigned int* as1_cuint;
typedef __attribute__((address_space(3))) unsigned int* as3_uint;
__device__ __forceinline__ void dma16(const void* g, void* l) {
    __builtin_amdgcn_global_load_lds((as1_cuint)g, (as3_uint)l, 16, 0, 0);
}

// ---------------- Embedding (wave per token): x@W+b -> LN -> GELU ----------
__global__ __launch_bounds__(256) void embed4_kernel(
    const float* __restrict__ x, const float* __restrict__ Wemb,
    const float* __restrict__ bemb, const float* __restrict__ g,
    const float* __restrict__ be, const float* __restrict__ cls,
    bf16* __restrict__ h)
{
    int wave = threadIdx.x >> 6, lane = threadIdx.x & 63;
    int t = blockIdx.x * 4 + wave;          // M_ = 4*2050 exactly
    int b = t / S_, s = t % S_;
    long base = (long)t * E_ + lane * 4;

    float4 o;
    if (s == 0) {
        o = *(const float4*)(cls + lane * 4);
    } else {
        const float* xr = x + ((long)b * N_ + (s - 1)) * C_;
        float xv[C_];
#pragma unroll
        for (int c = 0; c < C_; ++c) xv[c] = xr[c];

        float4 acc = *(const float4*)(bemb + lane * 4);
#pragma unroll
        for (int c = 0; c < C_; ++c) {
            float4 w = *(const float4*)(Wemb + c * E_ + lane * 4);
            acc.x += xv[c] * w.x; acc.y += xv[c] * w.y;
            acc.z += xv[c] * w.z; acc.w += xv[c] * w.w;
        }
        float sum = acc.x + acc.y + acc.z + acc.w;
        float sq  = acc.x*acc.x + acc.y*acc.y + acc.z*acc.z + acc.w*acc.w;
#pragma unroll
        for (int off = 1; off < 64; off <<= 1) {
            sum += __shfl_xor(sum, off);
            sq  += __shfl_xor(sq,  off);
        }
        float mean = sum * (1.0f / E_);
        float var  = sq * (1.0f / E_) - mean * mean;
        float rstd = rsqrtf(var + EPS_);
        float4 gg = *(const float4*)(g + lane * 4);
        float4 bb = *(const float4*)(be + lane * 4);
        float v;
        v = (acc.x - mean) * rstd * gg.x + bb.x; o.x = 0.5f * v * (1.0f + erff(v * 0.70710678118f));
        v = (acc.y - mean) * rstd * gg.y + bb.y; o.y = 0.5f * v * (1.0f + erff(v * 0.70710678118f));
        v = (acc.z - mean) * rstd * gg.z + bb.z; o.z = 0.5f * v * (1.0f + erff(v * 0.70710678118f));
        v = (acc.w - mean) * rstd * gg.w + bb.w; o.w = 0.5f * v * (1.0f + erff(v * 0.70710678118f));
    }
    bf16 ob[4];
    ob[0] = __float2bfloat16(o.x); ob[1] = __float2bfloat16(o.y);
    ob[2] = __float2bfloat16(o.z); ob[3] = __float2bfloat16(o.w);
    *(uint2*)(h + base) = *(uint2*)ob;
}

// ------------- LN (wave per token): optional h+=pos (bf16 h), y=LN(h) ------
__global__ __launch_bounds__(256) void ln4_kernel(
    bf16* __restrict__ h, const float* __restrict__ pos,
    const float* __restrict__ g, const float* __restrict__ bb,
    bf16* __restrict__ y)
{
    int wave = threadIdx.x >> 6, lane = threadIdx.x & 63;
    int t = blockIdx.x * 4 + wave;
    int s = t % S_;
    long base = (long)t * E_ + lane * 4;

    uint2 hu = *(const uint2*)(h + base);
    const bf16* hp = (const bf16*)&hu;
    float4 v = make_float4(__bfloat162float(hp[0]), __bfloat162float(hp[1]),
                           __bfloat162float(hp[2]), __bfloat162float(hp[3]));
    if (pos) {
        float4 pv = *(const float4*)(pos + (long)s * E_ + lane * 4);
        v.x += pv.x; v.y += pv.y; v.z += pv.z; v.w += pv.w;
        bf16 hw[4];
        hw[0] = __float2bfloat16(v.x); hw[1] = __float2bfloat16(v.y);
        hw[2] = __float2bfloat16(v.z); hw[3] = __float2bfloat16(v.w);
        *(uint2*)(h + base) = *(uint2*)hw;
    }
    float sum = v.x + v.y + v.z + v.w;
    float sq  = v.x*v.x + v.y*v.y + v.z*v.z + v.w*v.w;
#pragma unroll
    for (int off = 1; off < 64; off <<= 1) {
        sum += __shfl_xor(sum, off);
        sq  += __shfl_xor(sq,  off);
    }
    float mean = sum * (1.0f / E_);
    float var  = sq * (1.0f / E_) - mean * mean;
    float rstd = rsqrtf(var + EPS_);
    float4 gg = *(const float4*)(g + lane * 4);
    float4 b4 = *(const float4*)(bb + lane * 4);
    bf16 o[4];
    o[0] = __float2bfloat16((v.x - mean) * rstd * gg.x + b4.x);
    o[1] = __float2bfloat16((v.y - mean) * rstd * gg.y + b4.y);
    o[2] = __float2bfloat16((v.z - mean) * rstd * gg.z + b4.z);
    o[3] = __float2bfloat16((v.w - mean) * rstd * gg.w + b4.w);
    *(uint2*)(y + base) = *(uint2*)o;
}

// ---------- Single-launch weight pack (LDS 32x32 transpose) ----------------
__global__ __launch_bounds__(256) void pack_all(
    const float* __restrict__ Wq, const float* __restrict__ Wk,
    const float* __restrict__ Wv, const float* __restrict__ bq,
    const float* __restrict__ bk, const float* __restrict__ bv,
    const float* __restrict__ Wo, const float* __restrict__ W1,
    const float* __restrict__ W2,
    bf16* __restrict__ Wqkvt, float* __restrict__ bqkv,
    bf16* __restrict__ Wot, bf16* __restrict__ W1t, bf16* __restrict__ W2t)
{
    __shared__ float tile[32][33];
    int id = blockIdx.x;
    int tx = threadIdx.x & 31, ty = threadIdx.x >> 5;   // 32x8
    const float* src; bf16* dst;
    int c0, k0, Nsrc, Kd, row0;

    if (id < 768) {                       // QKV: 4l x 8k x 24n
        int l = id / 192, r = id % 192;
        int nt = r % 24, kt2 = r / 24;
        int n0 = nt * 32; k0 = kt2 * 32;
        Nsrc = 256; Kd = 256; row0 = n0;
        if (n0 < 256)      { src = Wq + (long)l * 65536; c0 = n0; }
        else if (n0 < 512) { src = Wk + (long)l * 65536; c0 = n0 - 256; }
        else               { src = Wv + (long)l * 65536; c0 = n0 - 512; }
        dst = Wqkvt + (long)l * 768 * 256;
        if (kt2 == 0 && ty == 0) {
            const float* bsrc = (n0 < 256) ? bq + l * 256 + c0
                              : (n0 < 512) ? bk + l * 256 + c0 : bv + l * 256 + c0;
            bqkv[l * 768 + n0 + tx] = bsrc[tx];
        }
    } else if (id < 1024) {               // Wo
        int r = id - 768; int l = r / 64; r %= 64;
        int nt = r & 7, kt2 = r >> 3;
        c0 = nt * 32; k0 = kt2 * 32; Nsrc = 256; Kd = 256; row0 = c0;
        src = Wo + (long)l * 65536; dst = Wot + (long)l * 65536;
    } else if (id < 2048) {               // W1
        int r = id - 1024; int l = r / 256; r %= 256;
        int nt = r % 32, kt2 = r / 32;
        c0 = nt * 32; k0 = kt2 * 32; Nsrc = 1024; Kd = 256; row0 = c0;
        src = W1 + (long)l * 262144; dst = W1t + (long)l * 262144;
    } else {                              // W2
        int r = id - 2048; int l = r / 256; r %= 256;
        int nt = r & 7, kt2 = r >> 3;
        c0 = nt * 32; k0 = kt2 * 32; Nsrc = 256; Kd = 1024; row0 = c0;
        src = W2 + (long)l * 262144; dst = W2t + (long)l * 262144;
    }
#pragma unroll
    for (int i = 0; i < 4; ++i)
        tile[ty + i * 8][tx] = src[(long)(k0 + ty + i * 8) * Nsrc + c0 + tx];
    __syncthreads();
#pragma unroll
    for (int i = 0; i < 4; ++i)
        dst[(long)(row0 + ty + i * 8) * Kd + k0 + tx] = __float2bfloat16(tile[tx][ty + i * 8]);
}

// ---- bf16 MFMA GEMM, 32-row x 64-col tile, DMA staging + double buffer ----
__global__ __launch_bounds__(256) void gemm_bf16_32x64(
    const bf16* __restrict__ A, const bf16* __restrict__ Wt,
    const float* __restrict__ bias, const bf16* __restrict__ res,
    bf16* __restrict__ outB, bf16* __restrict__ vTout,
    int M, int K, int N, int act)
{
    __shared__ bf16 As[2][32 * 64];    // 2 x 4 KB
    __shared__ bf16 Bs[2][64 * 64];    // 2 x 8 KB
    int tid = threadIdx.x;
    int wave = tid >> 6, lane = tid & 63;
    int quad = lane >> 4, l16 = lane & 15;
    int rw = wave & 1, cw = wave >> 1;
    int row0 = blockIdx.y * 32;
    int col0 = blockIdx.x * 64;

    int sr = lane >> 3;
    int sc = lane & 7;

    f32x4 acc[2] = {{0.f,0.f,0.f,0.f},{0.f,0.f,0.f,0.f}};
    int nk = K >> 6;

    // 12 DMA groups: 0..3 A (32 rows), 4..11 B (64 rows); 3 per wave
#pragma unroll
    for (int gi = 0; gi < 3; ++gi) {
        int id = wave * 3 + gi;           // 0..11
        if (id < 4) {
            int rr = id * 8 + sr;
            int cs = (sc - rr) & 7;
            dma16(A + (long)(row0 + rr) * K + cs * 8, &As[0][id * 8 * 64]);
        } else {
            int rr = (id - 4) * 8 + sr;
            int cs = (sc - rr) & 7;
            dma16(Wt + (long)(col0 + rr) * K + cs * 8, &Bs[0][(id - 4) * 8 * 64]);
        }
    }
    for (int kt = 0; kt < nk; ++kt) {
        __syncthreads();
        int buf = kt & 1;
        if (kt < nk - 1) {
            int k1 = (kt + 1) << 6;
            int nb = buf ^ 1;
#pragma unroll
            for (int gi = 0; gi < 3; ++gi) {
                int id = wave * 3 + gi;
                if (id < 4) {
                    int rr = id * 8 + sr;
                    int cs = (sc - rr) & 7;
                    dma16(A + (long)(row0 + rr) * K + k1 + cs * 8, &As[nb][id * 8 * 64]);
                } else {
                    int rr = (id - 4) * 8 + sr;
                    int cs = (sc - rr) & 7;
                    dma16(Wt + (long)(col0 + rr) * K + k1 + cs * 8, &Bs[nb][(id - 4) * 8 * 64]);
                }
            }
        }
#pragma unroll
        for (int ks8 = 0; ks8 < 8; ks8 += 4) {
            int rra = rw * 16 + l16;
            bf16x8 af = *(const bf16x8*)&As[buf][rra * 64 + (((quad + ks8) + rra) & 7) * 8];
#pragma unroll
            for (int nt = 0; nt < 2; ++nt) {
                int rrb = cw * 32 + nt * 16 + l16;
                bf16x8 bf = *(const bf16x8*)&Bs[buf][rrb * 64 + (((quad + ks8) + rrb) & 7) * 8];
                acc[nt] = __builtin_amdgcn_mfma_f32_16x16x32_bf16(af, bf, acc[nt], 0, 0, 0);
            }
        }
    }
#pragma unroll
    for (int nt = 0; nt < 2; ++nt) {
        int col = col0 + cw * 32 + nt * 16 + l16;
#pragma unroll
        for (int r = 0; r < 4; ++r) {
            int m = row0 + rw * 16 + quad * 4 + r;
            if (m >= M) continue;
            float v = acc[nt][r] + bias[col];
            if (act == 1) v = 0.5f * v * (1.0f + erff(v * 0.70710678118f));
            if (res)  v += __bfloat162float(res[(long)m * N + col]);
            bf16 bvv = __float2bfloat16(v);
            outB[(long)m * N + col] = bvv;
            if (vTout && col >= 512) {    // V cols -> vT[bh][d][key]
                int b2 = m / S_;
                int key = m - b2 * S_;
                int cc = col - 512;
                vTout[((long)(b2 * 8 + (cc >> 5)) * 32 + (cc & 31)) * SP_ + key] = bvv;
            }
        }
    }
}

// --------------- MFMA flash attention v9: DMA-staged K/V -------------------
// K rows 64 B (4 chunks), chunk rotated by (row>>1)&3; V rows 128 B
// (8 chunks), chunk rotated by row&7 — both give 2-way (free) frag reads.
// One dma16 per wave per tile for each of K and V. OOB tail reads are
// unpredicated but finite (0xAA bf16 is finite); per-column masking zeroes P.
#define NQT 17
__global__ __launch_bounds__(256) void attn_mfma9_kernel(
    const bf16* __restrict__ qkv, const bf16* __restrict__ vT,
    bf16* __restrict__ ob)
{
    __shared__ bf16 Ks[2][64 * 32];    // [key][d], row 64 B, swizzled
    __shared__ bf16 Vs[2][32 * 64];    // [d][key], row 128 B, swizzled
    __shared__ bf16 Pa[4][16 * 72];    // per-wave P [q][key], row 144 B

    int tid = threadIdx.x;
    int wave = tid >> 6, lane = tid & 63;
    int quad = lane >> 4, l16 = lane & 15;
    int bh = blockIdx.x / NQT, qt = blockIdx.x % NQT;
    int b = bh >> 3, hh = bh & 7;
    int q0 = qt * 64;
    long bS = (long)b * S_;
    bf16* Pw = Pa[wave];
    const bf16* kb = qkv + bS * 768 + 256 + hh * 32;   // + key*768 + chunk*8
    const bf16* vTb = vT + (long)bh * 32 * SP_;

    // K staging: lane -> row wave*16 + (lane>>2), chunk ((lane&3)-(row>>1))&3
    int krow = wave * 16 + (lane >> 2);
    int kcs  = ((lane & 3) - ((krow >> 1) & 3)) & 3;
    // V staging: lane -> drow wave*8 + (lane>>3), chunk ((lane&7)-drow)&7
    int vrow = wave * 8 + (lane >> 3);
    int vcs  = ((lane & 7) - (vrow & 7)) & 7;

    bf16x8 aq = {0,0,0,0,0,0,0,0};
    {
        int gq = q0 + wave * 16 + l16;
        if (gq < S_) aq = *(const bf16x8*)(qkv + (bS + gq) * 768 + hh * 32 + quad * 8);
    }

    f32x4 o0 = {0.f,0.f,0.f,0.f}, o1 = {0.f,0.f,0.f,0.f};
    float lsum[4] = {0.f,0.f,0.f,0.f};
    f32x4 zf = {0.f,0.f,0.f,0.f};

    {   // prologue: DMA tile 0 into buffer 0
        dma16(kb + (long)krow * 768 + kcs * 8, &Ks[0][wave * 16 * 32]);
        dma16(vTb + (long)vrow * SP_ + vcs * 8, &Vs[0][wave * 8 * 64]);
    }

    for (int kt = 0; kt < NQT; ++kt) {
        int j0 = kt * 64;
        int bb = kt & 1;
        __syncthreads();                  // drains DMA for buf bb

        if (kt < NQT - 1) {               // DMA next tile into other buffer
            int j1 = j0 + 64;
            dma16(kb + (long)(j1 + krow) * 768 + kcs * 8, &Ks[bb ^ 1][wave * 16 * 32]);
            dma16(vTb + (long)vrow * SP_ + j1 + vcs * 8, &Vs[bb ^ 1][wave * 8 * 64]);
        }

        f32x4 sc[4];
#pragma unroll
        for (int t4 = 0; t4 < 4; ++t4) {
            int rr = t4 * 16 + l16;
            bf16x8 bk = *(const bf16x8*)&Ks[bb][rr * 32 + ((quad + ((rr >> 1) & 3)) & 3) * 8];
            sc[t4] = __builtin_amdgcn_mfma_f32_16x16x32_bf16(aq, bk, zf, 0, 0, 0);
        }
        if (kt < NQT - 1) {
#pragma unroll
            for (int t4 = 0; t4 < 4; ++t4)
#pragma unroll
                for (int r = 0; r < 4; ++r) {
                    float p = __expf(sc[t4][r]);
                    lsum[r] += p;
                    Pw[(quad * 4 + r) * 72 + t4 * 16 + l16] = __float2bfloat16(p);
                }
        } else {
#pragma unroll
            for (int t4 = 0; t4 < 4; ++t4) {
                bool valid = (j0 + t4 * 16 + l16) < S_;
#pragma unroll
                for (int r = 0; r < 4; ++r) {
                    float p = valid ? __expf(sc[t4][r]) : 0.f;
                    lsum[r] += p;
                    Pw[(quad * 4 + r) * 72 + t4 * 16 + l16] = __float2bfloat16(p);
                }
            }
        }
#pragma unroll
        for (int ks2 = 0; ks2 < 64; ks2 += 32) {
            int ck = (ks2 >> 3) + quad;   // global chunk 0..7
            bf16x8 ap = *(const bf16x8*)&Pw[l16 * 72 + ks2 + quad * 8];
            int rv0 = l16;
            bf16x8 bv0 = *(const bf16x8*)&Vs[bb][rv0 * 64 + ((ck + (rv0 & 7)) & 7) * 8];
            o0 = __builtin_amdgcn_mfma_f32_16x16x32_bf16(ap, bv0, o0, 0, 0, 0);
            int rv1 = 16 + l16;
            bf16x8 bv1 = *(const bf16x8*)&Vs[bb][rv1 * 64 + ((ck + (rv1 & 7)) & 7) * 8];
            o1 = __builtin_amdgcn_mfma_f32_16x16x32_bf16(ap, bv1, o1, 0, 0, 0);
        }
    }

#pragma unroll
    for (int r = 0; r < 4; ++r) {
        float t = lsum[r];
        t += __shfl_xor(t, 1); t += __shfl_xor(t, 2);
        t += __shfl_xor(t, 4); t += __shfl_xor(t, 8);
        float inv = 1.0f / (t * 16.0f);
        int gq = q0 + wave * 16 + quad * 4 + r;
        if (gq < S_) {
            long base = (bS + gq) * 256 + hh * 32;
            ob[base + l16]      = __float2bfloat16(o0[r] * inv);
            ob[base + 16 + l16] = __float2bfloat16(o1[r] * inv);
        }
    }
}

// --------------- Pool: partial[b][sc][e] = sum over 65-row chunk -----------
__global__ __launch_bounds__(256) void pool_kernel(const bf16* __restrict__ h,
                                                   float* __restrict__ partial)
{
    int b = blockIdx.x >> 4, sc = blockIdx.x & 15;
    int e = threadIdx.x;
    int s0 = sc * 65, s1 = min(S_, s0 + 65);
    float acc = 0.f;
    for (int s = s0; s < s1; ++s)
        acc += __bfloat162float(h[((long)b * S_ + s) * E_ + e]);
    partial[((long)b * 16 + sc) * E_ + e] = acc;
}

// --------------- Classifier final: Linear -> LN -> Linear -----------------
__global__ __launch_bounds__(256) void cls_final(
    const float* __restrict__ partial, const float* __restrict__ Wc1,
    const float* __restrict__ bc1, const float* __restrict__ lg,
    const float* __restrict__ lb, const float* __restrict__ Wc2,
    const float* __restrict__ bc2, float* __restrict__ out)
{
    int b = blockIdx.x;
    int e = threadIdx.x;
    __shared__ float p[256];
    __shared__ float red[256];
    __shared__ float lnv[256];

    float acc = 0.f;
#pragma unroll
    for (int sc = 0; sc < 16; ++sc) acc += partial[((long)b * 16 + sc) * E_ + e];
    p[e] = acc * (1.0f / S_);
    __syncthreads();

    float c1 = bc1[e];
    for (int kk = 0; kk < E_; ++kk) c1 += p[kk] * Wc1[kk * E_ + e];

    red[e] = c1; __syncthreads();
    for (int st = 128; st; st >>= 1) { if (e < st) red[e] += red[e + st]; __syncthreads(); }
    float mean = red[0] * (1.0f / E_); __syncthreads();
    float d = c1 - mean;
    red[e] = d * d; __syncthreads();
    for (int st = 128; st; st >>= 1) { if (e < st) red[e] += red[e + st]; __syncthreads(); }
    float var = red[0] * (1.0f / E_);
    lnv[e] = d * rsqrtf(var + EPS_) * lg[e] + lb[e];
    __syncthreads();

    if (e < NC_) {
        float oacc = bc2[e];
        for (int kk = 0; kk < E_; ++kk) oacc += lnv[kk] * Wc2[kk * NC_ + e];
        out[b * NC_ + e] = oacc;
    }
}

extern "C" void kernel_launch(void* const* d_in, const int* in_sizes, int n_in,
                              void* d_out, int out_size, void* d_ws, size_t ws_size,
                              hipStream_t stream)
{
    const float* x      = (const float*)d_in[0];
    const float* W_emb  = (const float*)d_in[1];
    const float* b_emb  = (const float*)d_in[2];
    const float* g_emb  = (const float*)d_in[3];
    const float* be_emb = (const float*)d_in[4];
    const float* cls    = (const float*)d_in[5];
    const float* pos    = (const float*)d_in[6];
    const float* ln1_g  = (const float*)d_in[7];
    const float* ln1_b  = (const float*)d_in[8];
    const float* Wq     = (const float*)d_in[9];
    const float* bq     = (const float*)d_in[10];
    const float* Wk     = (const float*)d_in[11];
    const float* bk     = (const float*)d_in[12];
    const float* Wv     = (const float*)d_in[13];
    const float* bv     = (const float*)d_in[14];
    const float* Wo     = (const float*)d_in[15];
    const float* bo     = (const float*)d_in[16];
    const float* ln2_g  = (const float*)d_in[17];
    const float* ln2_b  = (const float*)d_in[18];
    const float* W1     = (const float*)d_in[19];
    const float* b1     = (const float*)d_in[20];
    const float* W2     = (const float*)d_in[21];
    const float* b2     = (const float*)d_in[22];
    const float* Wc1    = (const float*)d_in[23];
    const float* bc1    = (const float*)d_in[24];
    const float* lnc_g  = (const float*)d_in[25];
    const float* lnc_b  = (const float*)d_in[26];
    const float* Wc2    = (const float*)d_in[27];
    const float* bc2    = (const float*)d_in[28];
    float* out = (float*)d_out;

    char* p = (char*)d_ws;
    bf16* h     = (bf16*)p;  p += (long)M_ * 256 * 2;
    bf16* y     = (bf16*)p;  p += (long)M_ * 256 * 2;
    bf16* qkv   = (bf16*)p;  p += (long)M_ * 768 * 2;
    bf16* obuf  = (bf16*)p;  p += (long)M_ * 256 * 2;
    bf16* tb    = (bf16*)p;  p += (long)M_ * 1024 * 2;
    bf16* Wqkvt = (bf16*)p;  p += (long)L_ * 768 * 256 * 2;
    bf16* Wot   = (bf16*)p;  p += (long)L_ * 256 * 256 * 2;
    bf16* W1t   = (bf16*)p;  p += (long)L_ * 1024 * 256 * 2;
    bf16* W2t   = (bf16*)p;  p += (long)L_ * 256 * 1024 * 2;
    float* bqkv = (float*)p; p += (long)L_ * 768 * 4;
    float* pool = (float*)p; p += (long)B_ * 16 * 256 * 4;
    bf16* vT    = (bf16*)p;  p += (long)64 * 32 * SP_ * 2;

    // ---- weight packing (1 launch) ----
    pack_all<<<3072, 256, 0, stream>>>(Wq, Wk, Wv, bq, bk, bv, Wo, W1, W2,
                                       Wqkvt, bqkv, Wot, W1t, W2t);

    embed4_kernel<<<M_ / 4, 256, 0, stream>>>(x, W_emb, b_emb, g_emb, be_emb, cls, h);

    dim3 gQKV(12, 257), gMLP1(16, 257), gEE(4, 257);
    for (int l = 0; l < L_; ++l) {
        // h += pos; y = LN1(h)
        ln4_kernel<<<M_ / 4, 256, 0, stream>>>(h, pos, ln1_g + l * E_, ln1_b + l * E_, y);
        // qkv = y @ Wqkv + b (V cols also -> vT, transposed)
        gemm_bf16_32x64<<<gQKV, 256, 0, stream>>>(y, Wqkvt + (long)l * 768 * 256, bqkv + l * 768,
                                                  nullptr, qkv, vT, M_, 256, 768, 0);
        attn_mfma9_kernel<<<64 * NQT, 256, 0, stream>>>(qkv, vT, obuf);
        // h += o @ Wo + bo
        gemm_bf16_32x64<<<gEE, 256, 0, stream>>>(obuf, Wot + (long)l * 65536, bo + l * E_,
                                                 h, h, nullptr, M_, 256, 256, 0);
        // y = LN2(h); tb = GELU(y @ W1 + b1)
        ln4_kernel<<<M_ / 4, 256, 0, stream>>>(h, nullptr, ln2_g + l * E_, ln2_b + l * E_, y);
        gemm_bf16_32x64<<<gMLP1, 256, 0, stream>>>(y, W1t + (long)l * 262144, b1 + l * XE_,
                                                   nullptr, tb, nullptr, M_, 256, 1024, 1);
        // h += tb @ W2 + b2
        gemm_bf16_32x64<<<gEE, 256, 0, stream>>>(tb, W2t + (long)l * 262144, b2 + l * E_,
                                                 h, h, nullptr, M_, 1024, 256, 0);
    }

    pool_kernel<<<B_ * 16, 256, 0, stream>>>(h, pool);
    cls_final<<<B_, 256, 0, stream>>>(pool, Wc1, bc1, lnc_g, lnc_b, Wc2, bc2, out);
}